// Round 5
// baseline (2042.544 us; speedup 1.0000x reference)
//
#include <hip/hip_runtime.h>

#define NNODES 50000
#define NEDGES 300000
#define NL 6
#define AP 132

typedef float f32x4 __attribute__((ext_vector_type(4)));
typedef short s16x8 __attribute__((ext_vector_type(8)));
typedef unsigned short u16x4 __attribute__((ext_vector_type(4)));

#define MFMA(A,B,C) __builtin_amdgcn_mfma_f32_16x16x32_bf16((A),(B),(C),0,0,0)

__device__ __forceinline__ unsigned short bf_hi(float x){
  unsigned u = __float_as_uint(x);
  u += 0x7fffu + ((u>>16)&1u);
  return (unsigned short)(u>>16);
}
__device__ __forceinline__ float bf_f(unsigned short s){
  return __uint_as_float(((unsigned)s)<<16);
}
__device__ __forceinline__ void split2(float x, unsigned short &h, unsigned short &l){
  h = bf_hi(x);
  l = bf_hi(x - bf_f(h));
}

__device__ __forceinline__ f32x4 mm3(s16x8 ah, s16x8 al, s16x8 bh, s16x8 bl, f32x4 c){
  c = MFMA(ah, bh, c);
  c = MFMA(ah, bl, c);
  c = MFMA(al, bh, c);
  return c;
}

// ---- packed-weight fragment helpers ----
__device__ __forceinline__ void pack_tile(const float* W, int K, const float* iv,
                                          unsigned short* dst, int kt, int nt, int lane){
  int col = nt*16 + (lane&15);
  int k0 = kt*32 + (lane>>4)*8;
  s16x8 hv, lv;
  #pragma unroll
  for(int j=0;j<8;j++){
    int k = k0 + j;
    float x = 0.f;
    if(k < K){
      x = W[(size_t)k*128 + col];
      if(iv) x *= iv[k];
    }
    unsigned short hh, ll; split2(x, hh, ll);
    hv[j] = (short)hh; lv[j] = (short)ll;
  }
  unsigned short* p = dst + ((size_t)((kt<<3)+nt)*64 + lane)*16;
  *(s16x8*)p = hv;
  *(s16x8*)(p+8) = lv;
}
__device__ __forceinline__ void ld_b(const unsigned short* P, int kt, int nt, int lane,
                                     s16x8 &bh, s16x8 &bl){
  const unsigned short* p = P + ((size_t)((kt<<3)+nt)*64 + lane)*16;
  bh = *(const s16x8*)p;
  bl = *(const s16x8*)(p+8);
}
// LDS bf16 plane, pitch 128 ushorts (256B), XOR swizzle (row&7)<<4  (k_updM)
__device__ __forceinline__ s16x8 ld_z(const unsigned short* z, int row, int kByte){
  return *(const s16x8*)((const char*)z + row*256 + (kByte ^ ((row&7)<<4)));
}
__device__ __forceinline__ void st_z(unsigned short* zH, unsigned short* zL, int row, int col, float x){
  unsigned short hh, ll; split2(x, hh, ll);
  int byte = row*256 + ((col*2) ^ ((row&7)<<4));
  *(unsigned short*)((char*)zH + byte) = hh;
  *(unsigned short*)((char*)zL + byte) = ll;
}
// wave-private z half-plane: 16 rows x 64 cols, pitch 64 ushorts (128B), XOR (row&7)<<4
__device__ __forceinline__ s16x8 ld_y(const unsigned short* z, int row, int kByte){
  return *(const s16x8*)((const char*)z + row*128 + (kByte ^ ((row&7)<<4)));
}
__device__ __forceinline__ void st_y(unsigned short* zH, unsigned short* zL, int row, int lcol, float x){
  unsigned short hh, ll; split2(x, hh, ll);
  int byte = row*128 + ((lcol*2) ^ ((row&7)<<4));
  *(unsigned short*)((char*)zH + byte) = hh;
  *(unsigned short*)((char*)zL + byte) = ll;
}
// LDS bf16 plane, pitch 32 ushorts (64B), XOR swizzle (row&3)<<4 (edge features)
__device__ __forceinline__ s16x8 ld_t(const unsigned short* z, int row, int kByte){
  return *(const s16x8*)((const char*)z + row*64 + (kByte ^ ((row&3)<<4)));
}

// ---------- tiny setup kernels ----------
__global__ void k_gf(const float* dom, const float* t, const float* xg,
                     const float* domn, const float* tn, float* gf){
  int i = threadIdx.x;
  if(i < 3)        gf[i]  = dom[i];
  else if(i == 3)  gf[3]  = t[0];
  else if(i < 8)   gf[i]  = xg[i-4];
  else if(i < 11)  gf[i]  = domn[i-8];
  else if(i == 11) gf[11] = tn[0];
}

__global__ void k_deg(const int* ei, float* deg){
  int e = blockIdx.x*blockDim.x + threadIdx.x;
  if(e < NEDGES) atomicAdd(&deg[ei[NEDGES + e]], 1.0f);
}

__global__ void k_histi(const int* ei, int* cnt){
  int e = blockIdx.x*blockDim.x + threadIdx.x;
  if(e < NEDGES) atomicAdd(&cnt[ei[NEDGES + e]], 1);
}

__global__ __launch_bounds__(1024) void k_scan(const int* cnt, int* off){
  __shared__ int buf[1024];
  __shared__ int carry;
  int t = threadIdx.x;
  if(t == 0) carry = 0;
  __syncthreads();
  for(int base = 0; base < NNODES; base += 1024){
    int i = base + t;
    int x = (i < NNODES) ? cnt[i] : 0;
    buf[t] = x;
    __syncthreads();
    for(int ofs = 1; ofs < 1024; ofs <<= 1){
      int y = (t >= ofs) ? buf[t-ofs] : 0;
      __syncthreads();
      buf[t] += y;
      __syncthreads();
    }
    if(i < NNODES) off[i] = carry + buf[t] - x;
    __syncthreads();
    if(t == 1023) carry += buf[1023];
    __syncthreads();
  }
  if(t == 0) off[NNODES] = carry;
}

__global__ void k_scatter(const int* ei, const int* off, int* cur, int* srcP, int* dstP){
  int e = blockIdx.x*blockDim.x + threadIdx.x;
  if(e < NEDGES){
    int s = ei[e], d = ei[NEDGES + e];
    int p = atomicAdd(&cur[d], 1);
    int ix = off[d] + p;
    srcP[ix] = s; dstP[ix] = d;
  }
}

// old gf-fold (fallback path)
__global__ void k_gfb(const float* gf, const float* mW1, const float* mB1, float* bb1){
  int i = blockIdx.x*256 + threadIdx.x;
  if(i < 768){
    int l = i >> 7, c = i & 127;
    float s = mB1[l*128 + c];
    #pragma unroll
    for(int j=0;j<12;j++) s = fmaf(gf[j], mW1[(size_t)l*35712 + (size_t)(267+j)*128 + c], s);
    bb1[i] = s;
  }
}

// static bias parts: bb1s = msgB1 + gf@msgW1[267:279]; ub1s = updB1 + gf@updW1[256:268]
__global__ void k_gfb2(const float* gf, const float* mW1, const float* mB1,
                       const float* uW1, const float* uB1, float* bb1s, float* ub1s){
  int i = blockIdx.x*256 + threadIdx.x;
  if(i < 768){
    int l = i>>7, c = i&127;
    float s = mB1[l*128+c];
    #pragma unroll
    for(int j=0;j<12;j++) s = fmaf(gf[j], mW1[(size_t)l*35712 + (size_t)(267+j)*128 + c], s);
    bb1s[i] = s;
  } else if(i < 1536){
    int i2 = i-768, l = i2>>7, c = i2&127;
    float s = uB1[l*128+c];
    #pragma unroll
    for(int j=0;j<12;j++) s = fmaf(gf[j], uW1[(size_t)l*34304 + (size_t)(256+j)*128 + c], s);
    ub1s[i2] = s;
  }
}

// per-layer norm stats -> mu/iv (identity for l==0)
__global__ void k_fold(const float* S, float* muiv, int l){
  int c = threadIdx.x;
  if(c >= 128) return;
  if(l == 0){ muiv[c] = 0.f; muiv[128+c] = 1.f; return; }
  float mean = S[c] * (1.0f/NNODES);
  float var  = S[128+c] * (1.0f/NNODES) - mean*mean;
  if(var < 0.f) var = 0.f;
  muiv[c] = mean;
  muiv[128+c] = rsqrtf(var + 1e-5f);
}

// fold -mu*iv terms into biases
__global__ void k_dynbias(const float* muiv, const float* bb1s, const float* ub1s,
                          const float* msgW1l, const float* updW1l,
                          float* bb1d, float* ub1d){
  int c = threadIdx.x;
  if(blockIdx.x == 0){
    float s = bb1s[c];
    for(int k=0;k<128;k++){
      float f = muiv[k]*muiv[128+k];
      s -= f*(msgW1l[(size_t)k*128+c] + msgW1l[(size_t)(128+k)*128+c]);
    }
    bb1d[c] = s;
  } else {
    float s = ub1s[c];
    for(int k=0;k<128;k++) s -= muiv[k]*muiv[128+k]*updW1l[(size_t)k*128+c];
    ub1d[c] = s;
  }
}

// static packs: msgW2, updW1-agg-half, updW2, msg edge rows
__global__ void k_packAll(const float* msgW1, const float* msgW2,
                          const float* updW1, const float* updW2,
                          unsigned short* mPedge, unsigned short* mPw2,
                          unsigned short* uPagg, unsigned short* uPw2){
  int b = blockIdx.x, lane = threadIdx.x;
  if(b < 192){
    int l=b/32, t=b%32;
    pack_tile(msgW2 + (size_t)l*16384, 128, 0, mPw2 + (size_t)l*32768, t/8, t%8, lane);
  } else if(b < 384){
    int bb=b-192, l=bb/32, t=bb%32;
    pack_tile(updW1 + (size_t)l*34304 + 16384, 128, 0, uPagg + (size_t)l*32768, t/8, t%8, lane);
  } else if(b < 576){
    int bb=b-384, l=bb/32, t=bb%32;
    pack_tile(updW2 + (size_t)l*16384, 128, 0, uPw2 + (size_t)l*32768, t/8, t%8, lane);
  } else {
    int bb=b-576, l=bb/8, nt=bb%8;
    pack_tile(msgW1 + (size_t)l*35712 + 32768, 11, 0, mPedge + (size_t)l*8192, 0, nt, lane);
  }
}

// per-layer iv-scaled packs: msgW1 dst-half, src-half, updW1 h-half
__global__ void k_packDyn(const float* msgW1l, const float* updW1l, const float* muiv,
                          unsigned short* mPdst, unsigned short* mPsrc, unsigned short* uPh){
  int b = blockIdx.x, lane = threadIdx.x;
  const float* iv = muiv + 128;
  if(b < 32) pack_tile(msgW1l, 128, iv, mPdst, b>>3, b&7, lane);
  else if(b < 64){ int t=b-32; pack_tile(msgW1l + 16384, 128, iv, mPsrc, t>>3, t&7, lane); }
  else { int t=b-64; pack_tile(updW1l, 128, iv, uPh, t>>3, t&7, lane); }
}

// ---------- shared fp32 GEMM machinery (embed + fallback) ----------
__device__ __forceinline__ void fill_w(float* sW, const float* gW, int KC){
  for(int idx = threadIdx.x; idx < 32*32; idx += 256){
    int kk = idx >> 5, c4 = (idx & 31)*4;
    float4 w = make_float4(0.f,0.f,0.f,0.f);
    if(kk < KC) w = *(const float4*)(gW + (size_t)kk*128 + c4);
    *(float4*)(sW + kk*128 + c4) = w;
  }
}
__device__ __forceinline__ void gemm_chunk(const float* At, const float* sW,
                                           int KCp, int rg, int jc, float acc[4][4]){
  for(int kkg = 0; kkg < KCp; kkg += 4){
    float4 av[4];
    #pragma unroll
    for(int i=0;i<4;i++) av[i] = *(const float4*)(At + (rg*4+i)*AP + kkg);
    #pragma unroll
    for(int q=0;q<4;q++){
      float4 bq = *(const float4*)(sW + (kkg+q)*128 + 4*jc);
      #pragma unroll
      for(int i=0;i<4;i++){
        float aa = ((const float*)&av[i])[q];
        acc[i][0] = fmaf(aa, bq.x, acc[i][0]);
        acc[i][1] = fmaf(aa, bq.y, acc[i][1]);
        acc[i][2] = fmaf(aa, bq.z, acc[i][2]);
        acc[i][3] = fmaf(aa, bq.w, acc[i][3]);
      }
    }
  }
}
__device__ __forceinline__ void gemm_phase(const float* sA, float* sW, const float* gW,
                                           int K, int rg, int jc, float acc[4][4]){
  for(int k0 = 0; k0 < K; k0 += 32){
    int KC = (K - k0 < 32) ? (K - k0) : 32;
    __syncthreads();
    fill_w(sW, gW + (size_t)k0*128, KC);
    __syncthreads();
    gemm_chunk(sA + k0, sW, (KC+3)&~3, rg, jc, acc);
  }
}
__device__ __forceinline__ void init_bias(float acc[4][4], const float* b, int jc){
  float4 bb = *(const float4*)(b + 4*jc);
  #pragma unroll
  for(int i=0;i<4;i++){ acc[i][0]=bb.x; acc[i][1]=bb.y; acc[i][2]=bb.z; acc[i][3]=bb.w; }
}

// ---------- embedding (fp32; also writes bf16 hi/lo planes when hPu != 0) ----------
__global__ __launch_bounds__(256) void k_embed(const float* r, const float* v, const float* gf,
    const float* W1, const float* b1, const float* W2, const float* b2, float* h,
    unsigned short* hPu){
  __shared__ __align__(16) float sA[32*AP];
  __shared__ __align__(16) float sW[32*128];
  __shared__ float sGf[12];
  int t = threadIdx.x, n0 = blockIdx.x*32;
  if(t < 12) sGf[t] = gf[t];
  __syncthreads();
  for(int idx = t; idx < 32*20; idx += 256){
    int row = idx/20, c = idx%20;
    int n = n0 + row; if(n >= NNODES) n = NNODES-1;
    float val;
    if(c == 0)      val = r[n];
    else if(c < 7)  val = v[(size_t)n*6 + (c-1)];
    else if(c < 19) val = sGf[c-7];
    else            val = 0.0f;
    sA[row*AP + c] = val;
  }
  int rg = t>>5, jc = t&31;
  float acc[4][4];
  init_bias(acc, b1, jc);
  gemm_phase(sA, sW, W1, 19, rg, jc, acc);
  __syncthreads();
  #pragma unroll
  for(int i=0;i<4;i++){
    float4 x = make_float4(fmaxf(acc[i][0],0.f), fmaxf(acc[i][1],0.f),
                           fmaxf(acc[i][2],0.f), fmaxf(acc[i][3],0.f));
    *(float4*)&sA[(rg*4+i)*AP + 4*jc] = x;
  }
  init_bias(acc, b2, jc);
  gemm_phase(sA, sW, W2, 128, rg, jc, acc);
  #pragma unroll
  for(int i=0;i<4;i++){
    int n = n0 + rg*4 + i;
    if(n < NNODES){
      float4 x = make_float4(fmaxf(acc[i][0],0.f), fmaxf(acc[i][1],0.f),
                             fmaxf(acc[i][2],0.f), fmaxf(acc[i][3],0.f));
      *(float4*)&h[(size_t)n*128 + 4*jc] = x;
      if(hPu){
        unsigned short h0,h1,h2,h3,l0,l1,l2,l3;
        split2(x.x,h0,l0); split2(x.y,h1,l1); split2(x.z,h2,l2); split2(x.w,h3,l3);
        u16x4 hv; hv[0]=h0; hv[1]=h1; hv[2]=h2; hv[3]=h3;
        u16x4 lv; lv[0]=l0; lv[1]=l1; lv[2]=l2; lv[3]=l3;
        *(u16x4*)&hPu[(size_t)n*256 + 4*jc] = hv;
        *(u16x4*)&hPu[(size_t)n*256 + 128 + 4*jc] = lv;
      }
    }
  }
}

// ---------- MFMA edge kernel v3: wave = 16 edges x 128 cols (no cross-wave A redundancy) ----------
// z1 = norm(h[dst])@Wd + norm(h[src])@Ws + edge@We + bb1d  (norm folded into Wd/Ws/bb1d)
// z2 = relu(z1); m = relu(z2@W2 + b2); per-lane segment reduce -> atomicAdd agg
__global__ __launch_bounds__(256, 4) void k_msgM3(const int* __restrict__ srcP, const int* __restrict__ dstP,
    const unsigned short* __restrict__ hPu,
    const float* __restrict__ pos, const float* __restrict__ v, const float* __restrict__ r,
    const float* __restrict__ dom,
    const unsigned short* __restrict__ mPdst, const unsigned short* __restrict__ mPsrc,
    const unsigned short* __restrict__ mPedge, const unsigned short* __restrict__ mPw2,
    const float* __restrict__ bb1d, const float* __restrict__ b2, float* __restrict__ agg)
{
  // wave-private z half-buffers: [wave][hi/lo][16 rows * 64 cols]
  __shared__ __align__(16) unsigned short zAll[4][2][1024];
  __shared__ __align__(16) unsigned short sTh[2048], sTl[2048];
  __shared__ int sSrc[64], sDst[64];
  __shared__ float sDom[3];
  int t = threadIdx.x;
  // bijective XCD swizzle: 4688 blocks = 8 * 586
  int bid = blockIdx.x;
  int swz = (bid & 7)*586 + (bid >> 3);
  int e0 = swz*64;
  int evalid = NEDGES - e0; if(evalid > 64) evalid = 64;
  int w = t>>6, lane = t&63, lr = lane&15, g = lane>>4;
  if(t < 64){
    int ee = e0 + t; if(ee >= NEDGES) ee = NEDGES-1;
    sSrc[t] = srcP[ee]; sDst[t] = dstP[ee];
  }
  if(t >= 64 && t < 67) sDom[t-64] = dom[t-64];
  {
    // full zero of 64x32 edge-feature planes (256 chunks each) — round-4 bug fix
    s16x8 zz = {0,0,0,0,0,0,0,0};
    ((s16x8*)sTh)[t] = zz;
    ((s16x8*)sTl)[t] = zz;
  }
  __syncthreads();
  if(t < 64){
    int s = sSrc[t], d = sDst[t];
    float f[11];
    #pragma unroll
    for(int c=0;c<3;c++){
      float dp = pos[(size_t)d*3+c] - pos[(size_t)s*3+c];
      float dm = sDom[c];
      f[c] = dp - dm*rintf(dp/dm);
    }
    #pragma unroll
    for(int c=0;c<6;c++) f[3+c] = v[(size_t)d*6+c] - v[(size_t)s*6+c];
    f[9] = r[d]; f[10] = r[s];
    #pragma unroll
    for(int k=0;k<11;k++){
      unsigned short hh, ll; split2(f[k], hh, ll);
      int byte = t*64 + ((k*2) ^ ((t&3)<<4));
      *(unsigned short*)((char*)sTh + byte) = hh;
      *(unsigned short*)((char*)sTl + byte) = ll;
    }
  }
  __syncthreads();
  // this wave's edge rows: w*16 + (0..15); lane lr owns row w*16+lr
  int erow = (w<<4) + lr;
  const unsigned short* pd = hPu + (size_t)sDst[erow]*256;
  const unsigned short* ps = hPu + (size_t)sSrc[erow]*256;
  // z1 accumulators: A[nt] covers cols nt*16+lr, rows g*4..g*4+3 (of this wave's 16)
  f32x4 A[8];
  #pragma unroll
  for(int nt=0;nt<8;nt++){
    float b = bb1d[nt*16+lr];
    f32x4 bb = {b,b,b,b};
    A[nt] = bb;
  }
  int ko = g*8;
  #pragma unroll
  for(int kt=0;kt<4;kt++){
    int o = kt*32 + ko;
    s16x8 DH = *(const s16x8*)(pd + o);
    s16x8 DL = *(const s16x8*)(pd + 128 + o);
    s16x8 SH = *(const s16x8*)(ps + o);
    s16x8 SL = *(const s16x8*)(ps + 128 + o);
    #pragma unroll
    for(int nt=0;nt<8;nt++){
      s16x8 bh, bl;
      ld_b(mPdst, kt, nt, lane, bh, bl);
      A[nt] = mm3(DH, DL, bh, bl, A[nt]);
      ld_b(mPsrc, kt, nt, lane, bh, bl);
      A[nt] = mm3(SH, SL, bh, bl, A[nt]);
    }
  }
  {
    s16x8 TH = ld_t(sTh, erow, g*16);
    s16x8 TL = ld_t(sTl, erow, g*16);
    #pragma unroll
    for(int nt=0;nt<8;nt++){
      s16x8 bh, bl;
      ld_b(mPedge, 0, nt, lane, bh, bl);
      A[nt] = mm3(TH, TL, bh, bl, A[nt]);
    }
  }
  // ---- GEMM2 over wave-private z staging, two col-halves (no block barriers) ----
  unsigned short* zH = zAll[w][0];
  unsigned short* zL = zAll[w][1];
  f32x4 M[8];
  #pragma unroll
  for(int nt=0;nt<8;nt++){
    float b = b2[nt*16+lr];
    f32x4 bb = {b,b,b,b};
    M[nt] = bb;
  }
  #pragma unroll
  for(int hf=0; hf<2; hf++){
    // stage z2 cols hf*64 .. +63 (nt = hf*4 + q)
    #pragma unroll
    for(int q=0;q<4;q++){
      int nt = hf*4 + q;
      #pragma unroll
      for(int i=0;i<4;i++){
        st_y(zH, zL, g*4+i, q*16+lr, fmaxf(A[nt][i],0.f));
      }
    }
    // GEMM2 partial: K-cols hf*64..+63  (weight kt = hf*2 + kt2)
    #pragma unroll
    for(int kt2=0;kt2<2;kt2++){
      s16x8 ZH = ld_y(zH, lr, kt2*64 + g*16);
      s16x8 ZL = ld_y(zL, lr, kt2*64 + g*16);
      #pragma unroll
      for(int nt=0;nt<8;nt++){
        s16x8 bh, bl;
        ld_b(mPw2, hf*2+kt2, nt, lane, bh, bl);
        M[nt] = mm3(ZH, ZL, bh, bl, M[nt]);
      }
    }
  }
  // ---- per-lane segment reduce from accumulators (rows g*4..g*4+3 of this wave) ----
  int base = (w<<4) + (g<<2);
  int dR[4]; bool vR[4];
  #pragma unroll
  for(int i=0;i<4;i++){
    dR[i] = sDst[base+i];
    vR[i] = (base+i) < evalid;
  }
  #pragma unroll
  for(int nt=0;nt<8;nt++){
    int col = nt*16 + lr;
    float run = 0.f; int cur = dR[0];
    #pragma unroll
    for(int i=0;i<4;i++){
      if(vR[i]) run += fmaxf(M[nt][i], 0.f);
      int nxt = (i<3) ? dR[i+1] : -1;
      if(nxt != cur){
        atomicAdd(&agg[(size_t)cur*128 + col], run);
        run = 0.f; cur = nxt;
      }
    }
  }
}

// ---------- MFMA node-update kernel ----------
__global__ __launch_bounds__(256) void k_updM(float* __restrict__ h, unsigned short* __restrict__ hPu,
    float* __restrict__ agg, const int* __restrict__ cnt, const float* __restrict__ muiv,
    const unsigned short* __restrict__ uPh, const unsigned short* __restrict__ uPagg,
    const unsigned short* __restrict__ uPw2,
    const float* __restrict__ ub1d, const float* __restrict__ b2, float* __restrict__ S)
{
  __shared__ __align__(16) unsigned short zBuf[8192];   // agg planes, then z2 planes
  __shared__ __align__(16) float sH[32*AP];
  __shared__ float sRd[32];
  __shared__ float stS[512], stQ[512];
  unsigned short* zH = zBuf; unsigned short* zL = zBuf + 4096;
  int t = threadIdx.x, n0 = blockIdx.x*32;
  int w = t>>6, lane = t&63, lr = lane&15, g = lane>>4;
  int nt0 = w*2, nt1 = nt0+1;
  if(t < 32){
    int n = n0 + t; if(n >= NNODES) n = NNODES-1;
    sRd[t] = 1.0f / fmaxf((float)cnt[n], 1.0f);
  }
  __syncthreads();
  for(int idx = t; idx < 1024; idx += 256){
    int row = idx>>5, c4 = (idx&31)*4;
    int n = n0 + row; bool valid = (n < NNODES); if(!valid) n = NNODES-1;
    float4 hx = *(const float4*)&h[(size_t)n*128 + c4];
    *(float4*)&sH[row*AP + c4] = hx;
    float4 ax = *(const float4*)&agg[(size_t)n*128 + c4];
    float rd = sRd[row];
    ax.x*=rd; ax.y*=rd; ax.z*=rd; ax.w*=rd;
    unsigned short h0,h1,h2,h3,l0,l1,l2,l3;
    split2(ax.x,h0,l0); split2(ax.y,h1,l1); split2(ax.z,h2,l2); split2(ax.w,h3,l3);
    int byte = row*256 + ((c4*2) ^ ((row&7)<<4));
    u16x4 hv; hv[0]=h0; hv[1]=h1; hv[2]=h2; hv[3]=h3;
    u16x4 lv; lv[0]=l0; lv[1]=l1; lv[2]=l2; lv[3]=l3;
    *(u16x4*)((char*)zH + byte) = hv;
    *(u16x4*)((char*)zL + byte) = lv;
    if(valid) *(float4*)&agg[(size_t)n*128 + c4] = make_float4(0.f,0.f,0.f,0.f);
  }
  __syncthreads();
  float bias0 = ub1d[nt0*16+lr], bias1 = ub1d[nt1*16+lr];
  f32x4 a00 = {bias0,bias0,bias0,bias0};
  f32x4 a01 = {bias1,bias1,bias1,bias1};
  f32x4 a10 = a00, a11 = a01;
  int nA0 = n0+lr;    if(nA0 >= NNODES) nA0 = NNODES-1;
  int nA1 = n0+16+lr; if(nA1 >= NNODES) nA1 = NNODES-1;
  const unsigned short* ph0 = hPu + (size_t)nA0*256;
  const unsigned short* ph1 = hPu + (size_t)nA1*256;
  int ko = g*8;
  #pragma unroll
  for(int kt=0;kt<4;kt++){
    int o = kt*32 + ko;
    s16x8 ah0 = *(const s16x8*)(ph0 + o), al0 = *(const s16x8*)(ph0 + 128 + o);
    s16x8 ah1 = *(const s16x8*)(ph1 + o), al1 = *(const s16x8*)(ph1 + 128 + o);
    s16x8 bh, bl;
    ld_b(uPh, kt, nt0, lane, bh, bl);
    a00 = mm3(ah0, al0, bh, bl, a00);
    a10 = mm3(ah1, al1, bh, bl, a10);
    ld_b(uPh, kt, nt1, lane, bh, bl);
    a01 = mm3(ah0, al0, bh, bl, a01);
    a11 = mm3(ah1, al1, bh, bl, a11);
    int kb = kt*64 + g*16;
    s16x8 gh0 = ld_z(zH, lr, kb),    gl0 = ld_z(zL, lr, kb);
    s16x8 gh1 = ld_z(zH, 16+lr, kb), gl1 = ld_z(zL, 16+lr, kb);
    ld_b(uPagg, kt, nt0, lane, bh, bl);
    a00 = mm3(gh0, gl0, bh, bl, a00);
    a10 = mm3(gh1, gl1, bh, bl, a10);
    ld_b(uPagg, kt, nt1, lane, bh, bl);
    a01 = mm3(gh0, gl0, bh, bl, a01);
    a11 = mm3(gh1, gl1, bh, bl, a11);
  }
  __syncthreads();
  #pragma unroll
  for(int i=0;i<4;i++){
    int r0 = g*4+i, r1 = 16+g*4+i;
    st_z(zH, zL, r0, nt0*16+lr, fmaxf(a00[i],0.f));
    st_z(zH, zL, r0, nt1*16+lr, fmaxf(a01[i],0.f));
    st_z(zH, zL, r1, nt0*16+lr, fmaxf(a10[i],0.f));
    st_z(zH, zL, r1, nt1*16+lr, fmaxf(a11[i],0.f));
  }
  __syncthreads();
  float c0 = b2[nt0*16+lr], c1 = b2[nt1*16+lr];
  f32x4 m00 = {c0,c0,c0,c0}, m01 = {c1,c1,c1,c1};
  f32x4 m10 = m00, m11 = m01;
  #pragma unroll
  for(int kt=0;kt<4;kt++){
    int kb = kt*64 + g*16;
    s16x8 ah0 = ld_z(zH, lr, kb),    al0 = ld_z(zL, lr, kb);
    s16x8 ah1 = ld_z(zH, 16+lr, kb), al1 = ld_z(zL, 16+lr, kb);
    s16x8 bh, bl;
    ld_b(uPw2, kt, nt0, lane, bh, bl);
    m00 = mm3(ah0, al0, bh, bl, m00);
    m10 = mm3(ah1, al1, bh, bl, m10);
    ld_b(uPw2, kt, nt1, lane, bh, bl);
    m01 = mm3(ah0, al0, bh, bl, m01);
    m11 = mm3(ah1, al1, bh, bl, m11);
  }
  int col0 = nt0*16+lr, col1 = nt1*16+lr;
  float mu0 = muiv[col0], iv0 = muiv[128+col0];
  float mu1 = muiv[col1], iv1 = muiv[128+col1];
  float s0=0.f,q0=0.f,s1=0.f,q1=0.f;
  #pragma unroll
  for(int tm=0;tm<2;tm++){
    #pragma unroll
    for(int i=0;i<4;i++){
      int row = tm*16 + g*4 + i;
      int n = n0 + row;
      if(n < NNODES){
        float acc0 = (tm==0) ? m00[i] : m10[i];
        float acc1 = (tm==0) ? m01[i] : m11[i];
        float v0 = (sH[row*AP+col0]-mu0)*iv0 + acc0;
        float v1 = (sH[row*AP+col1]-mu1)*iv1 + acc1;
        h[(size_t)n*128+col0] = v0;
        h[(size_t)n*128+col1] = v1;
        unsigned short hh,ll;
        split2(v0,hh,ll); hPu[(size_t)n*256+col0]=hh; hPu[(size_t)n*256+128+col0]=ll;
        split2(v1,hh,ll); hPu[(size_t)n*256+col1]=hh; hPu[(size_t)n*256+128+col1]=ll;
        s0+=v0; q0+=v0*v0; s1+=v1; q1+=v1*v1;
      }
    }
  }
  stS[g*128+col0]=s0; stQ[g*128+col0]=q0;
  stS[g*128+col1]=s1; stQ[g*128+col1]=q1;
  __syncthreads();
  if(t < 128){
    float s = stS[t]+stS[128+t]+stS[256+t]+stS[384+t];
    float q = stQ[t]+stQ[128+t]+stQ[256+t]+stQ[384+t];
    atomicAdd(&S[t], s);
    atomicAdd(&S[128 + t], q);
  }
}

// ---------- fallback kernels (fp32 path, kept for smaller workspaces) ----------
__global__ __launch_bounds__(256) void k_pre(const float* h, const float* W1, float* P){
  __shared__ __align__(16) float sA[32*AP];
  __shared__ __align__(16) float sW[32*128];
  int t = threadIdx.x, n0 = blockIdx.x*32;
  for(int idx = t; idx < 1024; idx += 256){
    int row = idx>>5, c4 = (idx&31)*4;
    int n = n0 + row; if(n >= NNODES) n = NNODES-1;
    *(float4*)&sA[row*AP + c4] = *(const float4*)&h[(size_t)n*128 + c4];
  }
  int rg = t>>5, jc = t&31;
  float acc[4][4];
  #pragma unroll
  for(int i=0;i<4;i++){ acc[i][0]=0.f; acc[i][1]=0.f; acc[i][2]=0.f; acc[i][3]=0.f; }
  gemm_phase(sA, sW, W1, 128, rg, jc, acc);
  #pragma unroll
  for(int i=0;i<4;i++){
    int n = n0 + rg*4 + i;
    if(n < NNODES)
      *(float4*)&P[(size_t)n*256 + 4*jc] = make_float4(acc[i][0],acc[i][1],acc[i][2],acc[i][3]);
  }
  #pragma unroll
  for(int i=0;i<4;i++){ acc[i][0]=0.f; acc[i][1]=0.f; acc[i][2]=0.f; acc[i][3]=0.f; }
  gemm_phase(sA, sW, W1 + (size_t)128*128, 128, rg, jc, acc);
  #pragma unroll
  for(int i=0;i<4;i++){
    int n = n0 + rg*4 + i;
    if(n < NNODES)
      *(float4*)&P[(size_t)n*256 + 128 + 4*jc] = make_float4(acc[i][0],acc[i][1],acc[i][2],acc[i][3]);
  }
}

__global__ __launch_bounds__(256) void k_msg2(const int* ei, const float* P,
    const float* pos, const float* v, const float* r, const float* dom,
    const float* W1, const float* W2, const float* bb1, const float* b2, float* agg){
  __shared__ __align__(16) float sM[32*AP];
  __shared__ __align__(16) float sW[32*128];
  __shared__ float sT[32*12];
  __shared__ float sB[128];
  __shared__ int sSrc[32], sDst[32];
  int t = threadIdx.x, e0 = blockIdx.x*32;
  if(t < 32){ sSrc[t] = ei[e0+t]; sDst[t] = ei[NEDGES + e0 + t]; }
  if(t >= 128) sB[t-128] = bb1[t-128];
  __syncthreads();
  for(int idx = t; idx < 352; idx += 256){
    int kk = idx>>5, c4 = (idx&31)*4;
    *(float4*)&sW[kk*128 + c4] = *(const float4*)&W1[(size_t)(256+kk)*128 + c4];
  }
  if(t < 32){
    int s = sSrc[t], d = sDst[t];
    #pragma unroll
    for(int c=0;c<3;c++){
      float dp = pos[(size_t)d*3+c] - pos[(size_t)s*3+c];
      float dm = dom[c];
      dp = dp - dm * rintf(dp/dm);
      sT[t*12 + c] = dp;
    }
    #pragma unroll
    for(int c=0;c<6;c++)
      sT[t*12 + 3 + c] = v[(size_t)d*6+c] - v[(size_t)s*6+c];
    sT[t*12 + 9]  = r[d];
    sT[t*12 + 10] = r[s];
    sT[t*12 + 11] = 0.0f;
  }
  for(int idx = t; idx < 1024; idx += 256){
    int row = idx>>5, c4 = (idx&31)*4;
    float4 pd = *(const float4*)&P[(size_t)sDst[row]*256 + c4];
    float4 ps = *(const float4*)&P[(size_t)sSrc[row]*256 + 128 + c4];
    float4 bb = *(const float4*)&sB[c4];
    *(float4*)&sM[row*AP + c4] = make_float4(bb.x+pd.x+ps.x, bb.y+pd.y+ps.y,
                                             bb.z+pd.z+ps.z, bb.w+pd.w+ps.w);
  }
  __syncthreads();
  int rg = t>>5, jc = t&31;
  float acc[4][4];
  #pragma unroll
  for(int i=0;i<4;i++)
    #pragma unroll
    for(int c=0;c<4;c++) acc[i][c] = sM[(rg*4+i)*AP + 4*jc + c];
  for(int k=0;k<11;k++){
    float4 b = *(const float4*)&sW[k*128 + 4*jc];
    #pragma unroll
    for(int i=0;i<4;i++){
      float a = sT[(rg*4+i)*12 + k];
      acc[i][0] = fmaf(a, b.x, acc[i][0]);
      acc[i][1] = fmaf(a, b.y, acc[i][1]);
      acc[i][2] = fmaf(a, b.z, acc[i][2]);
      acc[i][3] = fmaf(a, b.w, acc[i][3]);
    }
  }
  #pragma unroll
  for(int i=0;i<4;i++){
    float4 x = make_float4(fmaxf(acc[i][0],0.f), fmaxf(acc[i][1],0.f),
                           fmaxf(acc[i][2],0.f), fmaxf(acc[i][3],0.f));
    *(float4*)&sM[(rg*4+i)*AP + 4*jc] = x;
  }
  init_bias(acc, b2, jc);
  gemm_phase(sM, sW, W2, 128, rg, jc, acc);
  #pragma unroll
  for(int i=0;i<4;i++){
    int d = sDst[rg*4+i];
    #pragma unroll
    for(int c=0;c<4;c++)
      atomicAdd(&agg[(size_t)d*128 + 4*jc + c], fmaxf(acc[i][c], 0.0f));
  }
}

__global__ __launch_bounds__(256) void k_upd(float* h, const float* agg, const float* deg,
    const float* gf, const float* W1, const float* b1, const float* W2, const float* b2, int l){
  __shared__ __align__(16) float sA[32*AP];
  __shared__ __align__(16) float sW[32*128];
  __shared__ float sGf[12], sRd[32];
  int t = threadIdx.x, n0 = blockIdx.x*32;
  if(t < 12) sGf[t] = gf[t];
  if(t < 32){
    int n = n0 + t; if(n >= NNODES) n = NNODES-1;
    sRd[t] = 1.0f / fmaxf(deg[n], 1.0f);
  }
  __syncthreads();
  const float* Wl1 = W1 + (size_t)l*34304;
  const float* Wl2 = W2 + (size_t)l*16384;
  const float* bl1 = b1 + l*128;
  const float* bl2 = b2 + l*128;
  int rg = t>>5, jc = t&31;
  float acc[4][4];
  init_bias(acc, bl1, jc);
  for(int idx = t; idx < 1024; idx += 256){
    int row = idx>>5, c4 = (idx&31)*4;
    int n = n0 + row; if(n >= NNODES) n = NNODES-1;
    *(float4*)&sA[row*AP + c4] = *(const float4*)&h[(size_t)n*128 + c4];
  }
  gemm_phase(sA, sW, Wl1, 128, rg, jc, acc);
  __syncthreads();
  for(int idx = t; idx < 1024; idx += 256){
    int row = idx>>5, c4 = (idx&31)*4;
    int n = n0 + row; if(n >= NNODES) n = NNODES-1;
    float4 x = *(const float4*)&agg[(size_t)n*128 + c4];
    float rd = sRd[row];
    x.x*=rd; x.y*=rd; x.z*=rd; x.w*=rd;
    *(float4*)&sA[row*AP + c4] = x;
  }
  gemm_phase(sA, sW, Wl1 + (size_t)128*128, 128, rg, jc, acc);
  __syncthreads();
  if(t < 32){
    #pragma unroll
    for(int c=0;c<12;c++) sA[t*AP + c] = sGf[c];
  }
  gemm_phase(sA, sW, Wl1 + (size_t)256*128, 12, rg, jc, acc);
  __syncthreads();
  #pragma unroll
  for(int i=0;i<4;i++){
    float4 x = make_float4(fmaxf(acc[i][0],0.f), fmaxf(acc[i][1],0.f),
                           fmaxf(acc[i][2],0.f), fmaxf(acc[i][3],0.f));
    *(float4*)&sA[(rg*4+i)*AP + 4*jc] = x;
  }
  init_bias(acc, bl2, jc);
  gemm_phase(sA, sW, Wl2, 128, rg, jc, acc);
  #pragma unroll
  for(int i=0;i<4;i++){
    int n = n0 + rg*4 + i;
    if(n < NNODES){
      float4 x = *(const float4*)&h[(size_t)n*128 + 4*jc];
      x.x += acc[i][0]; x.y += acc[i][1]; x.z += acc[i][2]; x.w += acc[i][3];
      *(float4*)&h[(size_t)n*128 + 4*jc] = x;
    }
  }
}

// ---------- instance-norm stats / norm ----------
__global__ __launch_bounds__(256) void k_stats(const float* h, float* sum, float* sq){
  int col = threadIdx.x & 127, half = threadIdx.x >> 7;
  float s = 0.f, q = 0.f;
  for(int n = blockIdx.x*2 + half; n < NNODES; n += gridDim.x*2){
    float x = h[(size_t)n*128 + col];
    s += x; q += x*x;
  }
  __shared__ float ls[256], lq[256];
  ls[threadIdx.x] = s; lq[threadIdx.x] = q;
  __syncthreads();
  if(half == 0){
    atomicAdd(&sum[col], ls[col] + ls[128+col]);
    atomicAdd(&sq[col],  lq[col] + lq[128+col]);
  }
}

__global__ void k_norm(float* h, const float* sum, const float* sq){
  size_t i = (size_t)blockIdx.x*256 + threadIdx.x;
  if(i < (size_t)NNODES*128){
    int col = i & 127;
    float mean = sum[col] * (1.0f/NNODES);
    float var  = sq[col] * (1.0f/NNODES) - mean*mean;
    if(var < 0.f) var = 0.f;
    h[i] = (h[i] - mean) * rsqrtf(var + 1e-5f);
  }
}

// ---------- output head + epilogue ----------
__global__ __launch_bounds__(256) void k_out(const float* h, const float* pos, const float* v,
    const float* domn, const float* W1, const float* b1, const float* W2, const float* b2,
    float* out){
  __shared__ __align__(16) float sA[32*AP];
  __shared__ __align__(16) float sW[32*128];
  __shared__ float sW2[128*9], sB2[9], sDn[3];
  int t = threadIdx.x, n0 = blockIdx.x*32;
  for(int idx = t; idx < 128*9; idx += 256) sW2[idx] = W2[idx];
  if(t < 9) sB2[t] = b2[t];
  if(t >= 16 && t < 19) sDn[t-16] = domn[t-16];
  for(int idx = t; idx < 1024; idx += 256){
    int row = idx>>5, c4 = (idx&31)*4;
    int n = n0 + row; if(n >= NNODES) n = NNODES-1;
    *(float4*)&sA[row*AP + c4] = *(const float4*)&h[(size_t)n*128 + c4];
  }
  int rg = t>>5, jc = t&31;
  float acc[4][4];
  init_bias(acc, b1, jc);
  gemm_phase(sA, sW, W1, 128, rg, jc, acc);
  __syncthreads();
  #pragma unroll
  for(int i=0;i<4;i++){
    float4 x = make_float4(fmaxf(acc[i][0],0.f), fmaxf(acc[i][1],0.f),
                           fmaxf(acc[i][2],0.f), fmaxf(acc[i][3],0.f));
    *(float4*)&sA[(rg*4+i)*AP + 4*jc] = x;
  }
  __syncthreads();
  for(int idx = t; idx < 32*9; idx += 256){
    int n = idx/9, c = idx%9;
    int gn = n0 + n;
    if(gn < NNODES){
      float s = sB2[c];
      for(int k=0;k<128;k++) s = fmaf(sA[n*AP + k], sW2[k*9 + c], s);
      if(c < 3){
        float p = 0.001f*s + pos[(size_t)gn*3 + c];
        float dn = sDn[c];
        p = p - floorf(p/dn)*dn;
        out[(size_t)gn*3 + c] = p;
      } else {
        float scale = (c < 6) ? 0.001f : 0.01f;
        float p = scale*s + v[(size_t)gn*6 + (c-3)];
        out[(size_t)150000 + (size_t)gn*6 + (c-3)] = p;
      }
    }
  }
}

// ---------- macro head ----------
__global__ __launch_bounds__(128) void k_macro(const float* sum, const float* W1,
    const float* b1, const float* W2, const float* b2, float* out){
  __shared__ float hm[128], t1[128];
  int t = threadIdx.x;
  hm[t] = sum[t] * (1.0f/NNODES);
  __syncthreads();
  float s = b1[t];
  for(int k=0;k<128;k++) s = fmaf(hm[k], W1[(size_t)k*128 + t], s);
  t1[t] = fmaxf(s, 0.0f);
  __syncthreads();
  if(t < 3){
    float o = b2[t];
    for(int k=0;k<128;k++) o = fmaf(t1[k], W2[(size_t)k*3 + t], o);
    out[450000 + t] = o;
  }
}

extern "C" void kernel_launch(void* const* d_in, const int* in_sizes, int n_in,
                              void* d_out, int out_size, void* d_ws, size_t ws_size,
                              hipStream_t stream){
  const float* v    = (const float*)d_in[0];
  const float* pos  = (const float*)d_in[1];
  const float* r    = (const float*)d_in[2];
  const float* dom  = (const float*)d_in[3];
  const float* tt   = (const float*)d_in[4];
  const float* xg   = (const float*)d_in[5];
  const float* domn = (const float*)d_in[6];
  const float* tn   = (const float*)d_in[7];
  const int*   ei   = (const int*)d_in[8];
  const float* embW1=(const float*)d_in[10]; const float* embB1=(const float*)d_in[11];
  const float* embW2=(const float*)d_in[12]; const float* embB2=(const float*)d_in[13];
  const float* msgW1=(const float*)d_in[14]; const float* msgB1=(const float*)d_in[15];
  const float* msgW2=(const float*)d_in[16]; const float* msgB2=(const float*)d_in[17];
  const float* updW1=(const float*)d_in[18]; const float* updB1=(const float*)d_in[19];
  const float* updW2=(const float*)d_in[20]; const float* updB2=(const float*)d_in[21];
  const float* outW1=(const float*)d_in[22]; const float* outB1=(const float*)d_in[23];
  const float* outW2=(const float*)d_in[24]; const float* outB2=(const float*)d_in[25];
  const float* macW1=(const float*)d_in[26]; const float* macB1=(const float*)d_in[27];
  const float* macW2=(const float*)d_in[28]; const float* macB2=(const float*)d_in[29];

  float* ws = (float*)d_ws;
  float* out = (float*)d_out;
  const bool mf = ws_size >= (size_t)105604292;

  if(mf){
    // ---- MFMA path ----
    float* h    = ws;                              // N*128
    float* agg  = ws + (size_t)6400000;            // N*128
    unsigned short* hPu = (unsigned short*)(ws + 12800000);  // N*256 ushort (hi|lo planes)
    float* Sb   = ws + (size_t)19200000;           // 7*256
    float* gf   = ws + (size_t)19201792;
    float* muiv = ws + (size_t)19201808;           // 256
    float* bb1s = ws + (size_t)19202064;           // 768
    float* ub1s = ws + (size_t)19202832;           // 768
    float* bb1d = ws + (size_t)19203600;           // 128
    float* ub1d = ws + (size_t)19203728;           // 128
    int* cnt  = (int*)(ws + 19203856);
    int* off  = (int*)(ws + 19253856);
    int* cur  = (int*)(ws + 19303857);
    int* srcP = (int*)(ws + 19353857);
    int* dstP = (int*)(ws + 19653857);
    unsigned short* mPdst  = (unsigned short*)(ws + 19953860);
    unsigned short* mPsrc  = (unsigned short*)(ws + 19970244);
    unsigned short* uPh    = (unsigned short*)(ws + 19986628);
    unsigned short* mPedge = (unsigned short*)(ws + 20003012);
    unsigned short* mPw2   = (unsigned short*)(ws + 20027588);
    unsigned short* uPagg  = (unsigned short*)(ws + 20125892);
    unsigned short* uPw2   = (unsigned short*)(ws + 20224196);

    k_gf<<<1, 64, 0, stream>>>(dom, tt, xg, domn, tn, gf);
    k_gfb2<<<6, 256, 0, stream>>>(gf, msgW1, msgB1, updW1, updB1, bb1s, ub1s);
    k_packAll<<<624, 64, 0, stream>>>(msgW1, msgW2, updW1, updW2, mPedge, mPw2, uPagg, uPw2);
    hipMemsetAsync(Sb, 0, 7*256*4, stream);
    hipMemsetAsync(agg, 0, (size_t)6400000*4, stream);
    hipMemsetAsync(cnt, 0, (size_t)NNODES*4, stream);
    hipMemsetAsync(cur, 0, (size_t)NNODES*4, stream);
    k_histi<<<(NEDGES+255)/256, 256, 0, stream>>>(ei, cnt);
    k_scan<<<1, 1024, 0, stream>>>(cnt, off);
    k_scatter<<<(NEDGES+255)/256, 256, 0, stream>>>(ei, off, cur, srcP, dstP);
    k_embed<<<(NNODES+31)/32, 256, 0, stream>>>(r, v, gf, embW1, embB1, embW2, embB2, h, hPu);
    for(int l = 0; l < NL; l++){
      k_fold<<<1, 128, 0, stream>>>((l > 0) ? (Sb + (l-1)*256) : Sb, muiv, l);
      k_dynbias<<<2, 128, 0, stream>>>(muiv, bb1s + l*128, ub1s + l*128,
          msgW1 + (size_t)l*35712, updW1 + (size_t)l*34304, bb1d, ub1d);
      k_packDyn<<<96, 64, 0, stream>>>(msgW1 + (size_t)l*35712, updW1 + (size_t)l*34304,
          muiv, mPdst, mPsrc, uPh);
      k_msgM3<<<4688, 256, 0, stream>>>(srcP, dstP, hPu, pos, v, r, dom,
          mPdst, mPsrc, mPedge + (size_t)l*8192, mPw2 + (size_t)l*32768,
          bb1d, msgB2 + l*128, agg);
      k_updM<<<(NNODES+31)/32, 256, 0, stream>>>(h, hPu, agg, cnt, muiv,
          uPh, uPagg + (size_t)l*32768, uPw2 + (size_t)l*32768,
          ub1d, updB2 + l*128, Sb + l*256);
    }
    k_norm<<<25000, 256, 0, stream>>>(h, Sb + 5*256, Sb + 5*256 + 128);
    k_stats<<<256, 256, 0, stream>>>(h, Sb + 6*256, Sb + 6*256 + 128);
    k_macro<<<1, 128, 0, stream>>>(Sb + 6*256, macW1, macB1, macW2, macB2, out);
    k_out<<<(NNODES+31)/32, 256, 0, stream>>>(h, pos, v, domn,
                                              outW1, outB1, outW2, outB2, out);
    return;
  }

  // ---- fallback fp32 path (smaller workspace; not expected to run) ----
  float* h   = ws;
  float* agg = ws + (size_t)6400000;
  float* P   = ws + (size_t)12800000;
  float* deg = ws + (size_t)25600000;
  float* gf  = ws + (size_t)25650016;
  float* sum = ws + (size_t)25650048;
  float* sq  = ws + (size_t)25650176;
  float* bb1 = ws + (size_t)25650304;

  k_gf<<<1, 64, 0, stream>>>(dom, tt, xg, domn, tn, gf);
  k_gfb<<<3, 256, 0, stream>>>(gf, msgW1, msgB1, bb1);
  hipMemsetAsync(deg, 0, (size_t)NNODES*4, stream);
  k_deg<<<(NEDGES+255)/256, 256, 0, stream>>>(ei, deg);
  k_embed<<<(NNODES+31)/32, 256, 0, stream>>>(r, v, gf, embW1, embB1, embW2, embB2, h,
                                              (unsigned short*)0);
  for(int l = 0; l < NL; l++){
    hipMemsetAsync(agg, 0, (size_t)6400000*4, stream);
    k_pre<<<(NNODES+31)/32, 256, 0, stream>>>(h, msgW1 + (size_t)l*35712, P);
    k_msg2<<<NEDGES/32, 256, 0, stream>>>(ei, P, pos, v, r, dom,
        msgW1 + (size_t)l*35712, msgW2 + (size_t)l*16384,
        bb1 + l*128, msgB2 + l*128, agg);
    k_upd<<<(NNODES+31)/32, 256, 0, stream>>>(h, agg, deg, gf,
        updW1, updB1, updW2, updB2, l);
    hipMemsetAsync(sum, 0, 128*4, stream);
    hipMemsetAsync(sq,  0, 128*4, stream);
    k_stats<<<256, 256, 0, stream>>>(h, sum, sq);
    k_norm<<<25000, 256, 0, stream>>>(h, sum, sq);
  }
  hipMemsetAsync(sum, 0, 128*4, stream);
  hipMemsetAsync(sq,  0, 128*4, stream);
  k_stats<<<256, 256, 0, stream>>>(h, sum, sq);
  k_macro<<<1, 128, 0, stream>>>(sum, macW1, macB1, macW2, macB2, out);
  k_out<<<(NNODES+31)/32, 256, 0, stream>>>(h, pos, v, domn,
                                            outW1, outB1, outW2, outB2, out);
}

// Round 7
// 1715.758 us; speedup vs baseline: 1.1905x; 1.1905x over previous
//
#include <hip/hip_runtime.h>

#define NNODES 50000
#define NEDGES 300000
#define NL 6
#define AP 132

typedef float f32x4 __attribute__((ext_vector_type(4)));
typedef short s16x8 __attribute__((ext_vector_type(8)));
typedef unsigned short u16x4 __attribute__((ext_vector_type(4)));

#define MFMA(A,B,C) __builtin_amdgcn_mfma_f32_16x16x32_bf16((A),(B),(C),0,0,0)

__device__ __forceinline__ unsigned short bf_hi(float x){
  unsigned u = __float_as_uint(x);
  u += 0x7fffu + ((u>>16)&1u);
  return (unsigned short)(u>>16);
}
__device__ __forceinline__ float bf_f(unsigned short s){
  return __uint_as_float(((unsigned)s)<<16);
}
__device__ __forceinline__ void split2(float x, unsigned short &h, unsigned short &l){
  h = bf_hi(x);
  l = bf_hi(x - bf_f(h));
}

__device__ __forceinline__ f32x4 mm3(s16x8 ah, s16x8 al, s16x8 bh, s16x8 bl, f32x4 c){
  c = MFMA(ah, bh, c);
  c = MFMA(ah, bl, c);
  c = MFMA(al, bh, c);
  return c;
}
// A-hi only (src path): B keeps hi+lo precision
__device__ __forceinline__ f32x4 mm2(s16x8 ah, s16x8 bh, s16x8 bl, f32x4 c){
  c = MFMA(ah, bh, c);
  c = MFMA(ah, bl, c);
  return c;
}

// ---- packed-weight fragment helpers ----
__device__ __forceinline__ void pack_tile(const float* W, int K, const float* iv,
                                          unsigned short* dst, int kt, int nt, int lane){
  int col = nt*16 + (lane&15);
  int k0 = kt*32 + (lane>>4)*8;
  s16x8 hv, lv;
  #pragma unroll
  for(int j=0;j<8;j++){
    int k = k0 + j;
    float x = 0.f;
    if(k < K){
      x = W[(size_t)k*128 + col];
      if(iv) x *= iv[k];
    }
    unsigned short hh, ll; split2(x, hh, ll);
    hv[j] = (short)hh; lv[j] = (short)ll;
  }
  unsigned short* p = dst + ((size_t)((kt<<3)+nt)*64 + lane)*16;
  *(s16x8*)p = hv;
  *(s16x8*)(p+8) = lv;
}
__device__ __forceinline__ void ld_b(const unsigned short* P, int kt, int nt, int lane,
                                     s16x8 &bh, s16x8 &bl){
  const unsigned short* p = P + ((size_t)((kt<<3)+nt)*64 + lane)*16;
  bh = *(const s16x8*)p;
  bl = *(const s16x8*)(p+8);
}
// LDS bf16 plane, pitch 128 ushorts (256B), XOR swizzle (row&7)<<4
__device__ __forceinline__ s16x8 ld_z(const unsigned short* z, int row, int kByte){
  return *(const s16x8*)((const char*)z + row*256 + (kByte ^ ((row&7)<<4)));
}
__device__ __forceinline__ void st_z(unsigned short* zH, unsigned short* zL, int row, int col, float x){
  unsigned short hh, ll; split2(x, hh, ll);
  int byte = row*256 + ((col*2) ^ ((row&7)<<4));
  *(unsigned short*)((char*)zH + byte) = hh;
  *(unsigned short*)((char*)zL + byte) = ll;
}
// LDS bf16 plane, pitch 32 ushorts (64B), XOR swizzle (row&3)<<4 (edge features)
__device__ __forceinline__ s16x8 ld_t(const unsigned short* z, int row, int kByte){
  return *(const s16x8*)((const char*)z + row*64 + (kByte ^ ((row&3)<<4)));
}

// ---------- tiny setup kernels ----------
__global__ void k_gf(const float* dom, const float* t, const float* xg,
                     const float* domn, const float* tn, float* gf){
  int i = threadIdx.x;
  if(i < 3)        gf[i]  = dom[i];
  else if(i == 3)  gf[3]  = t[0];
  else if(i < 8)   gf[i]  = xg[i-4];
  else if(i < 11)  gf[i]  = domn[i-8];
  else if(i == 11) gf[11] = tn[0];
}

__global__ void k_deg(const int* ei, float* deg){
  int e = blockIdx.x*blockDim.x + threadIdx.x;
  if(e < NEDGES) atomicAdd(&deg[ei[NEDGES + e]], 1.0f);
}

__global__ void k_histi(const int* ei, int* cnt){
  int e = blockIdx.x*blockDim.x + threadIdx.x;
  if(e < NEDGES) atomicAdd(&cnt[ei[NEDGES + e]], 1);
}

__global__ __launch_bounds__(1024) void k_scan(const int* cnt, int* off){
  __shared__ int buf[1024];
  __shared__ int carry;
  int t = threadIdx.x;
  if(t == 0) carry = 0;
  __syncthreads();
  for(int base = 0; base < NNODES; base += 1024){
    int i = base + t;
    int x = (i < NNODES) ? cnt[i] : 0;
    buf[t] = x;
    __syncthreads();
    for(int ofs = 1; ofs < 1024; ofs <<= 1){
      int y = (t >= ofs) ? buf[t-ofs] : 0;
      __syncthreads();
      buf[t] += y;
      __syncthreads();
    }
    if(i < NNODES) off[i] = carry + buf[t] - x;
    __syncthreads();
    if(t == 1023) carry += buf[1023];
    __syncthreads();
  }
  if(t == 0) off[NNODES] = carry;
}

__global__ void k_scatter(const int* ei, const int* off, int* cur, int* srcP, int* dstP){
  int e = blockIdx.x*blockDim.x + threadIdx.x;
  if(e < NEDGES){
    int s = ei[e], d = ei[NEDGES + e];
    int p = atomicAdd(&cur[d], 1);
    int ix = off[d] + p;
    srcP[ix] = s; dstP[ix] = d;
  }
}

// old gf-fold (fallback path)
__global__ void k_gfb(const float* gf, const float* mW1, const float* mB1, float* bb1){
  int i = blockIdx.x*256 + threadIdx.x;
  if(i < 768){
    int l = i >> 7, c = i & 127;
    float s = mB1[l*128 + c];
    #pragma unroll
    for(int j=0;j<12;j++) s = fmaf(gf[j], mW1[(size_t)l*35712 + (size_t)(267+j)*128 + c], s);
    bb1[i] = s;
  }
}

// static bias parts: bb1s = msgB1 + gf@msgW1[267:279]; ub1s = updB1 + gf@updW1[256:268]
__global__ void k_gfb2(const float* gf, const float* mW1, const float* mB1,
                       const float* uW1, const float* uB1, float* bb1s, float* ub1s){
  int i = blockIdx.x*256 + threadIdx.x;
  if(i < 768){
    int l = i>>7, c = i&127;
    float s = mB1[l*128+c];
    #pragma unroll
    for(int j=0;j<12;j++) s = fmaf(gf[j], mW1[(size_t)l*35712 + (size_t)(267+j)*128 + c], s);
    bb1s[i] = s;
  } else if(i < 1536){
    int i2 = i-768, l = i2>>7, c = i2&127;
    float s = uB1[l*128+c];
    #pragma unroll
    for(int j=0;j<12;j++) s = fmaf(gf[j], uW1[(size_t)l*34304 + (size_t)(256+j)*128 + c], s);
    ub1s[i2] = s;
  }
}

// per-layer norm stats -> mu/iv (identity for l==0)
__global__ void k_fold(const float* S, float* muiv, int l){
  int c = threadIdx.x;
  if(c >= 128) return;
  if(l == 0){ muiv[c] = 0.f; muiv[128+c] = 1.f; return; }
  float mean = S[c] * (1.0f/NNODES);
  float var  = S[128+c] * (1.0f/NNODES) - mean*mean;
  if(var < 0.f) var = 0.f;
  muiv[c] = mean;
  muiv[128+c] = rsqrtf(var + 1e-5f);
}

// fold -mu*iv terms into biases
__global__ void k_dynbias(const float* muiv, const float* bb1s, const float* ub1s,
                          const float* msgW1l, const float* updW1l,
                          float* bb1d, float* ub1d){
  int c = threadIdx.x;
  if(blockIdx.x == 0){
    float s = bb1s[c];
    for(int k=0;k<128;k++){
      float f = muiv[k]*muiv[128+k];
      s -= f*(msgW1l[(size_t)k*128+c] + msgW1l[(size_t)(128+k)*128+c]);
    }
    bb1d[c] = s;
  } else {
    float s = ub1s[c];
    for(int k=0;k<128;k++) s -= muiv[k]*muiv[128+k]*updW1l[(size_t)k*128+c];
    ub1d[c] = s;
  }
}

// static packs: msgW2, updW1-agg-half, updW2, msg edge rows
__global__ void k_packAll(const float* msgW1, const float* msgW2,
                          const float* updW1, const float* updW2,
                          unsigned short* mPedge, unsigned short* mPw2,
                          unsigned short* uPagg, unsigned short* uPw2){
  int b = blockIdx.x, lane = threadIdx.x;
  if(b < 192){
    int l=b/32, t=b%32;
    pack_tile(msgW2 + (size_t)l*16384, 128, 0, mPw2 + (size_t)l*32768, t/8, t%8, lane);
  } else if(b < 384){
    int bb=b-192, l=bb/32, t=bb%32;
    pack_tile(updW1 + (size_t)l*34304 + 16384, 128, 0, uPagg + (size_t)l*32768, t/8, t%8, lane);
  } else if(b < 576){
    int bb=b-384, l=bb/32, t=bb%32;
    pack_tile(updW2 + (size_t)l*16384, 128, 0, uPw2 + (size_t)l*32768, t/8, t%8, lane);
  } else {
    int bb=b-576, l=bb/8, nt=bb%8;
    pack_tile(msgW1 + (size_t)l*35712 + 32768, 11, 0, mPedge + (size_t)l*8192, 0, nt, lane);
  }
}

// per-layer iv-scaled packs: msgW1 dst-half, src-half, updW1 h-half
__global__ void k_packDyn(const float* msgW1l, const float* updW1l, const float* muiv,
                          unsigned short* mPdst, unsigned short* mPsrc, unsigned short* uPh){
  int b = blockIdx.x, lane = threadIdx.x;
  const float* iv = muiv + 128;
  if(b < 32) pack_tile(msgW1l, 128, iv, mPdst, b>>3, b&7, lane);
  else if(b < 64){ int t=b-32; pack_tile(msgW1l + 16384, 128, iv, mPsrc, t>>3, t&7, lane); }
  else { int t=b-64; pack_tile(updW1l, 128, iv, uPh, t>>3, t&7, lane); }
}

// ---------- shared fp32 GEMM machinery (embed + fallback) ----------
__device__ __forceinline__ void fill_w(float* sW, const float* gW, int KC){
  for(int idx = threadIdx.x; idx < 32*32; idx += 256){
    int kk = idx >> 5, c4 = (idx & 31)*4;
    float4 w = make_float4(0.f,0.f,0.f,0.f);
    if(kk < KC) w = *(const float4*)(gW + (size_t)kk*128 + c4);
    *(float4*)(sW + kk*128 + c4) = w;
  }
}
__device__ __forceinline__ void gemm_chunk(const float* At, const float* sW,
                                           int KCp, int rg, int jc, float acc[4][4]){
  for(int kkg = 0; kkg < KCp; kkg += 4){
    float4 av[4];
    #pragma unroll
    for(int i=0;i<4;i++) av[i] = *(const float4*)(At + (rg*4+i)*AP + kkg);
    #pragma unroll
    for(int q=0;q<4;q++){
      float4 bq = *(const float4*)(sW + (kkg+q)*128 + 4*jc);
      #pragma unroll
      for(int i=0;i<4;i++){
        float aa = ((const float*)&av[i])[q];
        acc[i][0] = fmaf(aa, bq.x, acc[i][0]);
        acc[i][1] = fmaf(aa, bq.y, acc[i][1]);
        acc[i][2] = fmaf(aa, bq.z, acc[i][2]);
        acc[i][3] = fmaf(aa, bq.w, acc[i][3]);
      }
    }
  }
}
__device__ __forceinline__ void gemm_phase(const float* sA, float* sW, const float* gW,
                                           int K, int rg, int jc, float acc[4][4]){
  for(int k0 = 0; k0 < K; k0 += 32){
    int KC = (K - k0 < 32) ? (K - k0) : 32;
    __syncthreads();
    fill_w(sW, gW + (size_t)k0*128, KC);
    __syncthreads();
    gemm_chunk(sA + k0, sW, (KC+3)&~3, rg, jc, acc);
  }
}
__device__ __forceinline__ void init_bias(float acc[4][4], const float* b, int jc){
  float4 bb = *(const float4*)(b + 4*jc);
  #pragma unroll
  for(int i=0;i<4;i++){ acc[i][0]=bb.x; acc[i][1]=bb.y; acc[i][2]=bb.z; acc[i][3]=bb.w; }
}

// ---------- embedding (fp32; also writes bf16 hi/lo planes when hPu != 0) ----------
__global__ __launch_bounds__(256) void k_embed(const float* r, const float* v, const float* gf,
    const float* W1, const float* b1, const float* W2, const float* b2, float* h,
    unsigned short* hPu){
  __shared__ __align__(16) float sA[32*AP];
  __shared__ __align__(16) float sW[32*128];
  __shared__ float sGf[12];
  int t = threadIdx.x, n0 = blockIdx.x*32;
  if(t < 12) sGf[t] = gf[t];
  __syncthreads();
  for(int idx = t; idx < 32*20; idx += 256){
    int row = idx/20, c = idx%20;
    int n = n0 + row; if(n >= NNODES) n = NNODES-1;
    float val;
    if(c == 0)      val = r[n];
    else if(c < 7)  val = v[(size_t)n*6 + (c-1)];
    else if(c < 19) val = sGf[c-7];
    else            val = 0.0f;
    sA[row*AP + c] = val;
  }
  int rg = t>>5, jc = t&31;
  float acc[4][4];
  init_bias(acc, b1, jc);
  gemm_phase(sA, sW, W1, 19, rg, jc, acc);
  __syncthreads();
  #pragma unroll
  for(int i=0;i<4;i++){
    float4 x = make_float4(fmaxf(acc[i][0],0.f), fmaxf(acc[i][1],0.f),
                           fmaxf(acc[i][2],0.f), fmaxf(acc[i][3],0.f));
    *(float4*)&sA[(rg*4+i)*AP + 4*jc] = x;
  }
  init_bias(acc, b2, jc);
  gemm_phase(sA, sW, W2, 128, rg, jc, acc);
  #pragma unroll
  for(int i=0;i<4;i++){
    int n = n0 + rg*4 + i;
    if(n < NNODES){
      float4 x = make_float4(fmaxf(acc[i][0],0.f), fmaxf(acc[i][1],0.f),
                             fmaxf(acc[i][2],0.f), fmaxf(acc[i][3],0.f));
      *(float4*)&h[(size_t)n*128 + 4*jc] = x;
      if(hPu){
        unsigned short h0,h1,h2,h3,l0,l1,l2,l3;
        split2(x.x,h0,l0); split2(x.y,h1,l1); split2(x.z,h2,l2); split2(x.w,h3,l3);
        u16x4 hv; hv[0]=h0; hv[1]=h1; hv[2]=h2; hv[3]=h3;
        u16x4 lv; lv[0]=l0; lv[1]=l1; lv[2]=l2; lv[3]=l3;
        *(u16x4*)&hPu[(size_t)n*256 + 4*jc] = hv;
        *(u16x4*)&hPu[(size_t)n*256 + 128 + 4*jc] = lv;
      }
    }
  }
}

// ---------- MFMA edge kernel, 64 edges/block, XCD-swizzled (round-2 proven structure) ----------
// src term uses hi-plane only (mm2) — halves the random src gather bytes.
__global__ __launch_bounds__(256) void k_msgM2(const int* __restrict__ srcP, const int* __restrict__ dstP,
    const unsigned short* __restrict__ hPu,
    const float* __restrict__ pos, const float* __restrict__ v, const float* __restrict__ r,
    const float* __restrict__ dom,
    const unsigned short* __restrict__ mPdst, const unsigned short* __restrict__ mPsrc,
    const unsigned short* __restrict__ mPedge, const unsigned short* __restrict__ mPw2,
    const float* __restrict__ bb1d, const float* __restrict__ b2, float* __restrict__ agg)
{
  // zH[8192] zL[8192] ushorts (64 rows x 128 cols each, swizzled); reused as fp32 sM[64*128]
  __shared__ __align__(16) unsigned short zBuf[16384];
  __shared__ __align__(16) unsigned short sTh[2048], sTl[2048];
  __shared__ int sSrc[64], sDst[64];
  __shared__ float sDom[3];
  unsigned short* zH = zBuf;
  unsigned short* zL = zBuf + 8192;
  int t = threadIdx.x;
  // bijective XCD swizzle: 4688 blocks = 8 * 586
  int bid = blockIdx.x;
  int swz = (bid & 7)*586 + (bid >> 3);
  int e0 = swz*64;
  int evalid = NEDGES - e0; if(evalid > 64) evalid = 64;
  int w = t>>6, lane = t&63, lr = lane&15, g = lane>>4;
  int nt0 = w*2, nt1 = nt0+1;
  if(t < 64){
    int ee = e0 + t; if(ee >= NEDGES) ee = NEDGES-1;
    sSrc[t] = srcP[ee]; sDst[t] = dstP[ee];
  }
  if(t >= 64 && t < 67) sDom[t-64] = dom[t-64];
  {
    s16x8 zz = {0,0,0,0,0,0,0,0};
    ((s16x8*)sTh)[t] = zz;
    ((s16x8*)sTl)[t] = zz;
  }
  __syncthreads();
  if(t < 64){
    int s = sSrc[t], d = sDst[t];
    float f[11];
    #pragma unroll
    for(int c=0;c<3;c++){
      float dp = pos[(size_t)d*3+c] - pos[(size_t)s*3+c];
      float dm = sDom[c];
      f[c] = dp - dm*rintf(dp/dm);
    }
    #pragma unroll
    for(int c=0;c<6;c++) f[3+c] = v[(size_t)d*6+c] - v[(size_t)s*6+c];
    f[9] = r[d]; f[10] = r[s];
    #pragma unroll
    for(int k=0;k<11;k++){
      unsigned short hh, ll; split2(f[k], hh, ll);
      int byte = t*64 + ((k*2) ^ ((t&3)<<4));
      *(unsigned short*)((char*)sTh + byte) = hh;
      *(unsigned short*)((char*)sTl + byte) = ll;
    }
  }
  float bias0 = bb1d[nt0*16+lr], bias1 = bb1d[nt1*16+lr];
  f32x4 A0[4], A1[4];   // A0[rt] = cols nt0, A1[rt] = cols nt1, rows rt*16+...
  #pragma unroll
  for(int rt=0;rt<4;rt++){
    f32x4 b0 = {bias0,bias0,bias0,bias0};
    f32x4 b1v = {bias1,bias1,bias1,bias1};
    A0[rt] = b0; A1[rt] = b1v;
  }
  __syncthreads();
  // per-lane node row pointers (rows rt*16 + lr)
  const unsigned short* pd[4];
  const unsigned short* ps[4];
  #pragma unroll
  for(int rt=0;rt<4;rt++){
    pd[rt] = hPu + (size_t)sDst[rt*16+lr]*256;
    ps[rt] = hPu + (size_t)sSrc[rt*16+lr]*256;
  }
  int ko = g*8;
  #pragma unroll
  for(int kt=0;kt<4;kt++){
    int o = kt*32 + ko;
    s16x8 DH[4], DL[4], SH[4];
    #pragma unroll
    for(int rt=0;rt<4;rt++){
      DH[rt] = *(const s16x8*)(pd[rt] + o);
      DL[rt] = *(const s16x8*)(pd[rt] + 128 + o);
      SH[rt] = *(const s16x8*)(ps[rt] + o);   // src: hi plane only
    }
    s16x8 bh, bl;
    ld_b(mPdst, kt, nt0, lane, bh, bl);
    #pragma unroll
    for(int rt=0;rt<4;rt++) A0[rt] = mm3(DH[rt], DL[rt], bh, bl, A0[rt]);
    ld_b(mPdst, kt, nt1, lane, bh, bl);
    #pragma unroll
    for(int rt=0;rt<4;rt++) A1[rt] = mm3(DH[rt], DL[rt], bh, bl, A1[rt]);
    ld_b(mPsrc, kt, nt0, lane, bh, bl);
    #pragma unroll
    for(int rt=0;rt<4;rt++) A0[rt] = mm2(SH[rt], bh, bl, A0[rt]);
    ld_b(mPsrc, kt, nt1, lane, bh, bl);
    #pragma unroll
    for(int rt=0;rt<4;rt++) A1[rt] = mm2(SH[rt], bh, bl, A1[rt]);
  }
  {
    s16x8 TH[4], TL[4];
    #pragma unroll
    for(int rt=0;rt<4;rt++){
      TH[rt] = ld_t(sTh, rt*16+lr, g*16);
      TL[rt] = ld_t(sTl, rt*16+lr, g*16);
    }
    s16x8 bh, bl;
    ld_b(mPedge, 0, nt0, lane, bh, bl);
    #pragma unroll
    for(int rt=0;rt<4;rt++) A0[rt] = mm3(TH[rt], TL[rt], bh, bl, A0[rt]);
    ld_b(mPedge, 0, nt1, lane, bh, bl);
    #pragma unroll
    for(int rt=0;rt<4;rt++) A1[rt] = mm3(TH[rt], TL[rt], bh, bl, A1[rt]);
  }
  #pragma unroll
  for(int rt=0;rt<4;rt++){
    #pragma unroll
    for(int i=0;i<4;i++){
      int row = rt*16 + g*4 + i;
      st_z(zH, zL, row, nt0*16+lr, fmaxf(A0[rt][i],0.f));
      st_z(zH, zL, row, nt1*16+lr, fmaxf(A1[rt][i],0.f));
    }
  }
  __syncthreads();
  float c0 = b2[nt0*16+lr], c1 = b2[nt1*16+lr];
  f32x4 M0[4], M1[4];
  #pragma unroll
  for(int rt=0;rt<4;rt++){
    f32x4 b0 = {c0,c0,c0,c0};
    f32x4 b1v = {c1,c1,c1,c1};
    M0[rt] = b0; M1[rt] = b1v;
  }
  #pragma unroll
  for(int kt=0;kt<4;kt++){
    int kb = kt*64 + g*16;
    s16x8 ZHv[4], ZLv[4];
    #pragma unroll
    for(int rt=0;rt<4;rt++){
      ZHv[rt] = ld_z(zH, rt*16+lr, kb);
      ZLv[rt] = ld_z(zL, rt*16+lr, kb);
    }
    s16x8 bh, bl;
    ld_b(mPw2, kt, nt0, lane, bh, bl);
    #pragma unroll
    for(int rt=0;rt<4;rt++) M0[rt] = mm3(ZHv[rt], ZLv[rt], bh, bl, M0[rt]);
    ld_b(mPw2, kt, nt1, lane, bh, bl);
    #pragma unroll
    for(int rt=0;rt<4;rt++) M1[rt] = mm3(ZHv[rt], ZLv[rt], bh, bl, M1[rt]);
  }
  __syncthreads();
  float* sM = (float*)zBuf;
  #pragma unroll
  for(int rt=0;rt<4;rt++){
    #pragma unroll
    for(int i=0;i<4;i++){
      int row = rt*16 + g*4 + i;
      sM[row*128 + nt0*16+lr] = fmaxf(M0[rt][i],0.f);
      sM[row*128 + nt1*16+lr] = fmaxf(M1[rt][i],0.f);
    }
  }
  __syncthreads();
  int col = t & 127, half = t >> 7;
  int rbeg = half*32, rend = rbeg + 32;
  int cur = sDst[rbeg];
  float run = 0.f;
  for(int row = rbeg; row < rend; row++){
    if(row < evalid) run += sM[row*128 + col];
    int nxt = (row+1 < rend) ? sDst[row+1] : -1;
    if(nxt != cur){
      atomicAdd(&agg[(size_t)cur*128 + col], run);
      run = 0.f; cur = nxt;
    }
  }
}

// ---------- MFMA node-update kernel ----------
__global__ __launch_bounds__(256) void k_updM(float* __restrict__ h, unsigned short* __restrict__ hPu,
    float* __restrict__ agg, const int* __restrict__ cnt, const float* __restrict__ muiv,
    const unsigned short* __restrict__ uPh, const unsigned short* __restrict__ uPagg,
    const unsigned short* __restrict__ uPw2,
    const float* __restrict__ ub1d, const float* __restrict__ b2, float* __restrict__ S)
{
  __shared__ __align__(16) unsigned short zBuf[8192];   // agg planes, then z2 planes
  __shared__ __align__(16) float sH[32*AP];
  __shared__ float sRd[32];
  __shared__ float stS[512], stQ[512];
  unsigned short* zH = zBuf; unsigned short* zL = zBuf + 4096;
  int t = threadIdx.x, n0 = blockIdx.x*32;
  int w = t>>6, lane = t&63, lr = lane&15, g = lane>>4;
  int nt0 = w*2, nt1 = nt0+1;
  if(t < 32){
    int n = n0 + t; if(n >= NNODES) n = NNODES-1;
    sRd[t] = 1.0f / fmaxf((float)cnt[n], 1.0f);
  }
  __syncthreads();
  for(int idx = t; idx < 1024; idx += 256){
    int row = idx>>5, c4 = (idx&31)*4;
    int n = n0 + row; bool valid = (n < NNODES); if(!valid) n = NNODES-1;
    float4 hx = *(const float4*)&h[(size_t)n*128 + c4];
    *(float4*)&sH[row*AP + c4] = hx;
    float4 ax = *(const float4*)&agg[(size_t)n*128 + c4];
    float rd = sRd[row];
    ax.x*=rd; ax.y*=rd; ax.z*=rd; ax.w*=rd;
    unsigned short h0,h1,h2,h3,l0,l1,l2,l3;
    split2(ax.x,h0,l0); split2(ax.y,h1,l1); split2(ax.z,h2,l2); split2(ax.w,h3,l3);
    int byte = row*256 + ((c4*2) ^ ((row&7)<<4));
    u16x4 hv; hv[0]=h0; hv[1]=h1; hv[2]=h2; hv[3]=h3;
    u16x4 lv; lv[0]=l0; lv[1]=l1; lv[2]=l2; lv[3]=l3;
    *(u16x4*)((char*)zH + byte) = hv;
    *(u16x4*)((char*)zL + byte) = lv;
    if(valid) *(float4*)&agg[(size_t)n*128 + c4] = make_float4(0.f,0.f,0.f,0.f);
  }
  __syncthreads();
  float bias0 = ub1d[nt0*16+lr], bias1 = ub1d[nt1*16+lr];
  f32x4 a00 = {bias0,bias0,bias0,bias0};
  f32x4 a01 = {bias1,bias1,bias1,bias1};
  f32x4 a10 = a00, a11 = a01;
  int nA0 = n0+lr;    if(nA0 >= NNODES) nA0 = NNODES-1;
  int nA1 = n0+16+lr; if(nA1 >= NNODES) nA1 = NNODES-1;
  const unsigned short* ph0 = hPu + (size_t)nA0*256;
  const unsigned short* ph1 = hPu + (size_t)nA1*256;
  int ko = g*8;
  #pragma unroll
  for(int kt=0;kt<4;kt++){
    int o = kt*32 + ko;
    s16x8 ah0 = *(const s16x8*)(ph0 + o), al0 = *(const s16x8*)(ph0 + 128 + o);
    s16x8 ah1 = *(const s16x8*)(ph1 + o), al1 = *(const s16x8*)(ph1 + 128 + o);
    s16x8 bh, bl;
    ld_b(uPh, kt, nt0, lane, bh, bl);
    a00 = mm3(ah0, al0, bh, bl, a00);
    a10 = mm3(ah1, al1, bh, bl, a10);
    ld_b(uPh, kt, nt1, lane, bh, bl);
    a01 = mm3(ah0, al0, bh, bl, a01);
    a11 = mm3(ah1, al1, bh, bl, a11);
    int kb = kt*64 + g*16;
    s16x8 gh0 = ld_z(zH, lr, kb),    gl0 = ld_z(zL, lr, kb);
    s16x8 gh1 = ld_z(zH, 16+lr, kb), gl1 = ld_z(zL, 16+lr, kb);
    ld_b(uPagg, kt, nt0, lane, bh, bl);
    a00 = mm3(gh0, gl0, bh, bl, a00);
    a10 = mm3(gh1, gl1, bh, bl, a10);
    ld_b(uPagg, kt, nt1, lane, bh, bl);
    a01 = mm3(gh0, gl0, bh, bl, a01);
    a11 = mm3(gh1, gl1, bh, bl, a11);
  }
  __syncthreads();
  #pragma unroll
  for(int i=0;i<4;i++){
    int r0 = g*4+i, r1 = 16+g*4+i;
    st_z(zH, zL, r0, nt0*16+lr, fmaxf(a00[i],0.f));
    st_z(zH, zL, r0, nt1*16+lr, fmaxf(a01[i],0.f));
    st_z(zH, zL, r1, nt0*16+lr, fmaxf(a10[i],0.f));
    st_z(zH, zL, r1, nt1*16+lr, fmaxf(a11[i],0.f));
  }
  __syncthreads();
  float c0 = b2[nt0*16+lr], c1 = b2[nt1*16+lr];
  f32x4 m00 = {c0,c0,c0,c0}, m01 = {c1,c1,c1,c1};
  f32x4 m10 = m00, m11 = m01;
  #pragma unroll
  for(int kt=0;kt<4;kt++){
    int kb = kt*64 + g*16;
    s16x8 ah0 = ld_z(zH, lr, kb),    al0 = ld_z(zL, lr, kb);
    s16x8 ah1 = ld_z(zH, 16+lr, kb), al1 = ld_z(zL, 16+lr, kb);
    s16x8 bh, bl;
    ld_b(uPw2, kt, nt0, lane, bh, bl);
    m00 = mm3(ah0, al0, bh, bl, m00);
    m10 = mm3(ah1, al1, bh, bl, m10);
    ld_b(uPw2, kt, nt1, lane, bh, bl);
    m01 = mm3(ah0, al0, bh, bl, m01);
    m11 = mm3(ah1, al1, bh, bl, m11);
  }
  int col0 = nt0*16+lr, col1 = nt1*16+lr;
  float mu0 = muiv[col0], iv0 = muiv[128+col0];
  float mu1 = muiv[col1], iv1 = muiv[128+col1];
  float s0=0.f,q0=0.f,s1=0.f,q1=0.f;
  #pragma unroll
  for(int tm=0;tm<2;tm++){
    #pragma unroll
    for(int i=0;i<4;i++){
      int row = tm*16 + g*4 + i;
      int n = n0 + row;
      if(n < NNODES){
        float acc0 = (tm==0) ? m00[i] : m10[i];
        float acc1 = (tm==0) ? m01[i] : m11[i];
        float v0 = (sH[row*AP+col0]-mu0)*iv0 + acc0;
        float v1 = (sH[row*AP+col1]-mu1)*iv1 + acc1;
        h[(size_t)n*128+col0] = v0;
        h[(size_t)n*128+col1] = v1;
        unsigned short hh,ll;
        split2(v0,hh,ll); hPu[(size_t)n*256+col0]=hh; hPu[(size_t)n*256+128+col0]=ll;
        split2(v1,hh,ll); hPu[(size_t)n*256+col1]=hh; hPu[(size_t)n*256+128+col1]=ll;
        s0+=v0; q0+=v0*v0; s1+=v1; q1+=v1*v1;
      }
    }
  }
  stS[g*128+col0]=s0; stQ[g*128+col0]=q0;
  stS[g*128+col1]=s1; stQ[g*128+col1]=q1;
  __syncthreads();
  if(t < 128){
    float s = stS[t]+stS[128+t]+stS[256+t]+stS[384+t];
    float q = stQ[t]+stQ[128+t]+stQ[256+t]+stQ[384+t];
    atomicAdd(&S[t], s);
    atomicAdd(&S[128 + t], q);
  }
}

// ---------- fallback kernels (fp32 path, kept for smaller workspaces) ----------
__global__ __launch_bounds__(256) void k_pre(const float* h, const float* W1, float* P){
  __shared__ __align__(16) float sA[32*AP];
  __shared__ __align__(16) float sW[32*128];
  int t = threadIdx.x, n0 = blockIdx.x*32;
  for(int idx = t; idx < 1024; idx += 256){
    int row = idx>>5, c4 = (idx&31)*4;
    int n = n0 + row; if(n >= NNODES) n = NNODES-1;
    *(float4*)&sA[row*AP + c4] = *(const float4*)&h[(size_t)n*128 + c4];
  }
  int rg = t>>5, jc = t&31;
  float acc[4][4];
  #pragma unroll
  for(int i=0;i<4;i++){ acc[i][0]=0.f; acc[i][1]=0.f; acc[i][2]=0.f; acc[i][3]=0.f; }
  gemm_phase(sA, sW, W1, 128, rg, jc, acc);
  #pragma unroll
  for(int i=0;i<4;i++){
    int n = n0 + rg*4 + i;
    if(n < NNODES)
      *(float4*)&P[(size_t)n*256 + 4*jc] = make_float4(acc[i][0],acc[i][1],acc[i][2],acc[i][3]);
  }
  #pragma unroll
  for(int i=0;i<4;i++){ acc[i][0]=0.f; acc[i][1]=0.f; acc[i][2]=0.f; acc[i][3]=0.f; }
  gemm_phase(sA, sW, W1 + (size_t)128*128, 128, rg, jc, acc);
  #pragma unroll
  for(int i=0;i<4;i++){
    int n = n0 + rg*4 + i;
    if(n < NNODES)
      *(float4*)&P[(size_t)n*256 + 128 + 4*jc] = make_float4(acc[i][0],acc[i][1],acc[i][2],acc[i][3]);
  }
}

__global__ __launch_bounds__(256) void k_msg2(const int* ei, const float* P,
    const float* pos, const float* v, const float* r, const float* dom,
    const float* W1, const float* W2, const float* bb1, const float* b2, float* agg){
  __shared__ __align__(16) float sM[32*AP];
  __shared__ __align__(16) float sW[32*128];
  __shared__ float sT[32*12];
  __shared__ float sB[128];
  __shared__ int sSrc[32], sDst[32];
  int t = threadIdx.x, e0 = blockIdx.x*32;
  if(t < 32){ sSrc[t] = ei[e0+t]; sDst[t] = ei[NEDGES + e0 + t]; }
  if(t >= 128) sB[t-128] = bb1[t-128];
  __syncthreads();
  for(int idx = t; idx < 352; idx += 256){
    int kk = idx>>5, c4 = (idx&31)*4;
    *(float4*)&sW[kk*128 + c4] = *(const float4*)&W1[(size_t)(256+kk)*128 + c4];
  }
  if(t < 32){
    int s = sSrc[t], d = sDst[t];
    #pragma unroll
    for(int c=0;c<3;c++){
      float dp = pos[(size_t)d*3+c] - pos[(size_t)s*3+c];
      float dm = dom[c];
      dp = dp - dm * rintf(dp/dm);
      sT[t*12 + c] = dp;
    }
    #pragma unroll
    for(int c=0;c<6;c++)
      sT[t*12 + 3 + c] = v[(size_t)d*6+c] - v[(size_t)s*6+c];
    sT[t*12 + 9]  = r[d];
    sT[t*12 + 10] = r[s];
    sT[t*12 + 11] = 0.0f;
  }
  for(int idx = t; idx < 1024; idx += 256){
    int row = idx>>5, c4 = (idx&31)*4;
    float4 pd = *(const float4*)&P[(size_t)sDst[row]*256 + c4];
    float4 ps = *(const float4*)&P[(size_t)sSrc[row]*256 + 128 + c4];
    float4 bb = *(const float4*)&sB[c4];
    *(float4*)&sM[row*AP + c4] = make_float4(bb.x+pd.x+ps.x, bb.y+pd.y+ps.y,
                                             bb.z+pd.z+ps.z, bb.w+pd.w+ps.w);
  }
  __syncthreads();
  int rg = t>>5, jc = t&31;
  float acc[4][4];
  #pragma unroll
  for(int i=0;i<4;i++)
    #pragma unroll
    for(int c=0;c<4;c++) acc[i][c] = sM[(rg*4+i)*AP + 4*jc + c];
  for(int k=0;k<11;k++){
    float4 b = *(const float4*)&sW[k*128 + 4*jc];
    #pragma unroll
    for(int i=0;i<4;i++){
      float a = sT[(rg*4+i)*12 + k];
      acc[i][0] = fmaf(a, b.x, acc[i][0]);
      acc[i][1] = fmaf(a, b.y, acc[i][1]);
      acc[i][2] = fmaf(a, b.z, acc[i][2]);
      acc[i][3] = fmaf(a, b.w, acc[i][3]);
    }
  }
  #pragma unroll
  for(int i=0;i<4;i++){
    float4 x = make_float4(fmaxf(acc[i][0],0.f), fmaxf(acc[i][1],0.f),
                           fmaxf(acc[i][2],0.f), fmaxf(acc[i][3],0.f));
    *(float4*)&sM[(rg*4+i)*AP + 4*jc] = x;
  }
  init_bias(acc, b2, jc);
  gemm_phase(sM, sW, W2, 128, rg, jc, acc);
  #pragma unroll
  for(int i=0;i<4;i++){
    int d = sDst[rg*4+i];
    #pragma unroll
    for(int c=0;c<4;c++)
      atomicAdd(&agg[(size_t)d*128 + 4*jc + c], fmaxf(acc[i][c], 0.0f));
  }
}

__global__ __launch_bounds__(256) void k_upd(float* h, const float* agg, const float* deg,
    const float* gf, const float* W1, const float* b1, const float* W2, const float* b2, int l){
  __shared__ __align__(16) float sA[32*AP];
  __shared__ __align__(16) float sW[32*128];
  __shared__ float sGf[12], sRd[32];
  int t = threadIdx.x, n0 = blockIdx.x*32;
  if(t < 12) sGf[t] = gf[t];
  if(t < 32){
    int n = n0 + t; if(n >= NNODES) n = NNODES-1;
    sRd[t] = 1.0f / fmaxf(deg[n], 1.0f);
  }
  __syncthreads();
  const float* Wl1 = W1 + (size_t)l*34304;
  const float* Wl2 = W2 + (size_t)l*16384;
  const float* bl1 = b1 + l*128;
  const float* bl2 = b2 + l*128;
  int rg = t>>5, jc = t&31;
  float acc[4][4];
  init_bias(acc, bl1, jc);
  for(int idx = t; idx < 1024; idx += 256){
    int row = idx>>5, c4 = (idx&31)*4;
    int n = n0 + row; if(n >= NNODES) n = NNODES-1;
    *(float4*)&sA[row*AP + c4] = *(const float4*)&h[(size_t)n*128 + c4];
  }
  gemm_phase(sA, sW, Wl1, 128, rg, jc, acc);
  __syncthreads();
  for(int idx = t; idx < 1024; idx += 256){
    int row = idx>>5, c4 = (idx&31)*4;
    int n = n0 + row; if(n >= NNODES) n = NNODES-1;
    float4 x = *(const float4*)&agg[(size_t)n*128 + c4];
    float rd = sRd[row];
    x.x*=rd; x.y*=rd; x.z*=rd; x.w*=rd;
    *(float4*)&sA[row*AP + c4] = x;
  }
  gemm_phase(sA, sW, Wl1 + (size_t)128*128, 128, rg, jc, acc);
  __syncthreads();
  if(t < 32){
    #pragma unroll
    for(int c=0;c<12;c++) sA[t*AP + c] = sGf[c];
  }
  gemm_phase(sA, sW, Wl1 + (size_t)256*128, 12, rg, jc, acc);
  __syncthreads();
  #pragma unroll
  for(int i=0;i<4;i++){
    float4 x = make_float4(fmaxf(acc[i][0],0.f), fmaxf(acc[i][1],0.f),
                           fmaxf(acc[i][2],0.f), fmaxf(acc[i][3],0.f));
    *(float4*)&sA[(rg*4+i)*AP + 4*jc] = x;
  }
  init_bias(acc, bl2, jc);
  gemm_phase(sA, sW, Wl2, 128, rg, jc, acc);
  #pragma unroll
  for(int i=0;i<4;i++){
    int n = n0 + rg*4 + i;
    if(n < NNODES){
      float4 x = *(const float4*)&h[(size_t)n*128 + 4*jc];
      x.x += acc[i][0]; x.y += acc[i][1]; x.z += acc[i][2]; x.w += acc[i][3];
      *(float4*)&h[(size_t)n*128 + 4*jc] = x;
    }
  }
}

// ---------- instance-norm stats / norm ----------
__global__ __launch_bounds__(256) void k_stats(const float* h, float* sum, float* sq){
  int col = threadIdx.x & 127, half = threadIdx.x >> 7;
  float s = 0.f, q = 0.f;
  for(int n = blockIdx.x*2 + half; n < NNODES; n += gridDim.x*2){
    float x = h[(size_t)n*128 + col];
    s += x; q += x*x;
  }
  __shared__ float ls[256], lq[256];
  ls[threadIdx.x] = s; lq[threadIdx.x] = q;
  __syncthreads();
  if(half == 0){
    atomicAdd(&sum[col], ls[col] + ls[128+col]);
    atomicAdd(&sq[col],  lq[col] + lq[128+col]);
  }
}

__global__ void k_norm(float* h, const float* sum, const float* sq){
  size_t i = (size_t)blockIdx.x*256 + threadIdx.x;
  if(i < (size_t)NNODES*128){
    int col = i & 127;
    float mean = sum[col] * (1.0f/NNODES);
    float var  = sq[col] * (1.0f/NNODES) - mean*mean;
    if(var < 0.f) var = 0.f;
    h[i] = (h[i] - mean) * rsqrtf(var + 1e-5f);
  }
}

// ---------- output head + epilogue ----------
__global__ __launch_bounds__(256) void k_out(const float* h, const float* pos, const float* v,
    const float* domn, const float* W1, const float* b1, const float* W2, const float* b2,
    float* out){
  __shared__ __align__(16) float sA[32*AP];
  __shared__ __align__(16) float sW[32*128];
  __shared__ float sW2[128*9], sB2[9], sDn[3];
  int t = threadIdx.x, n0 = blockIdx.x*32;
  for(int idx = t; idx < 128*9; idx += 256) sW2[idx] = W2[idx];
  if(t < 9) sB2[t] = b2[t];
  if(t >= 16 && t < 19) sDn[t-16] = domn[t-16];
  for(int idx = t; idx < 1024; idx += 256){
    int row = idx>>5, c4 = (idx&31)*4;
    int n = n0 + row; if(n >= NNODES) n = NNODES-1;
    *(float4*)&sA[row*AP + c4] = *(const float4*)&h[(size_t)n*128 + c4];
  }
  int rg = t>>5, jc = t&31;
  float acc[4][4];
  init_bias(acc, b1, jc);
  gemm_phase(sA, sW, W1, 128, rg, jc, acc);
  __syncthreads();
  #pragma unroll
  for(int i=0;i<4;i++){
    float4 x = make_float4(fmaxf(acc[i][0],0.f), fmaxf(acc[i][1],0.f),
                           fmaxf(acc[i][2],0.f), fmaxf(acc[i][3],0.f));
    *(float4*)&sA[(rg*4+i)*AP + 4*jc] = x;
  }
  __syncthreads();
  for(int idx = t; idx < 32*9; idx += 256){
    int n = idx/9, c = idx%9;
    int gn = n0 + n;
    if(gn < NNODES){
      float s = sB2[c];
      for(int k=0;k<128;k++) s = fmaf(sA[n*AP + k], sW2[k*9 + c], s);
      if(c < 3){
        float p = 0.001f*s + pos[(size_t)gn*3 + c];
        float dn = sDn[c];
        p = p - floorf(p/dn)*dn;
        out[(size_t)gn*3 + c] = p;
      } else {
        float scale = (c < 6) ? 0.001f : 0.01f;
        float p = scale*s + v[(size_t)gn*6 + (c-3)];
        out[(size_t)150000 + (size_t)gn*6 + (c-3)] = p;
      }
    }
  }
}

// ---------- macro head ----------
__global__ __launch_bounds__(128) void k_macro(const float* sum, const float* W1,
    const float* b1, const float* W2, const float* b2, float* out){
  __shared__ float hm[128], t1[128];
  int t = threadIdx.x;
  hm[t] = sum[t] * (1.0f/NNODES);
  __syncthreads();
  float s = b1[t];
  for(int k=0;k<128;k++) s = fmaf(hm[k], W1[(size_t)k*128 + t], s);
  t1[t] = fmaxf(s, 0.0f);
  __syncthreads();
  if(t < 3){
    float o = b2[t];
    for(int k=0;k<128;k++) o = fmaf(t1[k], W2[(size_t)k*3 + t], o);
    out[450000 + t] = o;
  }
}

extern "C" void kernel_launch(void* const* d_in, const int* in_sizes, int n_in,
                              void* d_out, int out_size, void* d_ws, size_t ws_size,
                              hipStream_t stream){
  const float* v    = (const float*)d_in[0];
  const float* pos  = (const float*)d_in[1];
  const float* r    = (const float*)d_in[2];
  const float* dom  = (const float*)d_in[3];
  const float* tt   = (const float*)d_in[4];
  const float* xg   = (const float*)d_in[5];
  const float* domn = (const float*)d_in[6];
  const float* tn   = (const float*)d_in[7];
  const int*   ei   = (const int*)d_in[8];
  const float* embW1=(const float*)d_in[10]; const float* embB1=(const float*)d_in[11];
  const float* embW2=(const float*)d_in[12]; const float* embB2=(const float*)d_in[13];
  const float* msgW1=(const float*)d_in[14]; const float* msgB1=(const float*)d_in[15];
  const float* msgW2=(const float*)d_in[16]; const float* msgB2=(const float*)d_in[17];
  const float* updW1=(const float*)d_in[18]; const float* updB1=(const float*)d_in[19];
  const float* updW2=(const float*)d_in[20]; const float* updB2=(const float*)d_in[21];
  const float* outW1=(const float*)d_in[22]; const float* outB1=(const float*)d_in[23];
  const float* outW2=(const float*)d_in[24]; const float* outB2=(const float*)d_in[25];
  const float* macW1=(const float*)d_in[26]; const float* macB1=(const float*)d_in[27];
  const float* macW2=(const float*)d_in[28]; const float* macB2=(const float*)d_in[29];

  float* ws = (float*)d_ws;
  float* out = (float*)d_out;
  const bool mf = ws_size >= (size_t)105604292;

  if(mf){
    // ---- MFMA path ----
    float* h    = ws;                              // N*128
    float* agg  = ws + (size_t)6400000;            // N*128
    unsigned short* hPu = (unsigned short*)(ws + 12800000);  // N*256 ushort (hi|lo planes)
    float* Sb   = ws + (size_t)19200000;           // 7*256
    float* gf   = ws + (size_t)19201792;
    float* muiv = ws + (size_t)19201808;           // 256
    float* bb1s = ws + (size_t)19202064;           // 768
    float* ub1s = ws + (size_t)19202832;           // 768
    float* bb1d = ws + (size_t)19203600;           // 128
    float* ub1d = ws + (size_t)19203728;           // 128
    int* cnt  = (int*)(ws + 19203856);
    int* off  = (int*)(ws + 19253856);
    int* cur  = (int*)(ws + 19303857);
    int* srcP = (int*)(ws + 19353857);
    int* dstP = (int*)(ws + 19653857);
    unsigned short* mPdst  = (unsigned short*)(ws + 19953860);
    unsigned short* mPsrc  = (unsigned short*)(ws + 19970244);
    unsigned short* uPh    = (unsigned short*)(ws + 19986628);
    unsigned short* mPedge = (unsigned short*)(ws + 20003012);
    unsigned short* mPw2   = (unsigned short*)(ws + 20027588);
    unsigned short* uPagg  = (unsigned short*)(ws + 20125892);
    unsigned short* uPw2   = (unsigned short*)(ws + 20224196);

    k_gf<<<1, 64, 0, stream>>>(dom, tt, xg, domn, tn, gf);
    k_gfb2<<<6, 256, 0, stream>>>(gf, msgW1, msgB1, updW1, updB1, bb1s, ub1s);
    k_packAll<<<624, 64, 0, stream>>>(msgW1, msgW2, updW1, updW2, mPedge, mPw2, uPagg, uPw2);
    hipMemsetAsync(Sb, 0, 7*256*4, stream);
    hipMemsetAsync(agg, 0, (size_t)6400000*4, stream);
    hipMemsetAsync(cnt, 0, (size_t)NNODES*4, stream);
    hipMemsetAsync(cur, 0, (size_t)NNODES*4, stream);
    k_histi<<<(NEDGES+255)/256, 256, 0, stream>>>(ei, cnt);
    k_scan<<<1, 1024, 0, stream>>>(cnt, off);
    k_scatter<<<(NEDGES+255)/256, 256, 0, stream>>>(ei, off, cur, srcP, dstP);
    k_embed<<<(NNODES+31)/32, 256, 0, stream>>>(r, v, gf, embW1, embB1, embW2, embB2, h, hPu);
    for(int l = 0; l < NL; l++){
      k_fold<<<1, 128, 0, stream>>>((l > 0) ? (Sb + (l-1)*256) : Sb, muiv, l);
      k_dynbias<<<2, 128, 0, stream>>>(muiv, bb1s + l*128, ub1s + l*128,
          msgW1 + (size_t)l*35712, updW1 + (size_t)l*34304, bb1d, ub1d);
      k_packDyn<<<96, 64, 0, stream>>>(msgW1 + (size_t)l*35712, updW1 + (size_t)l*34304,
          muiv, mPdst, mPsrc, uPh);
      k_msgM2<<<4688, 256, 0, stream>>>(srcP, dstP, hPu, pos, v, r, dom,
          mPdst, mPsrc, mPedge + (size_t)l*8192, mPw2 + (size_t)l*32768,
          bb1d, msgB2 + l*128, agg);
      k_updM<<<(NNODES+31)/32, 256, 0, stream>>>(h, hPu, agg, cnt, muiv,
          uPh, uPagg + (size_t)l*32768, uPw2 + (size_t)l*32768,
          ub1d, updB2 + l*128, Sb + l*256);
    }
    k_norm<<<25000, 256, 0, stream>>>(h, Sb + 5*256, Sb + 5*256 + 128);
    k_stats<<<256, 256, 0, stream>>>(h, Sb + 6*256, Sb + 6*256 + 128);
    k_macro<<<1, 128, 0, stream>>>(Sb + 6*256, macW1, macB1, macW2, macB2, out);
    k_out<<<(NNODES+31)/32, 256, 0, stream>>>(h, pos, v, domn,
                                              outW1, outB1, outW2, outB2, out);
    return;
  }

  // ---- fallback fp32 path (smaller workspace; not expected to run) ----
  float* h   = ws;
  float* agg = ws + (size_t)6400000;
  float* P   = ws + (size_t)12800000;
  float* deg = ws + (size_t)25600000;
  float* gf  = ws + (size_t)25650016;
  float* sum = ws + (size_t)25650048;
  float* sq  = ws + (size_t)25650176;
  float* bb1 = ws + (size_t)25650304;

  k_gf<<<1, 64, 0, stream>>>(dom, tt, xg, domn, tn, gf);
  k_gfb<<<3, 256, 0, stream>>>(gf, msgW1, msgB1, bb1);
  hipMemsetAsync(deg, 0, (size_t)NNODES*4, stream);
  k_deg<<<(NEDGES+255)/256, 256, 0, stream>>>(ei, deg);
  k_embed<<<(NNODES+31)/32, 256, 0, stream>>>(r, v, gf, embW1, embB1, embW2, embB2, h,
                                              (unsigned short*)0);
  for(int l = 0; l < NL; l++){
    hipMemsetAsync(agg, 0, (size_t)6400000*4, stream);
    k_pre<<<(NNODES+31)/32, 256, 0, stream>>>(h, msgW1 + (size_t)l*35712, P);
    k_msg2<<<NEDGES/32, 256, 0, stream>>>(ei, P, pos, v, r, dom,
        msgW1 + (size_t)l*35712, msgW2 + (size_t)l*16384,
        bb1 + l*128, msgB2 + l*128, agg);
    k_upd<<<(NNODES+31)/32, 256, 0, stream>>>(h, agg, deg, gf,
        updW1, updB1, updW2, updB2, l);
    hipMemsetAsync(sum, 0, 128*4, stream);
    hipMemsetAsync(sq,  0, 128*4, stream);
    k_stats<<<256, 256, 0, stream>>>(h, sum, sq);
    k_norm<<<25000, 256, 0, stream>>>(h, sum, sq);
  }
  hipMemsetAsync(sum, 0, 128*4, stream);
  hipMemsetAsync(sq,  0, 128*4, stream);
  k_stats<<<256, 256, 0, stream>>>(h, sum, sq);
  k_macro<<<1, 128, 0, stream>>>(sum, macW1, macB1, macW2, macB2, out);
  k_out<<<(NNODES+31)/32, 256, 0, stream>>>(h, pos, v, domn,
                                            outW1, outB1, outW2, outB2, out);
}

// Round 8
// 1714.401 us; speedup vs baseline: 1.1914x; 1.0008x over previous
//
#include <hip/hip_runtime.h>

#define NNODES 50000
#define NEDGES 300000
#define NL 6
#define AP 132

typedef float f32x4 __attribute__((ext_vector_type(4)));
typedef short s16x8 __attribute__((ext_vector_type(8)));
typedef unsigned short u16x4 __attribute__((ext_vector_type(4)));

#define MFMA(A,B,C) __builtin_amdgcn_mfma_f32_16x16x32_bf16((A),(B),(C),0,0,0)

__device__ __forceinline__ unsigned short bf_hi(float x){
  unsigned u = __float_as_uint(x);
  u += 0x7fffu + ((u>>16)&1u);
  return (unsigned short)(u>>16);
}
__device__ __forceinline__ float bf_f(unsigned short s){
  return __uint_as_float(((unsigned)s)<<16);
}
__device__ __forceinline__ void split2(float x, unsigned short &h, unsigned short &l){
  h = bf_hi(x);
  l = bf_hi(x - bf_f(h));
}

__device__ __forceinline__ f32x4 mm3(s16x8 ah, s16x8 al, s16x8 bh, s16x8 bl, f32x4 c){
  c = MFMA(ah, bh, c);
  c = MFMA(ah, bl, c);
  c = MFMA(al, bh, c);
  return c;
}
// A-hi only (src path): B keeps hi+lo precision
__device__ __forceinline__ f32x4 mm2(s16x8 ah, s16x8 bh, s16x8 bl, f32x4 c){
  c = MFMA(ah, bh, c);
  c = MFMA(ah, bl, c);
  return c;
}

// ---- packed-weight fragment helpers ----
__device__ __forceinline__ void pack_tile(const float* W, int K, const float* iv,
                                          unsigned short* dst, int kt, int nt, int lane){
  int col = nt*16 + (lane&15);
  int k0 = kt*32 + (lane>>4)*8;
  s16x8 hv, lv;
  #pragma unroll
  for(int j=0;j<8;j++){
    int k = k0 + j;
    float x = 0.f;
    if(k < K){
      x = W[(size_t)k*128 + col];
      if(iv) x *= iv[k];
    }
    unsigned short hh, ll; split2(x, hh, ll);
    hv[j] = (short)hh; lv[j] = (short)ll;
  }
  unsigned short* p = dst + ((size_t)((kt<<3)+nt)*64 + lane)*16;
  *(s16x8*)p = hv;
  *(s16x8*)(p+8) = lv;
}
__device__ __forceinline__ void ld_b(const unsigned short* P, int kt, int nt, int lane,
                                     s16x8 &bh, s16x8 &bl){
  const unsigned short* p = P + ((size_t)((kt<<3)+nt)*64 + lane)*16;
  bh = *(const s16x8*)p;
  bl = *(const s16x8*)(p+8);
}
// LDS bf16 plane, pitch 128 ushorts (256B), XOR swizzle (row&7)<<4
__device__ __forceinline__ s16x8 ld_z(const unsigned short* z, int row, int kByte){
  return *(const s16x8*)((const char*)z + row*256 + (kByte ^ ((row&7)<<4)));
}
__device__ __forceinline__ void st_z(unsigned short* zH, unsigned short* zL, int row, int col, float x){
  unsigned short hh, ll; split2(x, hh, ll);
  int byte = row*256 + ((col*2) ^ ((row&7)<<4));
  *(unsigned short*)((char*)zH + byte) = hh;
  *(unsigned short*)((char*)zL + byte) = ll;
}
// LDS bf16 plane, pitch 32 ushorts (64B), XOR swizzle (row&3)<<4 (edge features)
__device__ __forceinline__ s16x8 ld_t(const unsigned short* z, int row, int kByte){
  return *(const s16x8*)((const char*)z + row*64 + (kByte ^ ((row&3)<<4)));
}

// ---------- tiny setup kernels ----------
__global__ void k_gf(const float* dom, const float* t, const float* xg,
                     const float* domn, const float* tn, float* gf){
  int i = threadIdx.x;
  if(i < 3)        gf[i]  = dom[i];
  else if(i == 3)  gf[3]  = t[0];
  else if(i < 8)   gf[i]  = xg[i-4];
  else if(i < 11)  gf[i]  = domn[i-8];
  else if(i == 11) gf[11] = tn[0];
}

__global__ void k_deg(const int* ei, float* deg){
  int e = blockIdx.x*blockDim.x + threadIdx.x;
  if(e < NEDGES) atomicAdd(&deg[ei[NEDGES + e]], 1.0f);
}

__global__ void k_histi(const int* ei, int* cnt){
  int e = blockIdx.x*blockDim.x + threadIdx.x;
  if(e < NEDGES) atomicAdd(&cnt[ei[NEDGES + e]], 1);
}

__global__ __launch_bounds__(1024) void k_scan(const int* cnt, int* off){
  __shared__ int buf[1024];
  __shared__ int carry;
  int t = threadIdx.x;
  if(t == 0) carry = 0;
  __syncthreads();
  for(int base = 0; base < NNODES; base += 1024){
    int i = base + t;
    int x = (i < NNODES) ? cnt[i] : 0;
    buf[t] = x;
    __syncthreads();
    for(int ofs = 1; ofs < 1024; ofs <<= 1){
      int y = (t >= ofs) ? buf[t-ofs] : 0;
      __syncthreads();
      buf[t] += y;
      __syncthreads();
    }
    if(i < NNODES) off[i] = carry + buf[t] - x;
    __syncthreads();
    if(t == 1023) carry += buf[1023];
    __syncthreads();
  }
  if(t == 0) off[NNODES] = carry;
}

__global__ void k_scatter(const int* ei, const int* off, int* cur, int* srcP, int* dstP){
  int e = blockIdx.x*blockDim.x + threadIdx.x;
  if(e < NEDGES){
    int s = ei[e], d = ei[NEDGES + e];
    int p = atomicAdd(&cur[d], 1);
    int ix = off[d] + p;
    srcP[ix] = s; dstP[ix] = d;
  }
}

// old gf-fold (fallback path)
__global__ void k_gfb(const float* gf, const float* mW1, const float* mB1, float* bb1){
  int i = blockIdx.x*256 + threadIdx.x;
  if(i < 768){
    int l = i >> 7, c = i & 127;
    float s = mB1[l*128 + c];
    #pragma unroll
    for(int j=0;j<12;j++) s = fmaf(gf[j], mW1[(size_t)l*35712 + (size_t)(267+j)*128 + c], s);
    bb1[i] = s;
  }
}

// static bias parts: bb1s = msgB1 + gf@msgW1[267:279]; ub1s = updB1 + gf@updW1[256:268]
__global__ void k_gfb2(const float* gf, const float* mW1, const float* mB1,
                       const float* uW1, const float* uB1, float* bb1s, float* ub1s){
  int i = blockIdx.x*256 + threadIdx.x;
  if(i < 768){
    int l = i>>7, c = i&127;
    float s = mB1[l*128+c];
    #pragma unroll
    for(int j=0;j<12;j++) s = fmaf(gf[j], mW1[(size_t)l*35712 + (size_t)(267+j)*128 + c], s);
    bb1s[i] = s;
  } else if(i < 1536){
    int i2 = i-768, l = i2>>7, c = i2&127;
    float s = uB1[l*128+c];
    #pragma unroll
    for(int j=0;j<12;j++) s = fmaf(gf[j], uW1[(size_t)l*34304 + (size_t)(256+j)*128 + c], s);
    ub1s[i2] = s;
  }
}

// per-layer norm stats -> mu/iv (identity for l==0)
__global__ void k_fold(const float* S, float* muiv, int l){
  int c = threadIdx.x;
  if(c >= 128) return;
  if(l == 0){ muiv[c] = 0.f; muiv[128+c] = 1.f; return; }
  float mean = S[c] * (1.0f/NNODES);
  float var  = S[128+c] * (1.0f/NNODES) - mean*mean;
  if(var < 0.f) var = 0.f;
  muiv[c] = mean;
  muiv[128+c] = rsqrtf(var + 1e-5f);
}

// fold -mu*iv terms into biases
__global__ void k_dynbias(const float* muiv, const float* bb1s, const float* ub1s,
                          const float* msgW1l, const float* updW1l,
                          float* bb1d, float* ub1d){
  int c = threadIdx.x;
  if(blockIdx.x == 0){
    float s = bb1s[c];
    for(int k=0;k<128;k++){
      float f = muiv[k]*muiv[128+k];
      s -= f*(msgW1l[(size_t)k*128+c] + msgW1l[(size_t)(128+k)*128+c]);
    }
    bb1d[c] = s;
  } else {
    float s = ub1s[c];
    for(int k=0;k<128;k++) s -= muiv[k]*muiv[128+k]*updW1l[(size_t)k*128+c];
    ub1d[c] = s;
  }
}

// static packs: msgW2, updW1-agg-half, updW2, msg edge rows
__global__ void k_packAll(const float* msgW1, const float* msgW2,
                          const float* updW1, const float* updW2,
                          unsigned short* mPedge, unsigned short* mPw2,
                          unsigned short* uPagg, unsigned short* uPw2){
  int b = blockIdx.x, lane = threadIdx.x;
  if(b < 192){
    int l=b/32, t=b%32;
    pack_tile(msgW2 + (size_t)l*16384, 128, 0, mPw2 + (size_t)l*32768, t/8, t%8, lane);
  } else if(b < 384){
    int bb=b-192, l=bb/32, t=bb%32;
    pack_tile(updW1 + (size_t)l*34304 + 16384, 128, 0, uPagg + (size_t)l*32768, t/8, t%8, lane);
  } else if(b < 576){
    int bb=b-384, l=bb/32, t=bb%32;
    pack_tile(updW2 + (size_t)l*16384, 128, 0, uPw2 + (size_t)l*32768, t/8, t%8, lane);
  } else {
    int bb=b-576, l=bb/8, nt=bb%8;
    pack_tile(msgW1 + (size_t)l*35712 + 32768, 11, 0, mPedge + (size_t)l*8192, 0, nt, lane);
  }
}

// per-layer iv-scaled packs: msgW1 dst-half, src-half, updW1 h-half
__global__ void k_packDyn(const float* msgW1l, const float* updW1l, const float* muiv,
                          unsigned short* mPdst, unsigned short* mPsrc, unsigned short* uPh){
  int b = blockIdx.x, lane = threadIdx.x;
  const float* iv = muiv + 128;
  if(b < 32) pack_tile(msgW1l, 128, iv, mPdst, b>>3, b&7, lane);
  else if(b < 64){ int t=b-32; pack_tile(msgW1l + 16384, 128, iv, mPsrc, t>>3, t&7, lane); }
  else { int t=b-64; pack_tile(updW1l, 128, iv, uPh, t>>3, t&7, lane); }
}

// ---------- shared fp32 GEMM machinery (embed + fallback) ----------
__device__ __forceinline__ void fill_w(float* sW, const float* gW, int KC){
  for(int idx = threadIdx.x; idx < 32*32; idx += 256){
    int kk = idx >> 5, c4 = (idx & 31)*4;
    float4 w = make_float4(0.f,0.f,0.f,0.f);
    if(kk < KC) w = *(const float4*)(gW + (size_t)kk*128 + c4);
    *(float4*)(sW + kk*128 + c4) = w;
  }
}
__device__ __forceinline__ void gemm_chunk(const float* At, const float* sW,
                                           int KCp, int rg, int jc, float acc[4][4]){
  for(int kkg = 0; kkg < KCp; kkg += 4){
    float4 av[4];
    #pragma unroll
    for(int i=0;i<4;i++) av[i] = *(const float4*)(At + (rg*4+i)*AP + kkg);
    #pragma unroll
    for(int q=0;q<4;q++){
      float4 bq = *(const float4*)(sW + (kkg+q)*128 + 4*jc);
      #pragma unroll
      for(int i=0;i<4;i++){
        float aa = ((const float*)&av[i])[q];
        acc[i][0] = fmaf(aa, bq.x, acc[i][0]);
        acc[i][1] = fmaf(aa, bq.y, acc[i][1]);
        acc[i][2] = fmaf(aa, bq.z, acc[i][2]);
        acc[i][3] = fmaf(aa, bq.w, acc[i][3]);
      }
    }
  }
}
__device__ __forceinline__ void gemm_phase(const float* sA, float* sW, const float* gW,
                                           int K, int rg, int jc, float acc[4][4]){
  for(int k0 = 0; k0 < K; k0 += 32){
    int KC = (K - k0 < 32) ? (K - k0) : 32;
    __syncthreads();
    fill_w(sW, gW + (size_t)k0*128, KC);
    __syncthreads();
    gemm_chunk(sA + k0, sW, (KC+3)&~3, rg, jc, acc);
  }
}
__device__ __forceinline__ void init_bias(float acc[4][4], const float* b, int jc){
  float4 bb = *(const float4*)(b + 4*jc);
  #pragma unroll
  for(int i=0;i<4;i++){ acc[i][0]=bb.x; acc[i][1]=bb.y; acc[i][2]=bb.z; acc[i][3]=bb.w; }
}

// ---------- embedding (fp32; also writes bf16 hi/lo planes when hPu != 0) ----------
__global__ __launch_bounds__(256) void k_embed(const float* r, const float* v, const float* gf,
    const float* W1, const float* b1, const float* W2, const float* b2, float* h,
    unsigned short* hPu){
  __shared__ __align__(16) float sA[32*AP];
  __shared__ __align__(16) float sW[32*128];
  __shared__ float sGf[12];
  int t = threadIdx.x, n0 = blockIdx.x*32;
  if(t < 12) sGf[t] = gf[t];
  __syncthreads();
  for(int idx = t; idx < 32*20; idx += 256){
    int row = idx/20, c = idx%20;
    int n = n0 + row; if(n >= NNODES) n = NNODES-1;
    float val;
    if(c == 0)      val = r[n];
    else if(c < 7)  val = v[(size_t)n*6 + (c-1)];
    else if(c < 19) val = sGf[c-7];
    else            val = 0.0f;
    sA[row*AP + c] = val;
  }
  int rg = t>>5, jc = t&31;
  float acc[4][4];
  init_bias(acc, b1, jc);
  gemm_phase(sA, sW, W1, 19, rg, jc, acc);
  __syncthreads();
  #pragma unroll
  for(int i=0;i<4;i++){
    float4 x = make_float4(fmaxf(acc[i][0],0.f), fmaxf(acc[i][1],0.f),
                           fmaxf(acc[i][2],0.f), fmaxf(acc[i][3],0.f));
    *(float4*)&sA[(rg*4+i)*AP + 4*jc] = x;
  }
  init_bias(acc, b2, jc);
  gemm_phase(sA, sW, W2, 128, rg, jc, acc);
  #pragma unroll
  for(int i=0;i<4;i++){
    int n = n0 + rg*4 + i;
    if(n < NNODES){
      float4 x = make_float4(fmaxf(acc[i][0],0.f), fmaxf(acc[i][1],0.f),
                             fmaxf(acc[i][2],0.f), fmaxf(acc[i][3],0.f));
      *(float4*)&h[(size_t)n*128 + 4*jc] = x;
      if(hPu){
        unsigned short h0,h1,h2,h3,l0,l1,l2,l3;
        split2(x.x,h0,l0); split2(x.y,h1,l1); split2(x.z,h2,l2); split2(x.w,h3,l3);
        u16x4 hv; hv[0]=h0; hv[1]=h1; hv[2]=h2; hv[3]=h3;
        u16x4 lv; lv[0]=l0; lv[1]=l1; lv[2]=l2; lv[3]=l3;
        *(u16x4*)&hPu[(size_t)n*256 + 4*jc] = hv;
        *(u16x4*)&hPu[(size_t)n*256 + 128 + 4*jc] = lv;
      }
    }
  }
}

// ---------- MFMA edge kernel, 64 edges/block, XCD-swizzled (round-7 proven) ----------
// src term uses hi-plane only (mm2) — halves the random src gather bytes.
__global__ __launch_bounds__(256) void k_msgM2(const int* __restrict__ srcP, const int* __restrict__ dstP,
    const unsigned short* __restrict__ hPu,
    const float* __restrict__ pos, const float* __restrict__ v, const float* __restrict__ r,
    const float* __restrict__ dom,
    const unsigned short* __restrict__ mPdst, const unsigned short* __restrict__ mPsrc,
    const unsigned short* __restrict__ mPedge, const unsigned short* __restrict__ mPw2,
    const float* __restrict__ bb1d, const float* __restrict__ b2, float* __restrict__ agg)
{
  // zH[8192] zL[8192] ushorts (64 rows x 128 cols each, swizzled); reused as fp32 sM[64*128]
  __shared__ __align__(16) unsigned short zBuf[16384];
  __shared__ __align__(16) unsigned short sTh[2048], sTl[2048];
  __shared__ int sSrc[64], sDst[64];
  __shared__ float sDom[3];
  unsigned short* zH = zBuf;
  unsigned short* zL = zBuf + 8192;
  int t = threadIdx.x;
  // bijective XCD swizzle: 4688 blocks = 8 * 586
  int bid = blockIdx.x;
  int swz = (bid & 7)*586 + (bid >> 3);
  int e0 = swz*64;
  int evalid = NEDGES - e0; if(evalid > 64) evalid = 64;
  int w = t>>6, lane = t&63, lr = lane&15, g = lane>>4;
  int nt0 = w*2, nt1 = nt0+1;
  if(t < 64){
    int ee = e0 + t; if(ee >= NEDGES) ee = NEDGES-1;
    sSrc[t] = srcP[ee]; sDst[t] = dstP[ee];
  }
  if(t >= 64 && t < 67) sDom[t-64] = dom[t-64];
  {
    s16x8 zz = {0,0,0,0,0,0,0,0};
    ((s16x8*)sTh)[t] = zz;
    ((s16x8*)sTl)[t] = zz;
  }
  __syncthreads();
  if(t < 64){
    int s = sSrc[t], d = sDst[t];
    float f[11];
    #pragma unroll
    for(int c=0;c<3;c++){
      float dp = pos[(size_t)d*3+c] - pos[(size_t)s*3+c];
      float dm = sDom[c];
      f[c] = dp - dm*rintf(dp/dm);
    }
    #pragma unroll
    for(int c=0;c<6;c++) f[3+c] = v[(size_t)d*6+c] - v[(size_t)s*6+c];
    f[9] = r[d]; f[10] = r[s];
    #pragma unroll
    for(int k=0;k<11;k++){
      unsigned short hh, ll; split2(f[k], hh, ll);
      int byte = t*64 + ((k*2) ^ ((t&3)<<4));
      *(unsigned short*)((char*)sTh + byte) = hh;
      *(unsigned short*)((char*)sTl + byte) = ll;
    }
  }
  float bias0 = bb1d[nt0*16+lr], bias1 = bb1d[nt1*16+lr];
  f32x4 A0[4], A1[4];   // A0[rt] = cols nt0, A1[rt] = cols nt1, rows rt*16+...
  #pragma unroll
  for(int rt=0;rt<4;rt++){
    f32x4 b0 = {bias0,bias0,bias0,bias0};
    f32x4 b1v = {bias1,bias1,bias1,bias1};
    A0[rt] = b0; A1[rt] = b1v;
  }
  __syncthreads();
  // per-lane node row pointers (rows rt*16 + lr)
  const unsigned short* pd[4];
  const unsigned short* ps[4];
  #pragma unroll
  for(int rt=0;rt<4;rt++){
    pd[rt] = hPu + (size_t)sDst[rt*16+lr]*256;
    ps[rt] = hPu + (size_t)sSrc[rt*16+lr]*256;
  }
  int ko = g*8;
  #pragma unroll
  for(int kt=0;kt<4;kt++){
    int o = kt*32 + ko;
    s16x8 DH[4], DL[4], SH[4];
    #pragma unroll
    for(int rt=0;rt<4;rt++){
      DH[rt] = *(const s16x8*)(pd[rt] + o);
      DL[rt] = *(const s16x8*)(pd[rt] + 128 + o);
      SH[rt] = *(const s16x8*)(ps[rt] + o);   // src: hi plane only
    }
    s16x8 bh, bl;
    ld_b(mPdst, kt, nt0, lane, bh, bl);
    #pragma unroll
    for(int rt=0;rt<4;rt++) A0[rt] = mm3(DH[rt], DL[rt], bh, bl, A0[rt]);
    ld_b(mPdst, kt, nt1, lane, bh, bl);
    #pragma unroll
    for(int rt=0;rt<4;rt++) A1[rt] = mm3(DH[rt], DL[rt], bh, bl, A1[rt]);
    ld_b(mPsrc, kt, nt0, lane, bh, bl);
    #pragma unroll
    for(int rt=0;rt<4;rt++) A0[rt] = mm2(SH[rt], bh, bl, A0[rt]);
    ld_b(mPsrc, kt, nt1, lane, bh, bl);
    #pragma unroll
    for(int rt=0;rt<4;rt++) A1[rt] = mm2(SH[rt], bh, bl, A1[rt]);
  }
  {
    s16x8 TH[4], TL[4];
    #pragma unroll
    for(int rt=0;rt<4;rt++){
      TH[rt] = ld_t(sTh, rt*16+lr, g*16);
      TL[rt] = ld_t(sTl, rt*16+lr, g*16);
    }
    s16x8 bh, bl;
    ld_b(mPedge, 0, nt0, lane, bh, bl);
    #pragma unroll
    for(int rt=0;rt<4;rt++) A0[rt] = mm3(TH[rt], TL[rt], bh, bl, A0[rt]);
    ld_b(mPedge, 0, nt1, lane, bh, bl);
    #pragma unroll
    for(int rt=0;rt<4;rt++) A1[rt] = mm3(TH[rt], TL[rt], bh, bl, A1[rt]);
  }
  #pragma unroll
  for(int rt=0;rt<4;rt++){
    #pragma unroll
    for(int i=0;i<4;i++){
      int row = rt*16 + g*4 + i;
      st_z(zH, zL, row, nt0*16+lr, fmaxf(A0[rt][i],0.f));
      st_z(zH, zL, row, nt1*16+lr, fmaxf(A1[rt][i],0.f));
    }
  }
  __syncthreads();
  float c0 = b2[nt0*16+lr], c1 = b2[nt1*16+lr];
  f32x4 M0[4], M1[4];
  #pragma unroll
  for(int rt=0;rt<4;rt++){
    f32x4 b0 = {c0,c0,c0,c0};
    f32x4 b1v = {c1,c1,c1,c1};
    M0[rt] = b0; M1[rt] = b1v;
  }
  #pragma unroll
  for(int kt=0;kt<4;kt++){
    int kb = kt*64 + g*16;
    s16x8 ZHv[4], ZLv[4];
    #pragma unroll
    for(int rt=0;rt<4;rt++){
      ZHv[rt] = ld_z(zH, rt*16+lr, kb);
      ZLv[rt] = ld_z(zL, rt*16+lr, kb);
    }
    s16x8 bh, bl;
    ld_b(mPw2, kt, nt0, lane, bh, bl);
    #pragma unroll
    for(int rt=0;rt<4;rt++) M0[rt] = mm3(ZHv[rt], ZLv[rt], bh, bl, M0[rt]);
    ld_b(mPw2, kt, nt1, lane, bh, bl);
    #pragma unroll
    for(int rt=0;rt<4;rt++) M1[rt] = mm3(ZHv[rt], ZLv[rt], bh, bl, M1[rt]);
  }
  __syncthreads();
  float* sM = (float*)zBuf;
  #pragma unroll
  for(int rt=0;rt<4;rt++){
    #pragma unroll
    for(int i=0;i<4;i++){
      int row = rt*16 + g*4 + i;
      sM[row*128 + nt0*16+lr] = fmaxf(M0[rt][i],0.f);
      sM[row*128 + nt1*16+lr] = fmaxf(M1[rt][i],0.f);
    }
  }
  __syncthreads();
  int col = t & 127, half = t >> 7;
  int rbeg = half*32, rend = rbeg + 32;
  int cur = sDst[rbeg];
  float run = 0.f;
  for(int row = rbeg; row < rend; row++){
    if(row < evalid) run += sM[row*128 + col];
    int nxt = (row+1 < rend) ? sDst[row+1] : -1;
    if(nxt != cur){
      atomicAdd(&agg[(size_t)cur*128 + col], run);
      run = 0.f; cur = nxt;
    }
  }
}

// ---------- MFMA node-update kernel ----------
// h fp32 read replaced by hi+lo reconstruction from hPu; h fp32 written only when writeH.
__global__ __launch_bounds__(256) void k_updM(float* __restrict__ h, unsigned short* __restrict__ hPu,
    float* __restrict__ agg, const int* __restrict__ cnt, const float* __restrict__ muiv,
    const unsigned short* __restrict__ uPh, const unsigned short* __restrict__ uPagg,
    const unsigned short* __restrict__ uPw2,
    const float* __restrict__ ub1d, const float* __restrict__ b2, float* __restrict__ S,
    int writeH)
{
  __shared__ __align__(16) unsigned short zBuf[8192];   // agg planes, then z2 planes
  __shared__ __align__(16) float sH[32*AP];
  __shared__ float sRd[32];
  __shared__ float stS[512], stQ[512];
  unsigned short* zH = zBuf; unsigned short* zL = zBuf + 4096;
  int t = threadIdx.x, n0 = blockIdx.x*32;
  int w = t>>6, lane = t&63, lr = lane&15, g = lane>>4;
  int nt0 = w*2, nt1 = nt0+1;
  if(t < 32){
    int n = n0 + t; if(n >= NNODES) n = NNODES-1;
    sRd[t] = 1.0f / fmaxf((float)cnt[n], 1.0f);
  }
  __syncthreads();
  for(int idx = t; idx < 1024; idx += 256){
    int row = idx>>5, c4 = (idx&31)*4;
    int n = n0 + row; bool valid = (n < NNODES); if(!valid) n = NNODES-1;
    // reconstruct fp32 h from hi/lo planes (no fp32 h read)
    u16x4 hhv = *(const u16x4*)&hPu[(size_t)n*256 + c4];
    u16x4 hlv = *(const u16x4*)&hPu[(size_t)n*256 + 128 + c4];
    float4 hx;
    hx.x = bf_f(hhv[0]) + bf_f(hlv[0]);
    hx.y = bf_f(hhv[1]) + bf_f(hlv[1]);
    hx.z = bf_f(hhv[2]) + bf_f(hlv[2]);
    hx.w = bf_f(hhv[3]) + bf_f(hlv[3]);
    *(float4*)&sH[row*AP + c4] = hx;
    float4 ax = *(const float4*)&agg[(size_t)n*128 + c4];
    float rd = sRd[row];
    ax.x*=rd; ax.y*=rd; ax.z*=rd; ax.w*=rd;
    unsigned short h0,h1,h2,h3,l0,l1,l2,l3;
    split2(ax.x,h0,l0); split2(ax.y,h1,l1); split2(ax.z,h2,l2); split2(ax.w,h3,l3);
    int byte = row*256 + ((c4*2) ^ ((row&7)<<4));
    u16x4 hv; hv[0]=h0; hv[1]=h1; hv[2]=h2; hv[3]=h3;
    u16x4 lv; lv[0]=l0; lv[1]=l1; lv[2]=l2; lv[3]=l3;
    *(u16x4*)((char*)zH + byte) = hv;
    *(u16x4*)((char*)zL + byte) = lv;
    if(valid) *(float4*)&agg[(size_t)n*128 + c4] = make_float4(0.f,0.f,0.f,0.f);
  }
  __syncthreads();
  float bias0 = ub1d[nt0*16+lr], bias1 = ub1d[nt1*16+lr];
  f32x4 a00 = {bias0,bias0,bias0,bias0};
  f32x4 a01 = {bias1,bias1,bias1,bias1};
  f32x4 a10 = a00, a11 = a01;
  int nA0 = n0+lr;    if(nA0 >= NNODES) nA0 = NNODES-1;
  int nA1 = n0+16+lr; if(nA1 >= NNODES) nA1 = NNODES-1;
  const unsigned short* ph0 = hPu + (size_t)nA0*256;
  const unsigned short* ph1 = hPu + (size_t)nA1*256;
  int ko = g*8;
  #pragma unroll
  for(int kt=0;kt<4;kt++){
    int o = kt*32 + ko;
    s16x8 ah0 = *(const s16x8*)(ph0 + o), al0 = *(const s16x8*)(ph0 + 128 + o);
    s16x8 ah1 = *(const s16x8*)(ph1 + o), al1 = *(const s16x8*)(ph1 + 128 + o);
    s16x8 bh, bl;
    ld_b(uPh, kt, nt0, lane, bh, bl);
    a00 = mm3(ah0, al0, bh, bl, a00);
    a10 = mm3(ah1, al1, bh, bl, a10);
    ld_b(uPh, kt, nt1, lane, bh, bl);
    a01 = mm3(ah0, al0, bh, bl, a01);
    a11 = mm3(ah1, al1, bh, bl, a11);
    int kb = kt*64 + g*16;
    s16x8 gh0 = ld_z(zH, lr, kb),    gl0 = ld_z(zL, lr, kb);
    s16x8 gh1 = ld_z(zH, 16+lr, kb), gl1 = ld_z(zL, 16+lr, kb);
    ld_b(uPagg, kt, nt0, lane, bh, bl);
    a00 = mm3(gh0, gl0, bh, bl, a00);
    a10 = mm3(gh1, gl1, bh, bl, a10);
    ld_b(uPagg, kt, nt1, lane, bh, bl);
    a01 = mm3(gh0, gl0, bh, bl, a01);
    a11 = mm3(gh1, gl1, bh, bl, a11);
  }
  __syncthreads();
  #pragma unroll
  for(int i=0;i<4;i++){
    int r0 = g*4+i, r1 = 16+g*4+i;
    st_z(zH, zL, r0, nt0*16+lr, fmaxf(a00[i],0.f));
    st_z(zH, zL, r0, nt1*16+lr, fmaxf(a01[i],0.f));
    st_z(zH, zL, r1, nt0*16+lr, fmaxf(a10[i],0.f));
    st_z(zH, zL, r1, nt1*16+lr, fmaxf(a11[i],0.f));
  }
  __syncthreads();
  float c0 = b2[nt0*16+lr], c1 = b2[nt1*16+lr];
  f32x4 m00 = {c0,c0,c0,c0}, m01 = {c1,c1,c1,c1};
  f32x4 m10 = m00, m11 = m01;
  #pragma unroll
  for(int kt=0;kt<4;kt++){
    int kb = kt*64 + g*16;
    s16x8 ah0 = ld_z(zH, lr, kb),    al0 = ld_z(zL, lr, kb);
    s16x8 ah1 = ld_z(zH, 16+lr, kb), al1 = ld_z(zL, 16+lr, kb);
    s16x8 bh, bl;
    ld_b(uPw2, kt, nt0, lane, bh, bl);
    m00 = mm3(ah0, al0, bh, bl, m00);
    m10 = mm3(ah1, al1, bh, bl, m10);
    ld_b(uPw2, kt, nt1, lane, bh, bl);
    m01 = mm3(ah0, al0, bh, bl, m01);
    m11 = mm3(ah1, al1, bh, bl, m11);
  }
  int col0 = nt0*16+lr, col1 = nt1*16+lr;
  float mu0 = muiv[col0], iv0 = muiv[128+col0];
  float mu1 = muiv[col1], iv1 = muiv[128+col1];
  float s0=0.f,q0=0.f,s1=0.f,q1=0.f;
  #pragma unroll
  for(int tm=0;tm<2;tm++){
    #pragma unroll
    for(int i=0;i<4;i++){
      int row = tm*16 + g*4 + i;
      int n = n0 + row;
      if(n < NNODES){
        float acc0 = (tm==0) ? m00[i] : m10[i];
        float acc1 = (tm==0) ? m01[i] : m11[i];
        float v0 = (sH[row*AP+col0]-mu0)*iv0 + acc0;
        float v1 = (sH[row*AP+col1]-mu1)*iv1 + acc1;
        if(writeH){
          h[(size_t)n*128+col0] = v0;
          h[(size_t)n*128+col1] = v1;
        }
        unsigned short hh,ll;
        split2(v0,hh,ll); hPu[(size_t)n*256+col0]=hh; hPu[(size_t)n*256+128+col0]=ll;
        split2(v1,hh,ll); hPu[(size_t)n*256+col1]=hh; hPu[(size_t)n*256+128+col1]=ll;
        s0+=v0; q0+=v0*v0; s1+=v1; q1+=v1*v1;
      }
    }
  }
  stS[g*128+col0]=s0; stQ[g*128+col0]=q0;
  stS[g*128+col1]=s1; stQ[g*128+col1]=q1;
  __syncthreads();
  if(t < 128){
    float s = stS[t]+stS[128+t]+stS[256+t]+stS[384+t];
    float q = stQ[t]+stQ[128+t]+stQ[256+t]+stQ[384+t];
    atomicAdd(&S[t], s);
    atomicAdd(&S[128 + t], q);
  }
}

// ---------- fallback kernels (fp32 path, kept for smaller workspaces) ----------
__global__ __launch_bounds__(256) void k_pre(const float* h, const float* W1, float* P){
  __shared__ __align__(16) float sA[32*AP];
  __shared__ __align__(16) float sW[32*128];
  int t = threadIdx.x, n0 = blockIdx.x*32;
  for(int idx = t; idx < 1024; idx += 256){
    int row = idx>>5, c4 = (idx&31)*4;
    int n = n0 + row; if(n >= NNODES) n = NNODES-1;
    *(float4*)&sA[row*AP + c4] = *(const float4*)&h[(size_t)n*128 + c4];
  }
  int rg = t>>5, jc = t&31;
  float acc[4][4];
  #pragma unroll
  for(int i=0;i<4;i++){ acc[i][0]=0.f; acc[i][1]=0.f; acc[i][2]=0.f; acc[i][3]=0.f; }
  gemm_phase(sA, sW, W1, 128, rg, jc, acc);
  #pragma unroll
  for(int i=0;i<4;i++){
    int n = n0 + rg*4 + i;
    if(n < NNODES)
      *(float4*)&P[(size_t)n*256 + 4*jc] = make_float4(acc[i][0],acc[i][1],acc[i][2],acc[i][3]);
  }
  #pragma unroll
  for(int i=0;i<4;i++){ acc[i][0]=0.f; acc[i][1]=0.f; acc[i][2]=0.f; acc[i][3]=0.f; }
  gemm_phase(sA, sW, W1 + (size_t)128*128, 128, rg, jc, acc);
  #pragma unroll
  for(int i=0;i<4;i++){
    int n = n0 + rg*4 + i;
    if(n < NNODES)
      *(float4*)&P[(size_t)n*256 + 128 + 4*jc] = make_float4(acc[i][0],acc[i][1],acc[i][2],acc[i][3]);
  }
}

__global__ __launch_bounds__(256) void k_msg2(const int* ei, const float* P,
    const float* pos, const float* v, const float* r, const float* dom,
    const float* W1, const float* W2, const float* bb1, const float* b2, float* agg){
  __shared__ __align__(16) float sM[32*AP];
  __shared__ __align__(16) float sW[32*128];
  __shared__ float sT[32*12];
  __shared__ float sB[128];
  __shared__ int sSrc[32], sDst[32];
  int t = threadIdx.x, e0 = blockIdx.x*32;
  if(t < 32){ sSrc[t] = ei[e0+t]; sDst[t] = ei[NEDGES + e0 + t]; }
  if(t >= 128) sB[t-128] = bb1[t-128];
  __syncthreads();
  for(int idx = t; idx < 352; idx += 256){
    int kk = idx>>5, c4 = (idx&31)*4;
    *(float4*)&sW[kk*128 + c4] = *(const float4*)&W1[(size_t)(256+kk)*128 + c4];
  }
  if(t < 32){
    int s = sSrc[t], d = sDst[t];
    #pragma unroll
    for(int c=0;c<3;c++){
      float dp = pos[(size_t)d*3+c] - pos[(size_t)s*3+c];
      float dm = dom[c];
      dp = dp - dm * rintf(dp/dm);
      sT[t*12 + c] = dp;
    }
    #pragma unroll
    for(int c=0;c<6;c++)
      sT[t*12 + 3 + c] = v[(size_t)d*6+c] - v[(size_t)s*6+c];
    sT[t*12 + 9]  = r[d];
    sT[t*12 + 10] = r[s];
    sT[t*12 + 11] = 0.0f;
  }
  for(int idx = t; idx < 1024; idx += 256){
    int row = idx>>5, c4 = (idx&31)*4;
    float4 pd = *(const float4*)&P[(size_t)sDst[row]*256 + c4];
    float4 ps = *(const float4*)&P[(size_t)sSrc[row]*256 + 128 + c4];
    float4 bb = *(const float4*)&sB[c4];
    *(float4*)&sM[row*AP + c4] = make_float4(bb.x+pd.x+ps.x, bb.y+pd.y+ps.y,
                                             bb.z+pd.z+ps.z, bb.w+pd.w+ps.w);
  }
  __syncthreads();
  int rg = t>>5, jc = t&31;
  float acc[4][4];
  #pragma unroll
  for(int i=0;i<4;i++)
    #pragma unroll
    for(int c=0;c<4;c++) acc[i][c] = sM[(rg*4+i)*AP + 4*jc + c];
  for(int k=0;k<11;k++){
    float4 b = *(const float4*)&sW[k*128 + 4*jc];
    #pragma unroll
    for(int i=0;i<4;i++){
      float a = sT[(rg*4+i)*12 + k];
      acc[i][0] = fmaf(a, b.x, acc[i][0]);
      acc[i][1] = fmaf(a, b.y, acc[i][1]);
      acc[i][2] = fmaf(a, b.z, acc[i][2]);
      acc[i][3] = fmaf(a, b.w, acc[i][3]);
    }
  }
  #pragma unroll
  for(int i=0;i<4;i++){
    float4 x = make_float4(fmaxf(acc[i][0],0.f), fmaxf(acc[i][1],0.f),
                           fmaxf(acc[i][2],0.f), fmaxf(acc[i][3],0.f));
    *(float4*)&sM[(rg*4+i)*AP + 4*jc] = x;
  }
  init_bias(acc, b2, jc);
  gemm_phase(sM, sW, W2, 128, rg, jc, acc);
  #pragma unroll
  for(int i=0;i<4;i++){
    int d = sDst[rg*4+i];
    #pragma unroll
    for(int c=0;c<4;c++)
      atomicAdd(&agg[(size_t)d*128 + 4*jc + c], fmaxf(acc[i][c], 0.0f));
  }
}

__global__ __launch_bounds__(256) void k_upd(float* h, const float* agg, const float* deg,
    const float* gf, const float* W1, const float* b1, const float* W2, const float* b2, int l){
  __shared__ __align__(16) float sA[32*AP];
  __shared__ __align__(16) float sW[32*128];
  __shared__ float sGf[12], sRd[32];
  int t = threadIdx.x, n0 = blockIdx.x*32;
  if(t < 12) sGf[t] = gf[t];
  if(t < 32){
    int n = n0 + t; if(n >= NNODES) n = NNODES-1;
    sRd[t] = 1.0f / fmaxf(deg[n], 1.0f);
  }
  __syncthreads();
  const float* Wl1 = W1 + (size_t)l*34304;
  const float* Wl2 = W2 + (size_t)l*16384;
  const float* bl1 = b1 + l*128;
  const float* bl2 = b2 + l*128;
  int rg = t>>5, jc = t&31;
  float acc[4][4];
  init_bias(acc, bl1, jc);
  for(int idx = t; idx < 1024; idx += 256){
    int row = idx>>5, c4 = (idx&31)*4;
    int n = n0 + row; if(n >= NNODES) n = NNODES-1;
    *(float4*)&sA[row*AP + c4] = *(const float4*)&h[(size_t)n*128 + c4];
  }
  gemm_phase(sA, sW, Wl1, 128, rg, jc, acc);
  __syncthreads();
  for(int idx = t; idx < 1024; idx += 256){
    int row = idx>>5, c4 = (idx&31)*4;
    int n = n0 + row; if(n >= NNODES) n = NNODES-1;
    float4 x = *(const float4*)&agg[(size_t)n*128 + c4];
    float rd = sRd[row];
    x.x*=rd; x.y*=rd; x.z*=rd; x.w*=rd;
    *(float4*)&sA[row*AP + c4] = x;
  }
  gemm_phase(sA, sW, Wl1 + (size_t)128*128, 128, rg, jc, acc);
  __syncthreads();
  if(t < 32){
    #pragma unroll
    for(int c=0;c<12;c++) sA[t*AP + c] = sGf[c];
  }
  gemm_phase(sA, sW, Wl1 + (size_t)256*128, 12, rg, jc, acc);
  __syncthreads();
  #pragma unroll
  for(int i=0;i<4;i++){
    float4 x = make_float4(fmaxf(acc[i][0],0.f), fmaxf(acc[i][1],0.f),
                           fmaxf(acc[i][2],0.f), fmaxf(acc[i][3],0.f));
    *(float4*)&sA[(rg*4+i)*AP + 4*jc] = x;
  }
  init_bias(acc, bl2, jc);
  gemm_phase(sA, sW, Wl2, 128, rg, jc, acc);
  #pragma unroll
  for(int i=0;i<4;i++){
    int n = n0 + rg*4 + i;
    if(n < NNODES){
      float4 x = *(const float4*)&h[(size_t)n*128 + 4*jc];
      x.x += acc[i][0]; x.y += acc[i][1]; x.z += acc[i][2]; x.w += acc[i][3];
      *(float4*)&h[(size_t)n*128 + 4*jc] = x;
    }
  }
}

// ---------- instance-norm stats / norm ----------
__global__ __launch_bounds__(256) void k_stats(const float* h, float* sum, float* sq){
  int col = threadIdx.x & 127, half = threadIdx.x >> 7;
  float s = 0.f, q = 0.f;
  for(int n = blockIdx.x*2 + half; n < NNODES; n += gridDim.x*2){
    float x = h[(size_t)n*128 + col];
    s += x; q += x*x;
  }
  __shared__ float ls[256], lq[256];
  ls[threadIdx.x] = s; lq[threadIdx.x] = q;
  __syncthreads();
  if(half == 0){
    atomicAdd(&sum[col], ls[col] + ls[128+col]);
    atomicAdd(&sq[col],  lq[col] + lq[128+col]);
  }
}

__global__ void k_norm(float* h, const float* sum, const float* sq){
  size_t i = (size_t)blockIdx.x*256 + threadIdx.x;
  if(i < (size_t)NNODES*128){
    int col = i & 127;
    float mean = sum[col] * (1.0f/NNODES);
    float var  = sq[col] * (1.0f/NNODES) - mean*mean;
    if(var < 0.f) var = 0.f;
    h[i] = (h[i] - mean) * rsqrtf(var + 1e-5f);
  }
}

// ---------- output head + epilogue ----------
__global__ __launch_bounds__(256) void k_out(const float* h, const float* pos, const float* v,
    const float* domn, const float* W1, const float* b1, const float* W2, const float* b2,
    float* out){
  __shared__ __align__(16) float sA[32*AP];
  __shared__ __align__(16) float sW[32*128];
  __shared__ float sW2[128*9], sB2[9], sDn[3];
  int t = threadIdx.x, n0 = blockIdx.x*32;
  for(int idx = t; idx < 128*9; idx += 256) sW2[idx] = W2[idx];
  if(t < 9) sB2[t] = b2[t];
  if(t >= 16 && t < 19) sDn[t-16] = domn[t-16];
  for(int idx = t; idx < 1024; idx += 256){
    int row = idx>>5, c4 = (idx&31)*4;
    int n = n0 + row; if(n >= NNODES) n = NNODES-1;
    *(float4*)&sA[row*AP + c4] = *(const float4*)&h[(size_t)n*128 + c4];
  }
  int rg = t>>5, jc = t&31;
  float acc[4][4];
  init_bias(acc, b1, jc);
  gemm_phase(sA, sW, W1, 128, rg, jc, acc);
  __syncthreads();
  #pragma unroll
  for(int i=0;i<4;i++){
    float4 x = make_float4(fmaxf(acc[i][0],0.f), fmaxf(acc[i][1],0.f),
                           fmaxf(acc[i][2],0.f), fmaxf(acc[i][3],0.f));
    *(float4*)&sA[(rg*4+i)*AP + 4*jc] = x;
  }
  __syncthreads();
  for(int idx = t; idx < 32*9; idx += 256){
    int n = idx/9, c = idx%9;
    int gn = n0 + n;
    if(gn < NNODES){
      float s = sB2[c];
      for(int k=0;k<128;k++) s = fmaf(sA[n*AP + k], sW2[k*9 + c], s);
      if(c < 3){
        float p = 0.001f*s + pos[(size_t)gn*3 + c];
        float dn = sDn[c];
        p = p - floorf(p/dn)*dn;
        out[(size_t)gn*3 + c] = p;
      } else {
        float scale = (c < 6) ? 0.001f : 0.01f;
        float p = scale*s + v[(size_t)gn*6 + (c-3)];
        out[(size_t)150000 + (size_t)gn*6 + (c-3)] = p;
      }
    }
  }
}

// ---------- macro head ----------
__global__ __launch_bounds__(128) void k_macro(const float* sum, const float* W1,
    const float* b1, const float* W2, const float* b2, float* out){
  __shared__ float hm[128], t1[128];
  int t = threadIdx.x;
  hm[t] = sum[t] * (1.0f/NNODES);
  __syncthreads();
  float s = b1[t];
  for(int k=0;k<128;k++) s = fmaf(hm[k], W1[(size_t)k*128 + t], s);
  t1[t] = fmaxf(s, 0.0f);
  __syncthreads();
  if(t < 3){
    float o = b2[t];
    for(int k=0;k<128;k++) o = fmaf(t1[k], W2[(size_t)k*3 + t], o);
    out[450000 + t] = o;
  }
}

extern "C" void kernel_launch(void* const* d_in, const int* in_sizes, int n_in,
                              void* d_out, int out_size, void* d_ws, size_t ws_size,
                              hipStream_t stream){
  const float* v    = (const float*)d_in[0];
  const float* pos  = (const float*)d_in[1];
  const float* r    = (const float*)d_in[2];
  const float* dom  = (const float*)d_in[3];
  const float* tt   = (const float*)d_in[4];
  const float* xg   = (const float*)d_in[5];
  const float* domn = (const float*)d_in[6];
  const float* tn   = (const float*)d_in[7];
  const int*   ei   = (const int*)d_in[8];
  const float* embW1=(const float*)d_in[10]; const float* embB1=(const float*)d_in[11];
  const float* embW2=(const float*)d_in[12]; const float* embB2=(const float*)d_in[13];
  const float* msgW1=(const float*)d_in[14]; const float* msgB1=(const float*)d_in[15];
  const float* msgW2=(const float*)d_in[16]; const float* msgB2=(const float*)d_in[17];
  const float* updW1=(const float*)d_in[18]; const float* updB1=(const float*)d_in[19];
  const float* updW2=(const float*)d_in[20]; const float* updB2=(const float*)d_in[21];
  const float* outW1=(const float*)d_in[22]; const float* outB1=(const float*)d_in[23];
  const float* outW2=(const float*)d_in[24]; const float* outB2=(const float*)d_in[25];
  const float* macW1=(const float*)d_in[26]; const float* macB1=(const float*)d_in[27];
  const float* macW2=(const float*)d_in[28]; const float* macB2=(const float*)d_in[29];

  float* ws = (float*)d_ws;
  float* out = (float*)d_out;
  const bool mf = ws_size >= (size_t)105604292;

  if(mf){
    // ---- MFMA path ----
    float* h    = ws;                              // N*128
    float* agg  = ws + (size_t)6400000;            // N*128
    unsigned short* hPu = (unsigned short*)(ws + 12800000);  // N*256 ushort (hi|lo planes)
    float* Sb   = ws + (size_t)19200000;           // 7*256
    float* gf   = ws + (size_t)19201792;
    float* muiv = ws + (size_t)19201808;           // 256
    float* bb1s = ws + (size_t)19202064;           // 768
    float* ub1s = ws + (size_t)19202832;           // 768
    float* bb1d = ws + (size_t)19203600;           // 128
    float* ub1d = ws + (size_t)19203728;           // 128
    int* cnt  = (int*)(ws + 19203856);
    int* off  = (int*)(ws + 19253856);
    int* cur  = (int*)(ws + 19303857);
    int* srcP = (int*)(ws + 19353857);
    int* dstP = (int*)(ws + 19653857);
    unsigned short* mPdst  = (unsigned short*)(ws + 19953860);
    unsigned short* mPsrc  = (unsigned short*)(ws + 19970244);
    unsigned short* uPh    = (unsigned short*)(ws + 19986628);
    unsigned short* mPedge = (unsigned short*)(ws + 20003012);
    unsigned short* mPw2   = (unsigned short*)(ws + 20027588);
    unsigned short* uPagg  = (unsigned short*)(ws + 20125892);
    unsigned short* uPw2   = (unsigned short*)(ws + 20224196);

    k_gf<<<1, 64, 0, stream>>>(dom, tt, xg, domn, tn, gf);
    k_gfb2<<<6, 256, 0, stream>>>(gf, msgW1, msgB1, updW1, updB1, bb1s, ub1s);
    k_packAll<<<624, 64, 0, stream>>>(msgW1, msgW2, updW1, updW2, mPedge, mPw2, uPagg, uPw2);
    hipMemsetAsync(Sb, 0, 7*256*4, stream);
    hipMemsetAsync(agg, 0, (size_t)6400000*4, stream);
    hipMemsetAsync(cnt, 0, (size_t)NNODES*4, stream);
    hipMemsetAsync(cur, 0, (size_t)NNODES*4, stream);
    k_histi<<<(NEDGES+255)/256, 256, 0, stream>>>(ei, cnt);
    k_scan<<<1, 1024, 0, stream>>>(cnt, off);
    k_scatter<<<(NEDGES+255)/256, 256, 0, stream>>>(ei, off, cur, srcP, dstP);
    k_embed<<<(NNODES+31)/32, 256, 0, stream>>>(r, v, gf, embW1, embB1, embW2, embB2, h, hPu);
    for(int l = 0; l < NL; l++){
      k_fold<<<1, 128, 0, stream>>>((l > 0) ? (Sb + (l-1)*256) : Sb, muiv, l);
      k_dynbias<<<2, 128, 0, stream>>>(muiv, bb1s + l*128, ub1s + l*128,
          msgW1 + (size_t)l*35712, updW1 + (size_t)l*34304, bb1d, ub1d);
      k_packDyn<<<96, 64, 0, stream>>>(msgW1 + (size_t)l*35712, updW1 + (size_t)l*34304,
          muiv, mPdst, mPsrc, uPh);
      k_msgM2<<<4688, 256, 0, stream>>>(srcP, dstP, hPu, pos, v, r, dom,
          mPdst, mPsrc, mPedge + (size_t)l*8192, mPw2 + (size_t)l*32768,
          bb1d, msgB2 + l*128, agg);
      k_updM<<<(NNODES+31)/32, 256, 0, stream>>>(h, hPu, agg, cnt, muiv,
          uPh, uPagg + (size_t)l*32768, uPw2 + (size_t)l*32768,
          ub1d, updB2 + l*128, Sb + l*256, (l == NL-1) ? 1 : 0);
    }
    k_norm<<<25000, 256, 0, stream>>>(h, Sb + 5*256, Sb + 5*256 + 128);
    k_stats<<<256, 256, 0, stream>>>(h, Sb + 6*256, Sb + 6*256 + 128);
    k_macro<<<1, 128, 0, stream>>>(Sb + 6*256, macW1, macB1, macW2, macB2, out);
    k_out<<<(NNODES+31)/32, 256, 0, stream>>>(h, pos, v, domn,
                                              outW1, outB1, outW2, outB2, out);
    return;
  }

  // ---- fallback fp32 path (smaller workspace; not expected to run) ----
  float* h   = ws;
  float* agg = ws + (size_t)6400000;
  float* P   = ws + (size_t)12800000;
  float* deg = ws + (size_t)25600000;
  float* gf  = ws + (size_t)25650016;
  float* sum = ws + (size_t)25650048;
  float* sq  = ws + (size_t)25650176;
  float* bb1 = ws + (size_t)25650304;

  k_gf<<<1, 64, 0, stream>>>(dom, tt, xg, domn, tn, gf);
  k_gfb<<<3, 256, 0, stream>>>(gf, msgW1, msgB1, bb1);
  hipMemsetAsync(deg, 0, (size_t)NNODES*4, stream);
  k_deg<<<(NEDGES+255)/256, 256, 0, stream>>>(ei, deg);
  k_embed<<<(NNODES+31)/32, 256, 0, stream>>>(r, v, gf, embW1, embB1, embW2, embB2, h,
                                              (unsigned short*)0);
  for(int l = 0; l < NL; l++){
    hipMemsetAsync(agg, 0, (size_t)6400000*4, stream);
    k_pre<<<(NNODES+31)/32, 256, 0, stream>>>(h, msgW1 + (size_t)l*35712, P);
    k_msg2<<<NEDGES/32, 256, 0, stream>>>(ei, P, pos, v, r, dom,
        msgW1 + (size_t)l*35712, msgW2 + (size_t)l*16384,
        bb1 + l*128, msgB2 + l*128, agg);
    k_upd<<<(NNODES+31)/32, 256, 0, stream>>>(h, agg, deg, gf,
        updW1, updB1, updW2, updB2, l);
    hipMemsetAsync(sum, 0, 128*4, stream);
    hipMemsetAsync(sq,  0, 128*4, stream);
    k_stats<<<256, 256, 0, stream>>>(h, sum, sq);
    k_norm<<<25000, 256, 0, stream>>>(h, sum, sq);
  }
  hipMemsetAsync(sum, 0, 128*4, stream);
  hipMemsetAsync(sq,  0, 128*4, stream);
  k_stats<<<256, 256, 0, stream>>>(h, sum, sq);
  k_macro<<<1, 128, 0, stream>>>(sum, macW1, macB1, macW2, macB2, out);
  k_out<<<(NNODES+31)/32, 256, 0, stream>>>(h, pos, v, domn,
                                            outW1, outB1, outW2, outB2, out);
}

// Round 10
// 1639.964 us; speedup vs baseline: 1.2455x; 1.0454x over previous
//
#include <hip/hip_runtime.h>

#define NNODES 50000
#define NEDGES 300000
#define NL 6
#define AP 132

typedef float f32x4 __attribute__((ext_vector_type(4)));
typedef short s16x8 __attribute__((ext_vector_type(8)));
typedef unsigned short u16x4 __attribute__((ext_vector_type(4)));

#define MFMA(A,B,C) __builtin_amdgcn_mfma_f32_16x16x32_bf16((A),(B),(C),0,0,0)

__device__ __forceinline__ unsigned short bf_hi(float x){
  unsigned u = __float_as_uint(x);
  u += 0x7fffu + ((u>>16)&1u);
  return (unsigned short)(u>>16);
}
__device__ __forceinline__ float bf_f(unsigned short s){
  return __uint_as_float(((unsigned)s)<<16);
}
__device__ __forceinline__ void split2(float x, unsigned short &h, unsigned short &l){
  h = bf_hi(x);
  l = bf_hi(x - bf_f(h));
}

__device__ __forceinline__ f32x4 mm3(s16x8 ah, s16x8 al, s16x8 bh, s16x8 bl, f32x4 c){
  c = MFMA(ah, bh, c);
  c = MFMA(ah, bl, c);
  c = MFMA(al, bh, c);
  return c;
}
// A-hi only (src path): B keeps hi+lo precision
__device__ __forceinline__ f32x4 mm2(s16x8 ah, s16x8 bh, s16x8 bl, f32x4 c){
  c = MFMA(ah, bh, c);
  c = MFMA(ah, bl, c);
  return c;
}

// ---- packed-weight fragment helpers ----
__device__ __forceinline__ void pack_tile(const float* W, int K, const float* iv,
                                          unsigned short* dst, int kt, int nt, int lane){
  int col = nt*16 + (lane&15);
  int k0 = kt*32 + (lane>>4)*8;
  s16x8 hv, lv;
  #pragma unroll
  for(int j=0;j<8;j++){
    int k = k0 + j;
    float x = 0.f;
    if(k < K){
      x = W[(size_t)k*128 + col];
      if(iv) x *= iv[k];
    }
    unsigned short hh, ll; split2(x, hh, ll);
    hv[j] = (short)hh; lv[j] = (short)ll;
  }
  unsigned short* p = dst + ((size_t)((kt<<3)+nt)*64 + lane)*16;
  *(s16x8*)p = hv;
  *(s16x8*)(p+8) = lv;
}
__device__ __forceinline__ void ld_b(const unsigned short* P, int kt, int nt, int lane,
                                     s16x8 &bh, s16x8 &bl){
  const unsigned short* p = P + ((size_t)((kt<<3)+nt)*64 + lane)*16;
  bh = *(const s16x8*)p;
  bl = *(const s16x8*)(p+8);
}
// LDS bf16 plane, pitch 128 ushorts (256B), XOR swizzle (row&7)<<4
__device__ __forceinline__ s16x8 ld_z(const unsigned short* z, int row, int kByte){
  return *(const s16x8*)((const char*)z + row*256 + (kByte ^ ((row&7)<<4)));
}
__device__ __forceinline__ void st_z(unsigned short* zH, unsigned short* zL, int row, int col, float x){
  unsigned short hh, ll; split2(x, hh, ll);
  int byte = row*256 + ((col*2) ^ ((row&7)<<4));
  *(unsigned short*)((char*)zH + byte) = hh;
  *(unsigned short*)((char*)zL + byte) = ll;
}
// LDS bf16 plane, pitch 32 ushorts (64B), XOR swizzle (row&3)<<4 (edge features)
__device__ __forceinline__ s16x8 ld_t(const unsigned short* z, int row, int kByte){
  return *(const s16x8*)((const char*)z + row*64 + (kByte ^ ((row&3)<<4)));
}

// ---------- tiny setup kernels ----------
__global__ void k_gf(const float* dom, const float* t, const float* xg,
                     const float* domn, const float* tn, float* gf){
  int i = threadIdx.x;
  if(i < 3)        gf[i]  = dom[i];
  else if(i == 3)  gf[3]  = t[0];
  else if(i < 8)   gf[i]  = xg[i-4];
  else if(i < 11)  gf[i]  = domn[i-8];
  else if(i == 11) gf[11] = tn[0];
}

__global__ void k_deg(const int* ei, float* deg){
  int e = blockIdx.x*blockDim.x + threadIdx.x;
  if(e < NEDGES) atomicAdd(&deg[ei[NEDGES + e]], 1.0f);
}

__global__ void k_histi(const int* ei, int* cnt){
  int e = blockIdx.x*blockDim.x + threadIdx.x;
  if(e < NEDGES) atomicAdd(&cnt[ei[NEDGES + e]], 1);
}

__global__ __launch_bounds__(1024) void k_scan(const int* cnt, int* off){
  __shared__ int buf[1024];
  __shared__ int carry;
  int t = threadIdx.x;
  if(t == 0) carry = 0;
  __syncthreads();
  for(int base = 0; base < NNODES; base += 1024){
    int i = base + t;
    int x = (i < NNODES) ? cnt[i] : 0;
    buf[t] = x;
    __syncthreads();
    for(int ofs = 1; ofs < 1024; ofs <<= 1){
      int y = (t >= ofs) ? buf[t-ofs] : 0;
      __syncthreads();
      buf[t] += y;
      __syncthreads();
    }
    if(i < NNODES) off[i] = carry + buf[t] - x;
    __syncthreads();
    if(t == 1023) carry += buf[1023];
    __syncthreads();
  }
  if(t == 0) off[NNODES] = carry;
}

__global__ void k_scatter(const int* ei, const int* off, int* cur, int* srcP, int* dstP){
  int e = blockIdx.x*blockDim.x + threadIdx.x;
  if(e < NEDGES){
    int s = ei[e], d = ei[NEDGES + e];
    int p = atomicAdd(&cur[d], 1);
    int ix = off[d] + p;
    srcP[ix] = s; dstP[ix] = d;
  }
}

// old gf-fold (fallback path)
__global__ void k_gfb(const float* gf, const float* mW1, const float* mB1, float* bb1){
  int i = blockIdx.x*256 + threadIdx.x;
  if(i < 768){
    int l = i >> 7, c = i & 127;
    float s = mB1[l*128 + c];
    #pragma unroll
    for(int j=0;j<12;j++) s = fmaf(gf[j], mW1[(size_t)l*35712 + (size_t)(267+j)*128 + c], s);
    bb1[i] = s;
  }
}

// static bias parts: bb1s = msgB1 + gf@msgW1[267:279]; ub1s = updB1 + gf@updW1[256:268]
__global__ void k_gfb2(const float* gf, const float* mW1, const float* mB1,
                       const float* uW1, const float* uB1, float* bb1s, float* ub1s){
  int i = blockIdx.x*256 + threadIdx.x;
  if(i < 768){
    int l = i>>7, c = i&127;
    float s = mB1[l*128+c];
    #pragma unroll
    for(int j=0;j<12;j++) s = fmaf(gf[j], mW1[(size_t)l*35712 + (size_t)(267+j)*128 + c], s);
    bb1s[i] = s;
  } else if(i < 1536){
    int i2 = i-768, l = i2>>7, c = i2&127;
    float s = uB1[l*128+c];
    #pragma unroll
    for(int j=0;j<12;j++) s = fmaf(gf[j], uW1[(size_t)l*34304 + (size_t)(256+j)*128 + c], s);
    ub1s[i2] = s;
  }
}

// ---------- fused per-layer prep: stats->muiv, dynamic biases, iv-scaled packs ----------
// block 0: write muiv global + bb1d; block 1: ub1d; blocks 2..49: pack 2 tiles each (96 tiles)
__global__ __launch_bounds__(128) void k_prep(const float* S, int l,
    const float* msgW1l, const float* updW1l,
    const float* bb1s_l, const float* ub1s_l,
    float* muiv, float* bb1d, float* ub1d,
    unsigned short* mPdst, unsigned short* mPsrc, unsigned short* uPh)
{
  __shared__ float smu[128], siv[128];
  int t = threadIdx.x, b = blockIdx.x;
  {
    float mu, iv;
    if(l == 0){ mu = 0.f; iv = 1.f; }
    else {
      float mean = S[t] * (1.0f/NNODES);
      float var  = S[128+t] * (1.0f/NNODES) - mean*mean;
      if(var < 0.f) var = 0.f;
      mu = mean; iv = rsqrtf(var + 1e-5f);
    }
    smu[t] = mu; siv[t] = iv;
  }
  __syncthreads();
  if(b == 0){
    muiv[t] = smu[t]; muiv[128+t] = siv[t];
    float s = bb1s_l[t];
    for(int k=0;k<128;k++){
      float f = smu[k]*siv[k];
      s -= f*(msgW1l[(size_t)k*128+t] + msgW1l[(size_t)(128+k)*128+t]);
    }
    bb1d[t] = s;
  } else if(b == 1){
    float s = ub1s_l[t];
    for(int k=0;k<128;k++) s -= smu[k]*siv[k]*updW1l[(size_t)k*128+t];
    ub1d[t] = s;
  } else {
    int tt = (b-2)*2 + (t>>6);
    int lane = t&63;
    if(tt < 32)      pack_tile(msgW1l,          128, siv, mPdst, tt>>3, tt&7, lane);
    else if(tt < 64){ int q=tt-32; pack_tile(msgW1l + 16384, 128, siv, mPsrc, q>>3, q&7, lane); }
    else            { int q=tt-64; pack_tile(updW1l,         128, siv, uPh,   q>>3, q&7, lane); }
  }
}

// static packs: msgW2, updW1-agg-half, updW2, msg edge rows
__global__ void k_packAll(const float* msgW1, const float* msgW2,
                          const float* updW1, const float* updW2,
                          unsigned short* mPedge, unsigned short* mPw2,
                          unsigned short* uPagg, unsigned short* uPw2){
  int b = blockIdx.x, lane = threadIdx.x;
  if(b < 192){
    int l=b/32, t=b%32;
    pack_tile(msgW2 + (size_t)l*16384, 128, 0, mPw2 + (size_t)l*32768, t/8, t%8, lane);
  } else if(b < 384){
    int bb=b-192, l=bb/32, t=bb%32;
    pack_tile(updW1 + (size_t)l*34304 + 16384, 128, 0, uPagg + (size_t)l*32768, t/8, t%8, lane);
  } else if(b < 576){
    int bb=b-384, l=bb/32, t=bb%32;
    pack_tile(updW2 + (size_t)l*16384, 128, 0, uPw2 + (size_t)l*32768, t/8, t%8, lane);
  } else {
    int bb=b-576, l=bb/8, nt=bb%8;
    pack_tile(msgW1 + (size_t)l*35712 + 32768, 11, 0, mPedge + (size_t)l*8192, 0, nt, lane);
  }
}

// ---------- shared fp32 GEMM machinery (embed + fallback) ----------
__device__ __forceinline__ void fill_w(float* sW, const float* gW, int KC){
  for(int idx = threadIdx.x; idx < 32*32; idx += 256){
    int kk = idx >> 5, c4 = (idx & 31)*4;
    float4 w = make_float4(0.f,0.f,0.f,0.f);
    if(kk < KC) w = *(const float4*)(gW + (size_t)kk*128 + c4);
    *(float4*)(sW + kk*128 + c4) = w;
  }
}
__device__ __forceinline__ void gemm_chunk(const float* At, const float* sW,
                                           int KCp, int rg, int jc, float acc[4][4]){
  for(int kkg = 0; kkg < KCp; kkg += 4){
    float4 av[4];
    #pragma unroll
    for(int i=0;i<4;i++) av[i] = *(const float4*)(At + (rg*4+i)*AP + kkg);
    #pragma unroll
    for(int q=0;q<4;q++){
      float4 bq = *(const float4*)(sW + (kkg+q)*128 + 4*jc);
      #pragma unroll
      for(int i=0;i<4;i++){
        float aa = ((const float*)&av[i])[q];
        acc[i][0] = fmaf(aa, bq.x, acc[i][0]);
        acc[i][1] = fmaf(aa, bq.y, acc[i][1]);
        acc[i][2] = fmaf(aa, bq.z, acc[i][2]);
        acc[i][3] = fmaf(aa, bq.w, acc[i][3]);
      }
    }
  }
}
__device__ __forceinline__ void gemm_phase(const float* sA, float* sW, const float* gW,
                                           int K, int rg, int jc, float acc[4][4]){
  for(int k0 = 0; k0 < K; k0 += 32){
    int KC = (K - k0 < 32) ? (K - k0) : 32;
    __syncthreads();
    fill_w(sW, gW + (size_t)k0*128, KC);
    __syncthreads();
    gemm_chunk(sA + k0, sW, (KC+3)&~3, rg, jc, acc);
  }
}
__device__ __forceinline__ void init_bias(float acc[4][4], const float* b, int jc){
  float4 bb = *(const float4*)(b + 4*jc);
  #pragma unroll
  for(int i=0;i<4;i++){ acc[i][0]=bb.x; acc[i][1]=bb.y; acc[i][2]=bb.z; acc[i][3]=bb.w; }
}

// ---------- embedding (fp32; also writes bf16 hi/lo planes when hPu != 0) ----------
__global__ __launch_bounds__(256) void k_embed(const float* r, const float* v, const float* gf,
    const float* W1, const float* b1, const float* W2, const float* b2, float* h,
    unsigned short* hPu){
  __shared__ __align__(16) float sA[32*AP];
  __shared__ __align__(16) float sW[32*128];
  __shared__ float sGf[12];
  int t = threadIdx.x, n0 = blockIdx.x*32;
  if(t < 12) sGf[t] = gf[t];
  __syncthreads();
  for(int idx = t; idx < 32*20; idx += 256){
    int row = idx/20, c = idx%20;
    int n = n0 + row; if(n >= NNODES) n = NNODES-1;
    float val;
    if(c == 0)      val = r[n];
    else if(c < 7)  val = v[(size_t)n*6 + (c-1)];
    else if(c < 19) val = sGf[c-7];
    else            val = 0.0f;
    sA[row*AP + c] = val;
  }
  int rg = t>>5, jc = t&31;
  float acc[4][4];
  init_bias(acc, b1, jc);
  gemm_phase(sA, sW, W1, 19, rg, jc, acc);
  __syncthreads();
  #pragma unroll
  for(int i=0;i<4;i++){
    float4 x = make_float4(fmaxf(acc[i][0],0.f), fmaxf(acc[i][1],0.f),
                           fmaxf(acc[i][2],0.f), fmaxf(acc[i][3],0.f));
    *(float4*)&sA[(rg*4+i)*AP + 4*jc] = x;
  }
  init_bias(acc, b2, jc);
  gemm_phase(sA, sW, W2, 128, rg, jc, acc);
  #pragma unroll
  for(int i=0;i<4;i++){
    int n = n0 + rg*4 + i;
    if(n < NNODES){
      float4 x = make_float4(fmaxf(acc[i][0],0.f), fmaxf(acc[i][1],0.f),
                             fmaxf(acc[i][2],0.f), fmaxf(acc[i][3],0.f));
      *(float4*)&h[(size_t)n*128 + 4*jc] = x;
      if(hPu){
        unsigned short h0,h1,h2,h3,l0,l1,l2,l3;
        split2(x.x,h0,l0); split2(x.y,h1,l1); split2(x.z,h2,l2); split2(x.w,h3,l3);
        u16x4 hv; hv[0]=h0; hv[1]=h1; hv[2]=h2; hv[3]=h3;
        u16x4 lv; lv[0]=l0; lv[1]=l1; lv[2]=l2; lv[3]=l3;
        *(u16x4*)&hPu[(size_t)n*256 + 4*jc] = hv;
        *(u16x4*)&hPu[(size_t)n*256 + 128 + 4*jc] = lv;
      }
    }
  }
}

// ---------- MFMA edge kernel, 64 edges/block, XCD-swizzled (round-7 proven) ----------
// src term uses hi-plane only (mm2) — halves the random src gather bytes.
__global__ __launch_bounds__(256) void k_msgM2(const int* __restrict__ srcP, const int* __restrict__ dstP,
    const unsigned short* __restrict__ hPu,
    const float* __restrict__ pos, const float* __restrict__ v, const float* __restrict__ r,
    const float* __restrict__ dom,
    const unsigned short* __restrict__ mPdst, const unsigned short* __restrict__ mPsrc,
    const unsigned short* __restrict__ mPedge, const unsigned short* __restrict__ mPw2,
    const float* __restrict__ bb1d, const float* __restrict__ b2, float* __restrict__ agg)
{
  // zH[8192] zL[8192] ushorts (64 rows x 128 cols each, swizzled); reused as fp32 sM[64*128]
  __shared__ __align__(16) unsigned short zBuf[16384];
  __shared__ __align__(16) unsigned short sTh[2048], sTl[2048];
  __shared__ int sSrc[64], sDst[64];
  __shared__ float sDom[3];
  unsigned short* zH = zBuf;
  unsigned short* zL = zBuf + 8192;
  int t = threadIdx.x;
  // bijective XCD swizzle: 4688 blocks = 8 * 586
  int bid = blockIdx.x;
  int swz = (bid & 7)*586 + (bid >> 3);
  int e0 = swz*64;
  int evalid = NEDGES - e0; if(evalid > 64) evalid = 64;
  int w = t>>6, lane = t&63, lr = lane&15, g = lane>>4;
  int nt0 = w*2, nt1 = nt0+1;
  if(t < 64){
    int ee = e0 + t; if(ee >= NEDGES) ee = NEDGES-1;
    sSrc[t] = srcP[ee]; sDst[t] = dstP[ee];
  }
  if(t >= 64 && t < 67) sDom[t-64] = dom[t-64];
  {
    s16x8 zz = {0,0,0,0,0,0,0,0};
    ((s16x8*)sTh)[t] = zz;
    ((s16x8*)sTl)[t] = zz;
  }
  __syncthreads();
  if(t < 64){
    int s = sSrc[t], d = sDst[t];
    float f[11];
    #pragma unroll
    for(int c=0;c<3;c++){
      float dp = pos[(size_t)d*3+c] - pos[(size_t)s*3+c];
      float dm = sDom[c];
      f[c] = dp - dm*rintf(dp/dm);
    }
    #pragma unroll
    for(int c=0;c<6;c++) f[3+c] = v[(size_t)d*6+c] - v[(size_t)s*6+c];
    f[9] = r[d]; f[10] = r[s];
    #pragma unroll
    for(int k=0;k<11;k++){
      unsigned short hh, ll; split2(f[k], hh, ll);
      int byte = t*64 + ((k*2) ^ ((t&3)<<4));
      *(unsigned short*)((char*)sTh + byte) = hh;
      *(unsigned short*)((char*)sTl + byte) = ll;
    }
  }
  float bias0 = bb1d[nt0*16+lr], bias1 = bb1d[nt1*16+lr];
  f32x4 A0[4], A1[4];   // A0[rt] = cols nt0, A1[rt] = cols nt1, rows rt*16+...
  #pragma unroll
  for(int rt=0;rt<4;rt++){
    f32x4 b0 = {bias0,bias0,bias0,bias0};
    f32x4 b1v = {bias1,bias1,bias1,bias1};
    A0[rt] = b0; A1[rt] = b1v;
  }
  __syncthreads();
  // per-lane node row pointers (rows rt*16 + lr)
  const unsigned short* pd[4];
  const unsigned short* ps[4];
  #pragma unroll
  for(int rt=0;rt<4;rt++){
    pd[rt] = hPu + (size_t)sDst[rt*16+lr]*256;
    ps[rt] = hPu + (size_t)sSrc[rt*16+lr]*256;
  }
  int ko = g*8;
  #pragma unroll
  for(int kt=0;kt<4;kt++){
    int o = kt*32 + ko;
    s16x8 DH[4], DL[4], SH[4];
    #pragma unroll
    for(int rt=0;rt<4;rt++){
      DH[rt] = *(const s16x8*)(pd[rt] + o);
      DL[rt] = *(const s16x8*)(pd[rt] + 128 + o);
      SH[rt] = *(const s16x8*)(ps[rt] + o);   // src: hi plane only
    }
    s16x8 bh, bl;
    ld_b(mPdst, kt, nt0, lane, bh, bl);
    #pragma unroll
    for(int rt=0;rt<4;rt++) A0[rt] = mm3(DH[rt], DL[rt], bh, bl, A0[rt]);
    ld_b(mPdst, kt, nt1, lane, bh, bl);
    #pragma unroll
    for(int rt=0;rt<4;rt++) A1[rt] = mm3(DH[rt], DL[rt], bh, bl, A1[rt]);
    ld_b(mPsrc, kt, nt0, lane, bh, bl);
    #pragma unroll
    for(int rt=0;rt<4;rt++) A0[rt] = mm2(SH[rt], bh, bl, A0[rt]);
    ld_b(mPsrc, kt, nt1, lane, bh, bl);
    #pragma unroll
    for(int rt=0;rt<4;rt++) A1[rt] = mm2(SH[rt], bh, bl, A1[rt]);
  }
  {
    s16x8 TH[4], TL[4];
    #pragma unroll
    for(int rt=0;rt<4;rt++){
      TH[rt] = ld_t(sTh, rt*16+lr, g*16);
      TL[rt] = ld_t(sTl, rt*16+lr, g*16);
    }
    s16x8 bh, bl;
    ld_b(mPedge, 0, nt0, lane, bh, bl);
    #pragma unroll
    for(int rt=0;rt<4;rt++) A0[rt] = mm3(TH[rt], TL[rt], bh, bl, A0[rt]);
    ld_b(mPedge, 0, nt1, lane, bh, bl);
    #pragma unroll
    for(int rt=0;rt<4;rt++) A1[rt] = mm3(TH[rt], TL[rt], bh, bl, A1[rt]);
  }
  #pragma unroll
  for(int rt=0;rt<4;rt++){
    #pragma unroll
    for(int i=0;i<4;i++){
      int row = rt*16 + g*4 + i;
      st_z(zH, zL, row, nt0*16+lr, fmaxf(A0[rt][i],0.f));
      st_z(zH, zL, row, nt1*16+lr, fmaxf(A1[rt][i],0.f));
    }
  }
  __syncthreads();
  float c0 = b2[nt0*16+lr], c1 = b2[nt1*16+lr];
  f32x4 M0[4], M1[4];
  #pragma unroll
  for(int rt=0;rt<4;rt++){
    f32x4 b0 = {c0,c0,c0,c0};
    f32x4 b1v = {c1,c1,c1,c1};
    M0[rt] = b0; M1[rt] = b1v;
  }
  #pragma unroll
  for(int kt=0;kt<4;kt++){
    int kb = kt*64 + g*16;
    s16x8 ZHv[4], ZLv[4];
    #pragma unroll
    for(int rt=0;rt<4;rt++){
      ZHv[rt] = ld_z(zH, rt*16+lr, kb);
      ZLv[rt] = ld_z(zL, rt*16+lr, kb);
    }
    s16x8 bh, bl;
    ld_b(mPw2, kt, nt0, lane, bh, bl);
    #pragma unroll
    for(int rt=0;rt<4;rt++) M0[rt] = mm3(ZHv[rt], ZLv[rt], bh, bl, M0[rt]);
    ld_b(mPw2, kt, nt1, lane, bh, bl);
    #pragma unroll
    for(int rt=0;rt<4;rt++) M1[rt] = mm3(ZHv[rt], ZLv[rt], bh, bl, M1[rt]);
  }
  __syncthreads();
  float* sM = (float*)zBuf;
  #pragma unroll
  for(int rt=0;rt<4;rt++){
    #pragma unroll
    for(int i=0;i<4;i++){
      int row = rt*16 + g*4 + i;
      sM[row*128 + nt0*16+lr] = fmaxf(M0[rt][i],0.f);
      sM[row*128 + nt1*16+lr] = fmaxf(M1[rt][i],0.f);
    }
  }
  __syncthreads();
  int col = t & 127, half = t >> 7;
  int rbeg = half*32, rend = rbeg + 32;
  int cur = sDst[rbeg];
  float run = 0.f;
  for(int row = rbeg; row < rend; row++){
    if(row < evalid) run += sM[row*128 + col];
    int nxt = (row+1 < rend) ? sDst[row+1] : -1;
    if(nxt != cur){
      atomicAdd(&agg[(size_t)cur*128 + col], run);
      run = 0.f; cur = nxt;
    }
  }
}

// ---------- MFMA node-update kernel ----------
// h fp32 read replaced by hi+lo reconstruction from hPu; h fp32 written only when writeH.
__global__ __launch_bounds__(256) void k_updM(float* __restrict__ h, unsigned short* __restrict__ hPu,
    float* __restrict__ agg, const int* __restrict__ cnt, const float* __restrict__ muiv,
    const unsigned short* __restrict__ uPh, const unsigned short* __restrict__ uPagg,
    const unsigned short* __restrict__ uPw2,
    const float* __restrict__ ub1d, const float* __restrict__ b2, float* __restrict__ S,
    int writeH)
{
  __shared__ __align__(16) unsigned short zBuf[8192];   // agg planes, then z2 planes
  __shared__ __align__(16) float sH[32*AP];
  __shared__ float sRd[32];
  __shared__ float stS[512], stQ[512];
  unsigned short* zH = zBuf; unsigned short* zL = zBuf + 4096;
  int t = threadIdx.x, n0 = blockIdx.x*32;
  int w = t>>6, lane = t&63, lr = lane&15, g = lane>>4;
  int nt0 = w*2, nt1 = nt0+1;
  if(t < 32){
    int n = n0 + t; if(n >= NNODES) n = NNODES-1;
    sRd[t] = 1.0f / fmaxf((float)cnt[n], 1.0f);
  }
  __syncthreads();
  for(int idx = t; idx < 1024; idx += 256){
    int row = idx>>5, c4 = (idx&31)*4;
    int n = n0 + row; bool valid = (n < NNODES); if(!valid) n = NNODES-1;
    // reconstruct fp32 h from hi/lo planes (no fp32 h read)
    u16x4 hhv = *(const u16x4*)&hPu[(size_t)n*256 + c4];
    u16x4 hlv = *(const u16x4*)&hPu[(size_t)n*256 + 128 + c4];
    float4 hx;
    hx.x = bf_f(hhv[0]) + bf_f(hlv[0]);
    hx.y = bf_f(hhv[1]) + bf_f(hlv[1]);
    hx.z = bf_f(hhv[2]) + bf_f(hlv[2]);
    hx.w = bf_f(hhv[3]) + bf_f(hlv[3]);
    *(float4*)&sH[row*AP + c4] = hx;
    float4 ax = *(const float4*)&agg[(size_t)n*128 + c4];
    float rd = sRd[row];
    ax.x*=rd; ax.y*=rd; ax.z*=rd; ax.w*=rd;
    unsigned short h0,h1,h2,h3,l0,l1,l2,l3;
    split2(ax.x,h0,l0); split2(ax.y,h1,l1); split2(ax.z,h2,l2); split2(ax.w,h3,l3);
    int byte = row*256 + ((c4*2) ^ ((row&7)<<4));
    u16x4 hv; hv[0]=h0; hv[1]=h1; hv[2]=h2; hv[3]=h3;
    u16x4 lv; lv[0]=l0; lv[1]=l1; lv[2]=l2; lv[3]=l3;
    *(u16x4*)((char*)zH + byte) = hv;
    *(u16x4*)((char*)zL + byte) = lv;
    if(valid) *(float4*)&agg[(size_t)n*128 + c4] = make_float4(0.f,0.f,0.f,0.f);
  }
  __syncthreads();
  float bias0 = ub1d[nt0*16+lr], bias1 = ub1d[nt1*16+lr];
  f32x4 a00 = {bias0,bias0,bias0,bias0};
  f32x4 a01 = {bias1,bias1,bias1,bias1};
  f32x4 a10 = a00, a11 = a01;
  int nA0 = n0+lr;    if(nA0 >= NNODES) nA0 = NNODES-1;
  int nA1 = n0+16+lr; if(nA1 >= NNODES) nA1 = NNODES-1;
  const unsigned short* ph0 = hPu + (size_t)nA0*256;
  const unsigned short* ph1 = hPu + (size_t)nA1*256;
  int ko = g*8;
  #pragma unroll
  for(int kt=0;kt<4;kt++){
    int o = kt*32 + ko;
    s16x8 ah0 = *(const s16x8*)(ph0 + o), al0 = *(const s16x8*)(ph0 + 128 + o);
    s16x8 ah1 = *(const s16x8*)(ph1 + o), al1 = *(const s16x8*)(ph1 + 128 + o);
    s16x8 bh, bl;
    ld_b(uPh, kt, nt0, lane, bh, bl);
    a00 = mm3(ah0, al0, bh, bl, a00);
    a10 = mm3(ah1, al1, bh, bl, a10);
    ld_b(uPh, kt, nt1, lane, bh, bl);
    a01 = mm3(ah0, al0, bh, bl, a01);
    a11 = mm3(ah1, al1, bh, bl, a11);
    int kb = kt*64 + g*16;
    s16x8 gh0 = ld_z(zH, lr, kb),    gl0 = ld_z(zL, lr, kb);
    s16x8 gh1 = ld_z(zH, 16+lr, kb), gl1 = ld_z(zL, 16+lr, kb);
    ld_b(uPagg, kt, nt0, lane, bh, bl);
    a00 = mm3(gh0, gl0, bh, bl, a00);
    a10 = mm3(gh1, gl1, bh, bl, a10);
    ld_b(uPagg, kt, nt1, lane, bh, bl);
    a01 = mm3(gh0, gl0, bh, bl, a01);
    a11 = mm3(gh1, gl1, bh, bl, a11);
  }
  __syncthreads();
  #pragma unroll
  for(int i=0;i<4;i++){
    int r0 = g*4+i, r1 = 16+g*4+i;
    st_z(zH, zL, r0, nt0*16+lr, fmaxf(a00[i],0.f));
    st_z(zH, zL, r0, nt1*16+lr, fmaxf(a01[i],0.f));
    st_z(zH, zL, r1, nt0*16+lr, fmaxf(a10[i],0.f));
    st_z(zH, zL, r1, nt1*16+lr, fmaxf(a11[i],0.f));
  }
  __syncthreads();
  float c0 = b2[nt0*16+lr], c1 = b2[nt1*16+lr];
  f32x4 m00 = {c0,c0,c0,c0}, m01 = {c1,c1,c1,c1};
  f32x4 m10 = m00, m11 = m01;
  #pragma unroll
  for(int kt=0;kt<4;kt++){
    int kb = kt*64 + g*16;
    s16x8 ah0 = ld_z(zH, lr, kb),    al0 = ld_z(zL, lr, kb);
    s16x8 ah1 = ld_z(zH, 16+lr, kb), al1 = ld_z(zL, 16+lr, kb);
    s16x8 bh, bl;
    ld_b(uPw2, kt, nt0, lane, bh, bl);
    m00 = mm3(ah0, al0, bh, bl, m00);
    m10 = mm3(ah1, al1, bh, bl, m10);
    ld_b(uPw2, kt, nt1, lane, bh, bl);
    m01 = mm3(ah0, al0, bh, bl, m01);
    m11 = mm3(ah1, al1, bh, bl, m11);
  }
  int col0 = nt0*16+lr, col1 = nt1*16+lr;
  float mu0 = muiv[col0], iv0 = muiv[128+col0];
  float mu1 = muiv[col1], iv1 = muiv[128+col1];
  float s0=0.f,q0=0.f,s1=0.f,q1=0.f;
  #pragma unroll
  for(int tm=0;tm<2;tm++){
    #pragma unroll
    for(int i=0;i<4;i++){
      int row = tm*16 + g*4 + i;
      int n = n0 + row;
      if(n < NNODES){
        float acc0 = (tm==0) ? m00[i] : m10[i];
        float acc1 = (tm==0) ? m01[i] : m11[i];
        float v0 = (sH[row*AP+col0]-mu0)*iv0 + acc0;
        float v1 = (sH[row*AP+col1]-mu1)*iv1 + acc1;
        if(writeH){
          h[(size_t)n*128+col0] = v0;
          h[(size_t)n*128+col1] = v1;
        }
        unsigned short hh,ll;
        split2(v0,hh,ll); hPu[(size_t)n*256+col0]=hh; hPu[(size_t)n*256+128+col0]=ll;
        split2(v1,hh,ll); hPu[(size_t)n*256+col1]=hh; hPu[(size_t)n*256+128+col1]=ll;
        s0+=v0; q0+=v0*v0; s1+=v1; q1+=v1*v1;
      }
    }
  }
  stS[g*128+col0]=s0; stQ[g*128+col0]=q0;
  stS[g*128+col1]=s1; stQ[g*128+col1]=q1;
  __syncthreads();
  if(t < 128){
    float s = stS[t]+stS[128+t]+stS[256+t]+stS[384+t];
    float q = stQ[t]+stQ[128+t]+stQ[256+t]+stQ[384+t];
    atomicAdd(&S[t], s);
    atomicAdd(&S[128 + t], q);
  }
}

// ---------- fallback kernels (fp32 path, kept for smaller workspaces) ----------
__global__ __launch_bounds__(256) void k_pre(const float* h, const float* W1, float* P){
  __shared__ __align__(16) float sA[32*AP];
  __shared__ __align__(16) float sW[32*128];
  int t = threadIdx.x, n0 = blockIdx.x*32;
  for(int idx = t; idx < 1024; idx += 256){
    int row = idx>>5, c4 = (idx&31)*4;
    int n = n0 + row; if(n >= NNODES) n = NNODES-1;
    *(float4*)&sA[row*AP + c4] = *(const float4*)&h[(size_t)n*128 + c4];
  }
  int rg = t>>5, jc = t&31;
  float acc[4][4];
  #pragma unroll
  for(int i=0;i<4;i++){ acc[i][0]=0.f; acc[i][1]=0.f; acc[i][2]=0.f; acc[i][3]=0.f; }
  gemm_phase(sA, sW, W1, 128, rg, jc, acc);
  #pragma unroll
  for(int i=0;i<4;i++){
    int n = n0 + rg*4 + i;
    if(n < NNODES)
      *(float4*)&P[(size_t)n*256 + 4*jc] = make_float4(acc[i][0],acc[i][1],acc[i][2],acc[i][3]);
  }
  #pragma unroll
  for(int i=0;i<4;i++){ acc[i][0]=0.f; acc[i][1]=0.f; acc[i][2]=0.f; acc[i][3]=0.f; }
  gemm_phase(sA, sW, W1 + (size_t)128*128, 128, rg, jc, acc);
  #pragma unroll
  for(int i=0;i<4;i++){
    int n = n0 + rg*4 + i;
    if(n < NNODES)
      *(float4*)&P[(size_t)n*256 + 128 + 4*jc] = make_float4(acc[i][0],acc[i][1],acc[i][2],acc[i][3]);
  }
}

__global__ __launch_bounds__(256) void k_msg2(const int* ei, const float* P,
    const float* pos, const float* v, const float* r, const float* dom,
    const float* W1, const float* W2, const float* bb1, const float* b2, float* agg){
  __shared__ __align__(16) float sM[32*AP];
  __shared__ __align__(16) float sW[32*128];
  __shared__ float sT[32*12];
  __shared__ float sB[128];
  __shared__ int sSrc[32], sDst[32];
  int t = threadIdx.x, e0 = blockIdx.x*32;
  if(t < 32){ sSrc[t] = ei[e0+t]; sDst[t] = ei[NEDGES + e0 + t]; }
  if(t >= 128) sB[t-128] = bb1[t-128];
  __syncthreads();
  for(int idx = t; idx < 352; idx += 256){
    int kk = idx>>5, c4 = (idx&31)*4;
    *(float4*)&sW[kk*128 + c4] = *(const float4*)&W1[(size_t)(256+kk)*128 + c4];
  }
  if(t < 32){
    int s = sSrc[t], d = sDst[t];
    #pragma unroll
    for(int c=0;c<3;c++){
      float dp = pos[(size_t)d*3+c] - pos[(size_t)s*3+c];
      float dm = dom[c];
      dp = dp - dm * rintf(dp/dm);
      sT[t*12 + c] = dp;
    }
    #pragma unroll
    for(int c=0;c<6;c++)
      sT[t*12 + 3 + c] = v[(size_t)d*6+c] - v[(size_t)s*6+c];
    sT[t*12 + 9]  = r[d];
    sT[t*12 + 10] = r[s];
    sT[t*12 + 11] = 0.0f;
  }
  for(int idx = t; idx < 1024; idx += 256){
    int row = idx>>5, c4 = (idx&31)*4;
    float4 pd = *(const float4*)&P[(size_t)sDst[row]*256 + c4];
    float4 ps = *(const float4*)&P[(size_t)sSrc[row]*256 + 128 + c4];
    float4 bb = *(const float4*)&sB[c4];
    *(float4*)&sM[row*AP + c4] = make_float4(bb.x+pd.x+ps.x, bb.y+pd.y+ps.y,
                                             bb.z+pd.z+ps.z, bb.w+pd.w+ps.w);
  }
  __syncthreads();
  int rg = t>>5, jc = t&31;
  float acc[4][4];
  #pragma unroll
  for(int i=0;i<4;i++)
    #pragma unroll
    for(int c=0;c<4;c++) acc[i][c] = sM[(rg*4+i)*AP + 4*jc + c];
  for(int k=0;k<11;k++){
    float4 b = *(const float4*)&sW[k*128 + 4*jc];
    #pragma unroll
    for(int i=0;i<4;i++){
      float a = sT[(rg*4+i)*12 + k];
      acc[i][0] = fmaf(a, b.x, acc[i][0]);
      acc[i][1] = fmaf(a, b.y, acc[i][1]);
      acc[i][2] = fmaf(a, b.z, acc[i][2]);
      acc[i][3] = fmaf(a, b.w, acc[i][3]);
    }
  }
  #pragma unroll
  for(int i=0;i<4;i++){
    float4 x = make_float4(fmaxf(acc[i][0],0.f), fmaxf(acc[i][1],0.f),
                           fmaxf(acc[i][2],0.f), fmaxf(acc[i][3],0.f));
    *(float4*)&sM[(rg*4+i)*AP + 4*jc] = x;
  }
  init_bias(acc, b2, jc);
  gemm_phase(sM, sW, W2, 128, rg, jc, acc);
  #pragma unroll
  for(int i=0;i<4;i++){
    int d = sDst[rg*4+i];
    #pragma unroll
    for(int c=0;c<4;c++)
      atomicAdd(&agg[(size_t)d*128 + 4*jc + c], fmaxf(acc[i][c], 0.0f));
  }
}

__global__ __launch_bounds__(256) void k_upd(float* h, const float* agg, const float* deg,
    const float* gf, const float* W1, const float* b1, const float* W2, const float* b2, int l){
  __shared__ __align__(16) float sA[32*AP];
  __shared__ __align__(16) float sW[32*128];
  __shared__ float sGf[12], sRd[32];
  int t = threadIdx.x, n0 = blockIdx.x*32;
  if(t < 12) sGf[t] = gf[t];
  if(t < 32){
    int n = n0 + t; if(n >= NNODES) n = NNODES-1;
    sRd[t] = 1.0f / fmaxf(deg[n], 1.0f);
  }
  __syncthreads();
  const float* Wl1 = W1 + (size_t)l*34304;
  const float* Wl2 = W2 + (size_t)l*16384;
  const float* bl1 = b1 + l*128;
  const float* bl2 = b2 + l*128;
  int rg = t>>5, jc = t&31;
  float acc[4][4];
  init_bias(acc, bl1, jc);
  for(int idx = t; idx < 1024; idx += 256){
    int row = idx>>5, c4 = (idx&31)*4;
    int n = n0 + row; if(n >= NNODES) n = NNODES-1;
    *(float4*)&sA[row*AP + c4] = *(const float4*)&h[(size_t)n*128 + c4];
  }
  gemm_phase(sA, sW, Wl1, 128, rg, jc, acc);
  __syncthreads();
  for(int idx = t; idx < 1024; idx += 256){
    int row = idx>>5, c4 = (idx&31)*4;
    int n = n0 + row; if(n >= NNODES) n = NNODES-1;
    float4 x = *(const float4*)&agg[(size_t)n*128 + c4];
    float rd = sRd[row];
    x.x*=rd; x.y*=rd; x.z*=rd; x.w*=rd;
    *(float4*)&sA[row*AP + c4] = x;
  }
  gemm_phase(sA, sW, Wl1 + (size_t)128*128, 128, rg, jc, acc);
  __syncthreads();
  if(t < 32){
    #pragma unroll
    for(int c=0;c<12;c++) sA[t*AP + c] = sGf[c];
  }
  gemm_phase(sA, sW, Wl1 + (size_t)256*128, 12, rg, jc, acc);
  __syncthreads();
  #pragma unroll
  for(int i=0;i<4;i++){
    float4 x = make_float4(fmaxf(acc[i][0],0.f), fmaxf(acc[i][1],0.f),
                           fmaxf(acc[i][2],0.f), fmaxf(acc[i][3],0.f));
    *(float4*)&sA[(rg*4+i)*AP + 4*jc] = x;
  }
  init_bias(acc, bl2, jc);
  gemm_phase(sA, sW, Wl2, 128, rg, jc, acc);
  #pragma unroll
  for(int i=0;i<4;i++){
    int n = n0 + rg*4 + i;
    if(n < NNODES){
      float4 x = *(const float4*)&h[(size_t)n*128 + 4*jc];
      x.x += acc[i][0]; x.y += acc[i][1]; x.z += acc[i][2]; x.w += acc[i][3];
      *(float4*)&h[(size_t)n*128 + 4*jc] = x;
    }
  }
}

// ---------- instance-norm stats / norm (fallback) ----------
__global__ __launch_bounds__(256) void k_stats(const float* h, float* sum, float* sq){
  int col = threadIdx.x & 127, half = threadIdx.x >> 7;
  float s = 0.f, q = 0.f;
  for(int n = blockIdx.x*2 + half; n < NNODES; n += gridDim.x*2){
    float x = h[(size_t)n*128 + col];
    s += x; q += x*x;
  }
  __shared__ float ls[256], lq[256];
  ls[threadIdx.x] = s; lq[threadIdx.x] = q;
  __syncthreads();
  if(half == 0){
    atomicAdd(&sum[col], ls[col] + ls[128+col]);
    atomicAdd(&sq[col],  lq[col] + lq[128+col]);
  }
}

__global__ void k_norm(float* h, const float* sum, const float* sq){
  size_t i = (size_t)blockIdx.x*256 + threadIdx.x;
  if(i < (size_t)NNODES*128){
    int col = i & 127;
    float mean = sum[col] * (1.0f/NNODES);
    float var  = sq[col] * (1.0f/NNODES) - mean*mean;
    if(var < 0.f) var = 0.f;
    h[i] = (h[i] - mean) * rsqrtf(var + 1e-5f);
  }
}

// fused: normalize h in place using (sum,sq) stats AND accumulate column sums for macro head
__global__ __launch_bounds__(256) void k_normstats(float* h, const float* sum, const float* sq,
                                                   float* S2){
  int col = threadIdx.x & 127, half = threadIdx.x >> 7;
  float mean = sum[col] * (1.0f/NNODES);
  float var  = sq[col] * (1.0f/NNODES) - mean*mean;
  if(var < 0.f) var = 0.f;
  float iv = rsqrtf(var + 1e-5f);
  float s = 0.f;
  for(int n = blockIdx.x*2 + half; n < NNODES; n += gridDim.x*2){
    float x = (h[(size_t)n*128 + col] - mean) * iv;
    h[(size_t)n*128 + col] = x;
    s += x;
  }
  __shared__ float ls[256];
  ls[threadIdx.x] = s;
  __syncthreads();
  if(half == 0)
    atomicAdd(&S2[col], ls[col] + ls[128+col]);
}

// ---------- output head + epilogue ----------
__global__ __launch_bounds__(256) void k_out(const float* h, const float* pos, const float* v,
    const float* domn, const float* W1, const float* b1, const float* W2, const float* b2,
    float* out){
  __shared__ __align__(16) float sA[32*AP];
  __shared__ __align__(16) float sW[32*128];
  __shared__ float sW2[128*9], sB2[9], sDn[3];
  int t = threadIdx.x, n0 = blockIdx.x*32;
  for(int idx = t; idx < 128*9; idx += 256) sW2[idx] = W2[idx];
  if(t < 9) sB2[t] = b2[t];
  if(t >= 16 && t < 19) sDn[t-16] = domn[t-16];
  for(int idx = t; idx < 1024; idx += 256){
    int row = idx>>5, c4 = (idx&31)*4;
    int n = n0 + row; if(n >= NNODES) n = NNODES-1;
    *(float4*)&sA[row*AP + c4] = *(const float4*)&h[(size_t)n*128 + c4];
  }
  int rg = t>>5, jc = t&31;
  float acc[4][4];
  init_bias(acc, b1, jc);
  gemm_phase(sA, sW, W1, 128, rg, jc, acc);
  __syncthreads();
  #pragma unroll
  for(int i=0;i<4;i++){
    float4 x = make_float4(fmaxf(acc[i][0],0.f), fmaxf(acc[i][1],0.f),
                           fmaxf(acc[i][2],0.f), fmaxf(acc[i][3],0.f));
    *(float4*)&sA[(rg*4+i)*AP + 4*jc] = x;
  }
  __syncthreads();
  for(int idx = t; idx < 32*9; idx += 256){
    int n = idx/9, c = idx%9;
    int gn = n0 + n;
    if(gn < NNODES){
      float s = sB2[c];
      for(int k=0;k<128;k++) s = fmaf(sA[n*AP + k], sW2[k*9 + c], s);
      if(c < 3){
        float p = 0.001f*s + pos[(size_t)gn*3 + c];
        float dn = sDn[c];
        p = p - floorf(p/dn)*dn;
        out[(size_t)gn*3 + c] = p;
      } else {
        float scale = (c < 6) ? 0.001f : 0.01f;
        float p = scale*s + v[(size_t)gn*6 + (c-3)];
        out[(size_t)150000 + (size_t)gn*6 + (c-3)] = p;
      }
    }
  }
}

// ---------- macro head ----------
__global__ __launch_bounds__(128) void k_macro(const float* sum, const float* W1,
    const float* b1, const float* W2, const float* b2, float* out){
  __shared__ float hm[128], t1[128];
  int t = threadIdx.x;
  hm[t] = sum[t] * (1.0f/NNODES);
  __syncthreads();
  float s = b1[t];
  for(int k=0;k<128;k++) s = fmaf(hm[k], W1[(size_t)k*128 + t], s);
  t1[t] = fmaxf(s, 0.0f);
  __syncthreads();
  if(t < 3){
    float o = b2[t];
    for(int k=0;k<128;k++) o = fmaf(t1[k], W2[(size_t)k*3 + t], o);
    out[450000 + t] = o;
  }
}

extern "C" void kernel_launch(void* const* d_in, const int* in_sizes, int n_in,
                              void* d_out, int out_size, void* d_ws, size_t ws_size,
                              hipStream_t stream){
  const float* v    = (const float*)d_in[0];
  const float* pos  = (const float*)d_in[1];
  const float* r    = (const float*)d_in[2];
  const float* dom  = (const float*)d_in[3];
  const float* tt   = (const float*)d_in[4];
  const float* xg   = (const float*)d_in[5];
  const float* domn = (const float*)d_in[6];
  const float* tn   = (const float*)d_in[7];
  const int*   ei   = (const int*)d_in[8];
  const float* embW1=(const float*)d_in[10]; const float* embB1=(const float*)d_in[11];
  const float* embW2=(const float*)d_in[12]; const float* embB2=(const float*)d_in[13];
  const float* msgW1=(const float*)d_in[14]; const float* msgB1=(const float*)d_in[15];
  const float* msgW2=(const float*)d_in[16]; const float* msgB2=(const float*)d_in[17];
  const float* updW1=(const float*)d_in[18]; const float* updB1=(const float*)d_in[19];
  const float* updW2=(const float*)d_in[20]; const float* updB2=(const float*)d_in[21];
  const float* outW1=(const float*)d_in[22]; const float* outB1=(const float*)d_in[23];
  const float* outW2=(const float*)d_in[24]; const float* outB2=(const float*)d_in[25];
  const float* macW1=(const float*)d_in[26]; const float* macB1=(const float*)d_in[27];
  const float* macW2=(const float*)d_in[28]; const float* macB2=(const float*)d_in[29];

  float* ws = (float*)d_ws;
  float* out = (float*)d_out;
  const bool mf = ws_size >= (size_t)105604292;

  if(mf){
    // ---- MFMA path ----
    float* h    = ws;                              // N*128
    float* agg  = ws + (size_t)6400000;            // N*128
    unsigned short* hPu = (unsigned short*)(ws + 12800000);  // N*256 ushort (hi|lo planes)
    float* Sb   = ws + (size_t)19200000;           // 7*256
    float* gf   = ws + (size_t)19201792;
    float* muiv = ws + (size_t)19201808;           // 256
    float* bb1s = ws + (size_t)19202064;           // 768
    float* ub1s = ws + (size_t)19202832;           // 768
    float* bb1d = ws + (size_t)19203600;           // 128
    float* ub1d = ws + (size_t)19203728;           // 128
    int* cnt  = (int*)(ws + 19203856);
    int* off  = (int*)(ws + 19253856);
    int* cur  = (int*)(ws + 19303857);
    int* srcP = (int*)(ws + 19353857);
    int* dstP = (int*)(ws + 19653857);
    unsigned short* mPdst  = (unsigned short*)(ws + 19953860);
    unsigned short* mPsrc  = (unsigned short*)(ws + 19970244);
    unsigned short* uPh    = (unsigned short*)(ws + 19986628);
    unsigned short* mPedge = (unsigned short*)(ws + 20003012);
    unsigned short* mPw2   = (unsigned short*)(ws + 20027588);
    unsigned short* uPagg  = (unsigned short*)(ws + 20125892);
    unsigned short* uPw2   = (unsigned short*)(ws + 20224196);

    k_gf<<<1, 64, 0, stream>>>(dom, tt, xg, domn, tn, gf);
    k_gfb2<<<6, 256, 0, stream>>>(gf, msgW1, msgB1, updW1, updB1, bb1s, ub1s);
    k_packAll<<<624, 64, 0, stream>>>(msgW1, msgW2, updW1, updW2, mPedge, mPw2, uPagg, uPw2);
    hipMemsetAsync(Sb, 0, 7*256*4, stream);
    hipMemsetAsync(agg, 0, (size_t)6400000*4, stream);
    hipMemsetAsync(cnt, 0, (size_t)NNODES*4, stream);
    hipMemsetAsync(cur, 0, (size_t)NNODES*4, stream);
    k_histi<<<(NEDGES+255)/256, 256, 0, stream>>>(ei, cnt);
    k_scan<<<1, 1024, 0, stream>>>(cnt, off);
    k_scatter<<<(NEDGES+255)/256, 256, 0, stream>>>(ei, off, cur, srcP, dstP);
    k_embed<<<(NNODES+31)/32, 256, 0, stream>>>(r, v, gf, embW1, embB1, embW2, embB2, h, hPu);
    for(int l = 0; l < NL; l++){
      k_prep<<<50, 128, 0, stream>>>((l > 0) ? (Sb + (l-1)*256) : Sb, l,
          msgW1 + (size_t)l*35712, updW1 + (size_t)l*34304,
          bb1s + l*128, ub1s + l*128, muiv, bb1d, ub1d, mPdst, mPsrc, uPh);
      k_msgM2<<<4688, 256, 0, stream>>>(srcP, dstP, hPu, pos, v, r, dom,
          mPdst, mPsrc, mPedge + (size_t)l*8192, mPw2 + (size_t)l*32768,
          bb1d, msgB2 + l*128, agg);
      k_updM<<<(NNODES+31)/32, 256, 0, stream>>>(h, hPu, agg, cnt, muiv,
          uPh, uPagg + (size_t)l*32768, uPw2 + (size_t)l*32768,
          ub1d, updB2 + l*128, Sb + l*256, (l == NL-1) ? 1 : 0);
    }
    k_normstats<<<256, 256, 0, stream>>>(h, Sb + 5*256, Sb + 5*256 + 128, Sb + 6*256);
    k_macro<<<1, 128, 0, stream>>>(Sb + 6*256, macW1, macB1, macW2, macB2, out);
    k_out<<<(NNODES+31)/32, 256, 0, stream>>>(h, pos, v, domn,
                                              outW1, outB1, outW2, outB2, out);
    return;
  }

  // ---- fallback fp32 path (smaller workspace; not expected to run) ----
  float* h   = ws;
  float* agg = ws + (size_t)6400000;
  float* P   = ws + (size_t)12800000;
  float* deg = ws + (size_t)25600000;
  float* gf  = ws + (size_t)25650016;
  float* sum = ws + (size_t)25650048;
  float* sq  = ws + (size_t)25650176;
  float* bb1 = ws + (size_t)25650304;

  k_gf<<<1, 64, 0, stream>>>(dom, tt, xg, domn, tn, gf);
  k_gfb<<<3, 256, 0, stream>>>(gf, msgW1, msgB1, bb1);
  hipMemsetAsync(deg, 0, (size_t)NNODES*4, stream);
  k_deg<<<(NEDGES+255)/256, 256, 0, stream>>>(ei, deg);
  k_embed<<<(NNODES+31)/32, 256, 0, stream>>>(r, v, gf, embW1, embB1, embW2, embB2, h,
                                              (unsigned short*)0);
  for(int l = 0; l < NL; l++){
    hipMemsetAsync(agg, 0, (size_t)6400000*4, stream);
    k_pre<<<(NNODES+31)/32, 256, 0, stream>>>(h, msgW1 + (size_t)l*35712, P);
    k_msg2<<<NEDGES/32, 256, 0, stream>>>(ei, P, pos, v, r, dom,
        msgW1 + (size_t)l*35712, msgW2 + (size_t)l*16384,
        bb1 + l*128, msgB2 + l*128, agg);
    k_upd<<<(NNODES+31)/32, 256, 0, stream>>>(h, agg, deg, gf,
        updW1, updB1, updW2, updB2, l);
    hipMemsetAsync(sum, 0, 128*4, stream);
    hipMemsetAsync(sq,  0, 128*4, stream);
    k_stats<<<256, 256, 0, stream>>>(h, sum, sq);
    k_norm<<<25000, 256, 0, stream>>>(h, sum, sq);
  }
  hipMemsetAsync(sum, 0, 128*4, stream);
  hipMemsetAsync(sq,  0, 128*4, stream);
  k_stats<<<256, 256, 0, stream>>>(h, sum, sq);
  k_macro<<<1, 128, 0, stream>>>(sum, macW1, macB1, macW2, macB2, out);
  k_out<<<(NNODES+31)/32, 256, 0, stream>>>(h, pos, v, domn,
                                            outW1, outB1, outW2, outB2, out);
}

// Round 12
// 1610.079 us; speedup vs baseline: 1.2686x; 1.0186x over previous
//
#include <hip/hip_runtime.h>

#define NNODES 50000
#define NEDGES 300000
#define NL 6
#define AP 132

typedef float f32x4 __attribute__((ext_vector_type(4)));
typedef short s16x8 __attribute__((ext_vector_type(8)));
typedef unsigned short u16x4 __attribute__((ext_vector_type(4)));

#define MFMA(A,B,C) __builtin_amdgcn_mfma_f32_16x16x32_bf16((A),(B),(C),0,0,0)

__device__ __forceinline__ unsigned short bf_hi(float x){
  unsigned u = __float_as_uint(x);
  u += 0x7fffu + ((u>>16)&1u);
  return (unsigned short)(u>>16);
}
__device__ __forceinline__ float bf_f(unsigned short s){
  return __uint_as_float(((unsigned)s)<<16);
}
__device__ __forceinline__ void split2(float x, unsigned short &h, unsigned short &l){
  h = bf_hi(x);
  l = bf_hi(x - bf_f(h));
}

__device__ __forceinline__ f32x4 mm3(s16x8 ah, s16x8 al, s16x8 bh, s16x8 bl, f32x4 c){
  c = MFMA(ah, bh, c);
  c = MFMA(ah, bl, c);
  c = MFMA(al, bh, c);
  return c;
}
// A-hi only (src path): B keeps hi+lo precision
__device__ __forceinline__ f32x4 mm2(s16x8 ah, s16x8 bh, s16x8 bl, f32x4 c){
  c = MFMA(ah, bh, c);
  c = MFMA(ah, bl, c);
  return c;
}

// ---- packed-weight fragment helpers ----
__device__ __forceinline__ void pack_tile(const float* W, int K, const float* iv,
                                          unsigned short* dst, int kt, int nt, int lane){
  int col = nt*16 + (lane&15);
  int k0 = kt*32 + (lane>>4)*8;
  s16x8 hv, lv;
  #pragma unroll
  for(int j=0;j<8;j++){
    int k = k0 + j;
    float x = 0.f;
    if(k < K){
      x = W[(size_t)k*128 + col];
      if(iv) x *= iv[k];
    }
    unsigned short hh, ll; split2(x, hh, ll);
    hv[j] = (short)hh; lv[j] = (short)ll;
  }
  unsigned short* p = dst + ((size_t)((kt<<3)+nt)*64 + lane)*16;
  *(s16x8*)p = hv;
  *(s16x8*)(p+8) = lv;
}
__device__ __forceinline__ void ld_b(const unsigned short* P, int kt, int nt, int lane,
                                     s16x8 &bh, s16x8 &bl){
  const unsigned short* p = P + ((size_t)((kt<<3)+nt)*64 + lane)*16;
  bh = *(const s16x8*)p;
  bl = *(const s16x8*)(p+8);
}
// LDS bf16 plane, pitch 128 ushorts (256B), XOR swizzle (row&7)<<4
__device__ __forceinline__ s16x8 ld_z(const unsigned short* z, int row, int kByte){
  return *(const s16x8*)((const char*)z + row*256 + (kByte ^ ((row&7)<<4)));
}
__device__ __forceinline__ void st_z(unsigned short* zH, unsigned short* zL, int row, int col, float x){
  unsigned short hh, ll; split2(x, hh, ll);
  int byte = row*256 + ((col*2) ^ ((row&7)<<4));
  *(unsigned short*)((char*)zH + byte) = hh;
  *(unsigned short*)((char*)zL + byte) = ll;
}
// LDS bf16 plane, pitch 32 ushorts (64B), XOR swizzle (row&3)<<4 (edge features)
__device__ __forceinline__ s16x8 ld_t(const unsigned short* z, int row, int kByte){
  return *(const s16x8*)((const char*)z + row*64 + (kByte ^ ((row&3)<<4)));
}

// ---------- tiny setup kernels ----------
__global__ void k_gf(const float* dom, const float* t, const float* xg,
                     const float* domn, const float* tn, float* gf){
  int i = threadIdx.x;
  if(i < 3)        gf[i]  = dom[i];
  else if(i == 3)  gf[3]  = t[0];
  else if(i < 8)   gf[i]  = xg[i-4];
  else if(i < 11)  gf[i]  = domn[i-8];
  else if(i == 11) gf[11] = tn[0];
}

__global__ void k_deg(const int* ei, float* deg){
  int e = blockIdx.x*blockDim.x + threadIdx.x;
  if(e < NEDGES) atomicAdd(&deg[ei[NEDGES + e]], 1.0f);
}

__global__ void k_histi(const int* ei, int* cnt){
  int e = blockIdx.x*blockDim.x + threadIdx.x;
  if(e < NEDGES) atomicAdd(&cnt[ei[NEDGES + e]], 1);
}

__global__ __launch_bounds__(1024) void k_scan(const int* cnt, int* off){
  __shared__ int buf[1024];
  __shared__ int carry;
  int t = threadIdx.x;
  if(t == 0) carry = 0;
  __syncthreads();
  for(int base = 0; base < NNODES; base += 1024){
    int i = base + t;
    int x = (i < NNODES) ? cnt[i] : 0;
    buf[t] = x;
    __syncthreads();
    for(int ofs = 1; ofs < 1024; ofs <<= 1){
      int y = (t >= ofs) ? buf[t-ofs] : 0;
      __syncthreads();
      buf[t] += y;
      __syncthreads();
    }
    if(i < NNODES) off[i] = carry + buf[t] - x;
    __syncthreads();
    if(t == 1023) carry += buf[1023];
    __syncthreads();
  }
  if(t == 0) off[NNODES] = carry;
}

__global__ void k_scatter(const int* ei, const int* off, int* cur, int* srcP, int* dstP){
  int e = blockIdx.x*blockDim.x + threadIdx.x;
  if(e < NEDGES){
    int s = ei[e], d = ei[NEDGES + e];
    int p = atomicAdd(&cur[d], 1);
    int ix = off[d] + p;
    srcP[ix] = s; dstP[ix] = d;
  }
}

// old gf-fold (fallback path)
__global__ void k_gfb(const float* gf, const float* mW1, const float* mB1, float* bb1){
  int i = blockIdx.x*256 + threadIdx.x;
  if(i < 768){
    int l = i >> 7, c = i & 127;
    float s = mB1[l*128 + c];
    #pragma unroll
    for(int j=0;j<12;j++) s = fmaf(gf[j], mW1[(size_t)l*35712 + (size_t)(267+j)*128 + c], s);
    bb1[i] = s;
  }
}

// static bias parts: bb1s = msgB1 + gf@msgW1[267:279]; ub1s = updB1 + gf@updW1[256:268]
__global__ void k_gfb2(const float* gf, const float* mW1, const float* mB1,
                       const float* uW1, const float* uB1, float* bb1s, float* ub1s){
  int i = blockIdx.x*256 + threadIdx.x;
  if(i < 768){
    int l = i>>7, c = i&127;
    float s = mB1[l*128+c];
    #pragma unroll
    for(int j=0;j<12;j++) s = fmaf(gf[j], mW1[(size_t)l*35712 + (size_t)(267+j)*128 + c], s);
    bb1s[i] = s;
  } else if(i < 1536){
    int i2 = i-768, l = i2>>7, c = i2&127;
    float s = uB1[l*128+c];
    #pragma unroll
    for(int j=0;j<12;j++) s = fmaf(gf[j], uW1[(size_t)l*34304 + (size_t)(256+j)*128 + c], s);
    ub1s[i2] = s;
  }
}

// ---------- fused per-layer prep: stats->muiv, dynamic biases, iv-scaled packs ----------
__global__ __launch_bounds__(128) void k_prep(const float* S, int l,
    const float* msgW1l, const float* updW1l,
    const float* bb1s_l, const float* ub1s_l,
    float* muiv, float* bb1d, float* ub1d,
    unsigned short* mPdst, unsigned short* mPsrc, unsigned short* uPh)
{
  __shared__ float smu[128], siv[128];
  int t = threadIdx.x, b = blockIdx.x;
  {
    float mu, iv;
    if(l == 0){ mu = 0.f; iv = 1.f; }
    else {
      float mean = S[t] * (1.0f/NNODES);
      float var  = S[128+t] * (1.0f/NNODES) - mean*mean;
      if(var < 0.f) var = 0.f;
      mu = mean; iv = rsqrtf(var + 1e-5f);
    }
    smu[t] = mu; siv[t] = iv;
  }
  __syncthreads();
  if(b == 0){
    muiv[t] = smu[t]; muiv[128+t] = siv[t];
    float s = bb1s_l[t];
    for(int k=0;k<128;k++){
      float f = smu[k]*siv[k];
      s -= f*(msgW1l[(size_t)k*128+t] + msgW1l[(size_t)(128+k)*128+t]);
    }
    bb1d[t] = s;
  } else if(b == 1){
    float s = ub1s_l[t];
    for(int k=0;k<128;k++) s -= smu[k]*siv[k]*updW1l[(size_t)k*128+t];
    ub1d[t] = s;
  } else {
    int tt = (b-2)*2 + (t>>6);
    int lane = t&63;
    if(tt < 32)      pack_tile(msgW1l,          128, siv, mPdst, tt>>3, tt&7, lane);
    else if(tt < 64){ int q=tt-32; pack_tile(msgW1l + 16384, 128, siv, mPsrc, q>>3, q&7, lane); }
    else            { int q=tt-64; pack_tile(updW1l,         128, siv, uPh,   q>>3, q&7, lane); }
  }
}

// static packs: msgW2, updW1-agg-half, updW2, msg edge rows
__global__ void k_packAll(const float* msgW1, const float* msgW2,
                          const float* updW1, const float* updW2,
                          unsigned short* mPedge, unsigned short* mPw2,
                          unsigned short* uPagg, unsigned short* uPw2){
  int b = blockIdx.x, lane = threadIdx.x;
  if(b < 192){
    int l=b/32, t=b%32;
    pack_tile(msgW2 + (size_t)l*16384, 128, 0, mPw2 + (size_t)l*32768, t/8, t%8, lane);
  } else if(b < 384){
    int bb=b-192, l=bb/32, t=bb%32;
    pack_tile(updW1 + (size_t)l*34304 + 16384, 128, 0, uPagg + (size_t)l*32768, t/8, t%8, lane);
  } else if(b < 576){
    int bb=b-384, l=bb/32, t=bb%32;
    pack_tile(updW2 + (size_t)l*16384, 128, 0, uPw2 + (size_t)l*32768, t/8, t%8, lane);
  } else {
    int bb=b-576, l=bb/8, nt=bb%8;
    pack_tile(msgW1 + (size_t)l*35712 + 32768, 11, 0, mPedge + (size_t)l*8192, 0, nt, lane);
  }
}

// ---------- shared fp32 GEMM machinery (embed + fallback) ----------
__device__ __forceinline__ void fill_w(float* sW, const float* gW, int KC){
  for(int idx = threadIdx.x; idx < 32*32; idx += 256){
    int kk = idx >> 5, c4 = (idx & 31)*4;
    float4 w = make_float4(0.f,0.f,0.f,0.f);
    if(kk < KC) w = *(const float4*)(gW + (size_t)kk*128 + c4);
    *(float4*)(sW + kk*128 + c4) = w;
  }
}
__device__ __forceinline__ void gemm_chunk(const float* At, const float* sW,
                                           int KCp, int rg, int jc, float acc[4][4]){
  for(int kkg = 0; kkg < KCp; kkg += 4){
    float4 av[4];
    #pragma unroll
    for(int i=0;i<4;i++) av[i] = *(const float4*)(At + (rg*4+i)*AP + kkg);
    #pragma unroll
    for(int q=0;q<4;q++){
      float4 bq = *(const float4*)(sW + (kkg+q)*128 + 4*jc);
      #pragma unroll
      for(int i=0;i<4;i++){
        float aa = ((const float*)&av[i])[q];
        acc[i][0] = fmaf(aa, bq.x, acc[i][0]);
        acc[i][1] = fmaf(aa, bq.y, acc[i][1]);
        acc[i][2] = fmaf(aa, bq.z, acc[i][2]);
        acc[i][3] = fmaf(aa, bq.w, acc[i][3]);
      }
    }
  }
}
__device__ __forceinline__ void gemm_phase(const float* sA, float* sW, const float* gW,
                                           int K, int rg, int jc, float acc[4][4]){
  for(int k0 = 0; k0 < K; k0 += 32){
    int KC = (K - k0 < 32) ? (K - k0) : 32;
    __syncthreads();
    fill_w(sW, gW + (size_t)k0*128, KC);
    __syncthreads();
    gemm_chunk(sA + k0, sW, (KC+3)&~3, rg, jc, acc);
  }
}
__device__ __forceinline__ void init_bias(float acc[4][4], const float* b, int jc){
  float4 bb = *(const float4*)(b + 4*jc);
  #pragma unroll
  for(int i=0;i<4;i++){ acc[i][0]=bb.x; acc[i][1]=bb.y; acc[i][2]=bb.z; acc[i][3]=bb.w; }
}

// ---------- embedding (fp32; also writes bf16 hi/lo planes when hPu != 0) ----------
__global__ __launch_bounds__(256) void k_embed(const float* r, const float* v, const float* gf,
    const float* W1, const float* b1, const float* W2, const float* b2, float* h,
    unsigned short* hPu){
  __shared__ __align__(16) float sA[32*AP];
  __shared__ __align__(16) float sW[32*128];
  __shared__ float sGf[12];
  int t = threadIdx.x, n0 = blockIdx.x*32;
  if(t < 12) sGf[t] = gf[t];
  __syncthreads();
  for(int idx = t; idx < 32*20; idx += 256){
    int row = idx/20, c = idx%20;
    int n = n0 + row; if(n >= NNODES) n = NNODES-1;
    float val;
    if(c == 0)      val = r[n];
    else if(c < 7)  val = v[(size_t)n*6 + (c-1)];
    else if(c < 19) val = sGf[c-7];
    else            val = 0.0f;
    sA[row*AP + c] = val;
  }
  int rg = t>>5, jc = t&31;
  float acc[4][4];
  init_bias(acc, b1, jc);
  gemm_phase(sA, sW, W1, 19, rg, jc, acc);
  __syncthreads();
  #pragma unroll
  for(int i=0;i<4;i++){
    float4 x = make_float4(fmaxf(acc[i][0],0.f), fmaxf(acc[i][1],0.f),
                           fmaxf(acc[i][2],0.f), fmaxf(acc[i][3],0.f));
    *(float4*)&sA[(rg*4+i)*AP + 4*jc] = x;
  }
  init_bias(acc, b2, jc);
  gemm_phase(sA, sW, W2, 128, rg, jc, acc);
  #pragma unroll
  for(int i=0;i<4;i++){
    int n = n0 + rg*4 + i;
    if(n < NNODES){
      float4 x = make_float4(fmaxf(acc[i][0],0.f), fmaxf(acc[i][1],0.f),
                             fmaxf(acc[i][2],0.f), fmaxf(acc[i][3],0.f));
      *(float4*)&h[(size_t)n*128 + 4*jc] = x;
      if(hPu){
        unsigned short h0,h1,h2,h3,l0,l1,l2,l3;
        split2(x.x,h0,l0); split2(x.y,h1,l1); split2(x.z,h2,l2); split2(x.w,h3,l3);
        u16x4 hv; hv[0]=h0; hv[1]=h1; hv[2]=h2; hv[3]=h3;
        u16x4 lv; lv[0]=l0; lv[1]=l1; lv[2]=l2; lv[3]=l3;
        *(u16x4*)&hPu[(size_t)n*256 + 4*jc] = hv;
        *(u16x4*)&hPu[(size_t)n*256 + 128 + 4*jc] = lv;
      }
    }
  }
}

// ---------- MFMA edge kernel, 64 edges/block, XCD-swizzled (round-10 proven numerics) ----------
// src term uses hi-plane only (mm2); z2 full hi+lo split (mm3).
__global__ __launch_bounds__(256) void k_msgM2(const int* __restrict__ srcP, const int* __restrict__ dstP,
    const unsigned short* __restrict__ hPu,
    const float* __restrict__ pos, const float* __restrict__ v, const float* __restrict__ r,
    const float* __restrict__ dom,
    const unsigned short* __restrict__ mPdst, const unsigned short* __restrict__ mPsrc,
    const unsigned short* __restrict__ mPedge, const unsigned short* __restrict__ mPw2,
    const float* __restrict__ bb1d, const float* __restrict__ b2, float* __restrict__ agg)
{
  // zH[8192] zL[8192] ushorts (64 rows x 128 cols each, swizzled); reused as fp32 sM[64*128]
  __shared__ __align__(16) unsigned short zBuf[16384];
  __shared__ __align__(16) unsigned short sTh[2048], sTl[2048];
  __shared__ int sSrc[64], sDst[64];
  __shared__ float sDom[3];
  unsigned short* zH = zBuf;
  unsigned short* zL = zBuf + 8192;
  int t = threadIdx.x;
  // bijective XCD swizzle: 4688 blocks = 8 * 586
  int bid = blockIdx.x;
  int swz = (bid & 7)*586 + (bid >> 3);
  int e0 = swz*64;
  int evalid = NEDGES - e0; if(evalid > 64) evalid = 64;
  int w = t>>6, lane = t&63, lr = lane&15, g = lane>>4;
  int nt0 = w*2, nt1 = nt0+1;
  if(t < 64){
    int ee = e0 + t; if(ee >= NEDGES) ee = NEDGES-1;
    sSrc[t] = srcP[ee]; sDst[t] = dstP[ee];
  }
  if(t >= 64 && t < 67) sDom[t-64] = dom[t-64];
  {
    s16x8 zz = {0,0,0,0,0,0,0,0};
    ((s16x8*)sTh)[t] = zz;
    ((s16x8*)sTl)[t] = zz;
  }
  __syncthreads();
  if(t < 64){
    int s = sSrc[t], d = sDst[t];
    float f[11];
    #pragma unroll
    for(int c=0;c<3;c++){
      float dp = pos[(size_t)d*3+c] - pos[(size_t)s*3+c];
      float dm = sDom[c];
      f[c] = dp - dm*rintf(dp/dm);
    }
    #pragma unroll
    for(int c=0;c<6;c++) f[3+c] = v[(size_t)d*6+c] - v[(size_t)s*6+c];
    f[9] = r[d]; f[10] = r[s];
    #pragma unroll
    for(int k=0;k<11;k++){
      unsigned short hh, ll; split2(f[k], hh, ll);
      int byte = t*64 + ((k*2) ^ ((t&3)<<4));
      *(unsigned short*)((char*)sTh + byte) = hh;
      *(unsigned short*)((char*)sTl + byte) = ll;
    }
  }
  float bias0 = bb1d[nt0*16+lr], bias1 = bb1d[nt1*16+lr];
  f32x4 A0[4], A1[4];   // A0[rt] = cols nt0, A1[rt] = cols nt1, rows rt*16+...
  #pragma unroll
  for(int rt=0;rt<4;rt++){
    f32x4 b0 = {bias0,bias0,bias0,bias0};
    f32x4 b1v = {bias1,bias1,bias1,bias1};
    A0[rt] = b0; A1[rt] = b1v;
  }
  __syncthreads();
  // per-lane node row pointers (rows rt*16 + lr)
  const unsigned short* pd[4];
  const unsigned short* ps[4];
  #pragma unroll
  for(int rt=0;rt<4;rt++){
    pd[rt] = hPu + (size_t)sDst[rt*16+lr]*256;
    ps[rt] = hPu + (size_t)sSrc[rt*16+lr]*256;
  }
  int ko = g*8;
  #pragma unroll
  for(int kt=0;kt<4;kt++){
    int o = kt*32 + ko;
    s16x8 DH[4], DL[4], SH[4];
    #pragma unroll
    for(int rt=0;rt<4;rt++){
      DH[rt] = *(const s16x8*)(pd[rt] + o);
      DL[rt] = *(const s16x8*)(pd[rt] + 128 + o);
      SH[rt] = *(const s16x8*)(ps[rt] + o);   // src: hi plane only
    }
    s16x8 bh, bl;
    ld_b(mPdst, kt, nt0, lane, bh, bl);
    #pragma unroll
    for(int rt=0;rt<4;rt++) A0[rt] = mm3(DH[rt], DL[rt], bh, bl, A0[rt]);
    ld_b(mPdst, kt, nt1, lane, bh, bl);
    #pragma unroll
    for(int rt=0;rt<4;rt++) A1[rt] = mm3(DH[rt], DL[rt], bh, bl, A1[rt]);
    ld_b(mPsrc, kt, nt0, lane, bh, bl);
    #pragma unroll
    for(int rt=0;rt<4;rt++) A0[rt] = mm2(SH[rt], bh, bl, A0[rt]);
    ld_b(mPsrc, kt, nt1, lane, bh, bl);
    #pragma unroll
    for(int rt=0;rt<4;rt++) A1[rt] = mm2(SH[rt], bh, bl, A1[rt]);
  }
  {
    s16x8 TH[4], TL[4];
    #pragma unroll
    for(int rt=0;rt<4;rt++){
      TH[rt] = ld_t(sTh, rt*16+lr, g*16);
      TL[rt] = ld_t(sTl, rt*16+lr, g*16);
    }
    s16x8 bh, bl;
    ld_b(mPedge, 0, nt0, lane, bh, bl);
    #pragma unroll
    for(int rt=0;rt<4;rt++) A0[rt] = mm3(TH[rt], TL[rt], bh, bl, A0[rt]);
    ld_b(mPedge, 0, nt1, lane, bh, bl);
    #pragma unroll
    for(int rt=0;rt<4;rt++) A1[rt] = mm3(TH[rt], TL[rt], bh, bl, A1[rt]);
  }
  #pragma unroll
  for(int rt=0;rt<4;rt++){
    #pragma unroll
    for(int i=0;i<4;i++){
      int row = rt*16 + g*4 + i;
      st_z(zH, zL, row, nt0*16+lr, fmaxf(A0[rt][i],0.f));
      st_z(zH, zL, row, nt1*16+lr, fmaxf(A1[rt][i],0.f));
    }
  }
  __syncthreads();
  float c0 = b2[nt0*16+lr], c1 = b2[nt1*16+lr];
  f32x4 M0[4], M1[4];
  #pragma unroll
  for(int rt=0;rt<4;rt++){
    f32x4 b0 = {c0,c0,c0,c0};
    f32x4 b1v = {c1,c1,c1,c1};
    M0[rt] = b0; M1[rt] = b1v;
  }
  #pragma unroll
  for(int kt=0;kt<4;kt++){
    int kb = kt*64 + g*16;
    s16x8 ZHv[4], ZLv[4];
    #pragma unroll
    for(int rt=0;rt<4;rt++){
      ZHv[rt] = ld_z(zH, rt*16+lr, kb);
      ZLv[rt] = ld_z(zL, rt*16+lr, kb);
    }
    s16x8 bh, bl;
    ld_b(mPw2, kt, nt0, lane, bh, bl);
    #pragma unroll
    for(int rt=0;rt<4;rt++) M0[rt] = mm3(ZHv[rt], ZLv[rt], bh, bl, M0[rt]);
    ld_b(mPw2, kt, nt1, lane, bh, bl);
    #pragma unroll
    for(int rt=0;rt<4;rt++) M1[rt] = mm3(ZHv[rt], ZLv[rt], bh, bl, M1[rt]);
  }
  __syncthreads();
  float* sM = (float*)zBuf;
  #pragma unroll
  for(int rt=0;rt<4;rt++){
    #pragma unroll
    for(int i=0;i<4;i++){
      int row = rt*16 + g*4 + i;
      sM[row*128 + nt0*16+lr] = fmaxf(M0[rt][i],0.f);
      sM[row*128 + nt1*16+lr] = fmaxf(M1[rt][i],0.f);
    }
  }
  __syncthreads();
  int col = t & 127, half = t >> 7;
  int rbeg = half*32, rend = rbeg + 32;
  int cur = sDst[rbeg];
  float run = 0.f;
  for(int row = rbeg; row < rend; row++){
    if(row < evalid) run += sM[row*128 + col];
    int nxt = (row+1 < rend) ? sDst[row+1] : -1;
    if(nxt != cur){
      atomicAdd(&agg[(size_t)cur*128 + col], run);
      run = 0.f; cur = nxt;
    }
  }
}

// ---------- MFMA node-update kernel (round-10 proven numerics) ----------
__global__ __launch_bounds__(256) void k_updM(float* __restrict__ h, unsigned short* __restrict__ hPu,
    float* __restrict__ agg, const int* __restrict__ cnt, const float* __restrict__ muiv,
    const unsigned short* __restrict__ uPh, const unsigned short* __restrict__ uPagg,
    const unsigned short* __restrict__ uPw2,
    const float* __restrict__ ub1d, const float* __restrict__ b2, float* __restrict__ S,
    int writeH)
{
  __shared__ __align__(16) unsigned short zBuf[8192];   // agg planes, then z2 planes
  __shared__ __align__(16) float sH[32*AP];
  __shared__ float sRd[32];
  __shared__ float stS[512], stQ[512];
  unsigned short* zH = zBuf; unsigned short* zL = zBuf + 4096;
  int t = threadIdx.x, n0 = blockIdx.x*32;
  int w = t>>6, lane = t&63, lr = lane&15, g = lane>>4;
  int nt0 = w*2, nt1 = nt0+1;
  if(t < 32){
    int n = n0 + t; if(n >= NNODES) n = NNODES-1;
    sRd[t] = 1.0f / fmaxf((float)cnt[n], 1.0f);
  }
  __syncthreads();
  for(int idx = t; idx < 1024; idx += 256){
    int row = idx>>5, c4 = (idx&31)*4;
    int n = n0 + row; bool valid = (n < NNODES); if(!valid) n = NNODES-1;
    // reconstruct fp32 h from hi/lo planes (no fp32 h read)
    u16x4 hhv = *(const u16x4*)&hPu[(size_t)n*256 + c4];
    u16x4 hlv = *(const u16x4*)&hPu[(size_t)n*256 + 128 + c4];
    float4 hx;
    hx.x = bf_f(hhv[0]) + bf_f(hlv[0]);
    hx.y = bf_f(hhv[1]) + bf_f(hlv[1]);
    hx.z = bf_f(hhv[2]) + bf_f(hlv[2]);
    hx.w = bf_f(hhv[3]) + bf_f(hlv[3]);
    *(float4*)&sH[row*AP + c4] = hx;
    float4 ax = *(const float4*)&agg[(size_t)n*128 + c4];
    float rd = sRd[row];
    ax.x*=rd; ax.y*=rd; ax.z*=rd; ax.w*=rd;
    unsigned short h0,h1,h2,h3,l0,l1,l2,l3;
    split2(ax.x,h0,l0); split2(ax.y,h1,l1); split2(ax.z,h2,l2); split2(ax.w,h3,l3);
    int byte = row*256 + ((c4*2) ^ ((row&7)<<4));
    u16x4 hv; hv[0]=h0; hv[1]=h1; hv[2]=h2; hv[3]=h3;
    u16x4 lv; lv[0]=l0; lv[1]=l1; lv[2]=l2; lv[3]=l3;
    *(u16x4*)((char*)zH + byte) = hv;
    *(u16x4*)((char*)zL + byte) = lv;
    if(valid) *(float4*)&agg[(size_t)n*128 + c4] = make_float4(0.f,0.f,0.f,0.f);
  }
  __syncthreads();
  float bias0 = ub1d[nt0*16+lr], bias1 = ub1d[nt1*16+lr];
  f32x4 a00 = {bias0,bias0,bias0,bias0};
  f32x4 a01 = {bias1,bias1,bias1,bias1};
  f32x4 a10 = a00, a11 = a01;
  int nA0 = n0+lr;    if(nA0 >= NNODES) nA0 = NNODES-1;
  int nA1 = n0+16+lr; if(nA1 >= NNODES) nA1 = NNODES-1;
  const unsigned short* ph0 = hPu + (size_t)nA0*256;
  const unsigned short* ph1 = hPu + (size_t)nA1*256;
  int ko = g*8;
  #pragma unroll
  for(int kt=0;kt<4;kt++){
    int o = kt*32 + ko;
    s16x8 ah0 = *(const s16x8*)(ph0 + o), al0 = *(const s16x8*)(ph0 + 128 + o);
    s16x8 ah1 = *(const s16x8*)(ph1 + o), al1 = *(const s16x8*)(ph1 + 128 + o);
    s16x8 bh, bl;
    ld_b(uPh, kt, nt0, lane, bh, bl);
    a00 = mm3(ah0, al0, bh, bl, a00);
    a10 = mm3(ah1, al1, bh, bl, a10);
    ld_b(uPh, kt, nt1, lane, bh, bl);
    a01 = mm3(ah0, al0, bh, bl, a01);
    a11 = mm3(ah1, al1, bh, bl, a11);
    int kb = kt*64 + g*16;
    s16x8 gh0 = ld_z(zH, lr, kb),    gl0 = ld_z(zL, lr, kb);
    s16x8 gh1 = ld_z(zH, 16+lr, kb), gl1 = ld_z(zL, 16+lr, kb);
    ld_b(uPagg, kt, nt0, lane, bh, bl);
    a00 = mm3(gh0, gl0, bh, bl, a00);
    a10 = mm3(gh1, gl1, bh, bl, a10);
    ld_b(uPagg, kt, nt1, lane, bh, bl);
    a01 = mm3(gh0, gl0, bh, bl, a01);
    a11 = mm3(gh1, gl1, bh, bl, a11);
  }
  __syncthreads();
  #pragma unroll
  for(int i=0;i<4;i++){
    int r0 = g*4+i, r1 = 16+g*4+i;
    st_z(zH, zL, r0, nt0*16+lr, fmaxf(a00[i],0.f));
    st_z(zH, zL, r0, nt1*16+lr, fmaxf(a01[i],0.f));
    st_z(zH, zL, r1, nt0*16+lr, fmaxf(a10[i],0.f));
    st_z(zH, zL, r1, nt1*16+lr, fmaxf(a11[i],0.f));
  }
  __syncthreads();
  float c0 = b2[nt0*16+lr], c1 = b2[nt1*16+lr];
  f32x4 m00 = {c0,c0,c0,c0}, m01 = {c1,c1,c1,c1};
  f32x4 m10 = m00, m11 = m01;
  #pragma unroll
  for(int kt=0;kt<4;kt++){
    int kb = kt*64 + g*16;
    s16x8 ah0 = ld_z(zH, lr, kb),    al0 = ld_z(zL, lr, kb);
    s16x8 ah1 = ld_z(zH, 16+lr, kb), al1 = ld_z(zL, 16+lr, kb);
    s16x8 bh, bl;
    ld_b(uPw2, kt, nt0, lane, bh, bl);
    m00 = mm3(ah0, al0, bh, bl, m00);
    m10 = mm3(ah1, al1, bh, bl, m10);
    ld_b(uPw2, kt, nt1, lane, bh, bl);
    m01 = mm3(ah0, al0, bh, bl, m01);
    m11 = mm3(ah1, al1, bh, bl, m11);
  }
  int col0 = nt0*16+lr, col1 = nt1*16+lr;
  float mu0 = muiv[col0], iv0 = muiv[128+col0];
  float mu1 = muiv[col1], iv1 = muiv[128+col1];
  float s0=0.f,q0=0.f,s1=0.f,q1=0.f;
  #pragma unroll
  for(int tm=0;tm<2;tm++){
    #pragma unroll
    for(int i=0;i<4;i++){
      int row = tm*16 + g*4 + i;
      int n = n0 + row;
      if(n < NNODES){
        float acc0 = (tm==0) ? m00[i] : m10[i];
        float acc1 = (tm==0) ? m01[i] : m11[i];
        float v0 = (sH[row*AP+col0]-mu0)*iv0 + acc0;
        float v1 = (sH[row*AP+col1]-mu1)*iv1 + acc1;
        if(writeH){
          h[(size_t)n*128+col0] = v0;
          h[(size_t)n*128+col1] = v1;
        }
        unsigned short hh,ll;
        split2(v0,hh,ll); hPu[(size_t)n*256+col0]=hh; hPu[(size_t)n*256+128+col0]=ll;
        split2(v1,hh,ll); hPu[(size_t)n*256+col1]=hh; hPu[(size_t)n*256+128+col1]=ll;
        s0+=v0; q0+=v0*v0; s1+=v1; q1+=v1*v1;
      }
    }
  }
  stS[g*128+col0]=s0; stQ[g*128+col0]=q0;
  stS[g*128+col1]=s1; stQ[g*128+col1]=q1;
  __syncthreads();
  if(t < 128){
    float s = stS[t]+stS[128+t]+stS[256+t]+stS[384+t];
    float q = stQ[t]+stQ[128+t]+stQ[256+t]+stQ[384+t];
    atomicAdd(&S[t], s);
    atomicAdd(&S[128 + t], q);
  }
}

// ---------- fallback kernels (fp32 path, kept for smaller workspaces) ----------
__global__ __launch_bounds__(256) void k_pre(const float* h, const float* W1, float* P){
  __shared__ __align__(16) float sA[32*AP];
  __shared__ __align__(16) float sW[32*128];
  int t = threadIdx.x, n0 = blockIdx.x*32;
  for(int idx = t; idx < 1024; idx += 256){
    int row = idx>>5, c4 = (idx&31)*4;
    int n = n0 + row; if(n >= NNODES) n = NNODES-1;
    *(float4*)&sA[row*AP + c4] = *(const float4*)&h[(size_t)n*128 + c4];
  }
  int rg = t>>5, jc = t&31;
  float acc[4][4];
  #pragma unroll
  for(int i=0;i<4;i++){ acc[i][0]=0.f; acc[i][1]=0.f; acc[i][2]=0.f; acc[i][3]=0.f; }
  gemm_phase(sA, sW, W1, 128, rg, jc, acc);
  #pragma unroll
  for(int i=0;i<4;i++){
    int n = n0 + rg*4 + i;
    if(n < NNODES)
      *(float4*)&P[(size_t)n*256 + 4*jc] = make_float4(acc[i][0],acc[i][1],acc[i][2],acc[i][3]);
  }
  #pragma unroll
  for(int i=0;i<4;i++){ acc[i][0]=0.f; acc[i][1]=0.f; acc[i][2]=0.f; acc[i][3]=0.f; }
  gemm_phase(sA, sW, W1 + (size_t)128*128, 128, rg, jc, acc);
  #pragma unroll
  for(int i=0;i<4;i++){
    int n = n0 + rg*4 + i;
    if(n < NNODES)
      *(float4*)&P[(size_t)n*256 + 128 + 4*jc] = make_float4(acc[i][0],acc[i][1],acc[i][2],acc[i][3]);
  }
}

__global__ __launch_bounds__(256) void k_msg2(const int* ei, const float* P,
    const float* pos, const float* v, const float* r, const float* dom,
    const float* W1, const float* W2, const float* bb1, const float* b2, float* agg){
  __shared__ __align__(16) float sM[32*AP];
  __shared__ __align__(16) float sW[32*128];
  __shared__ float sT[32*12];
  __shared__ float sB[128];
  __shared__ int sSrc[32], sDst[32];
  int t = threadIdx.x, e0 = blockIdx.x*32;
  if(t < 32){ sSrc[t] = ei[e0+t]; sDst[t] = ei[NEDGES + e0 + t]; }
  if(t >= 128) sB[t-128] = bb1[t-128];
  __syncthreads();
  for(int idx = t; idx < 352; idx += 256){
    int kk = idx>>5, c4 = (idx&31)*4;
    *(float4*)&sW[kk*128 + c4] = *(const float4*)&W1[(size_t)(256+kk)*128 + c4];
  }
  if(t < 32){
    int s = sSrc[t], d = sDst[t];
    #pragma unroll
    for(int c=0;c<3;c++){
      float dp = pos[(size_t)d*3+c] - pos[(size_t)s*3+c];
      float dm = dom[c];
      dp = dp - dm * rintf(dp/dm);
      sT[t*12 + c] = dp;
    }
    #pragma unroll
    for(int c=0;c<6;c++)
      sT[t*12 + 3 + c] = v[(size_t)d*6+c] - v[(size_t)s*6+c];
    sT[t*12 + 9]  = r[d];
    sT[t*12 + 10] = r[s];
    sT[t*12 + 11] = 0.0f;
  }
  for(int idx = t; idx < 1024; idx += 256){
    int row = idx>>5, c4 = (idx&31)*4;
    float4 pd = *(const float4*)&P[(size_t)sDst[row]*256 + c4];
    float4 ps = *(const float4*)&P[(size_t)sSrc[row]*256 + 128 + c4];
    float4 bb = *(const float4*)&sB[c4];
    *(float4*)&sM[row*AP + c4] = make_float4(bb.x+pd.x+ps.x, bb.y+pd.y+ps.y,
                                             bb.z+pd.z+ps.z, bb.w+pd.w+ps.w);
  }
  __syncthreads();
  int rg = t>>5, jc = t&31;
  float acc[4][4];
  #pragma unroll
  for(int i=0;i<4;i++)
    #pragma unroll
    for(int c=0;c<4;c++) acc[i][c] = sM[(rg*4+i)*AP + 4*jc + c];
  for(int k=0;k<11;k++){
    float4 b = *(const float4*)&sW[k*128 + 4*jc];
    #pragma unroll
    for(int i=0;i<4;i++){
      float a = sT[(rg*4+i)*12 + k];
      acc[i][0] = fmaf(a, b.x, acc[i][0]);
      acc[i][1] = fmaf(a, b.y, acc[i][1]);
      acc[i][2] = fmaf(a, b.z, acc[i][2]);
      acc[i][3] = fmaf(a, b.w, acc[i][3]);
    }
  }
  #pragma unroll
  for(int i=0;i<4;i++){
    float4 x = make_float4(fmaxf(acc[i][0],0.f), fmaxf(acc[i][1],0.f),
                           fmaxf(acc[i][2],0.f), fmaxf(acc[i][3],0.f));
    *(float4*)&sM[(rg*4+i)*AP + 4*jc] = x;
  }
  init_bias(acc, b2, jc);
  gemm_phase(sM, sW, W2, 128, rg, jc, acc);
  #pragma unroll
  for(int i=0;i<4;i++){
    int d = sDst[rg*4+i];
    #pragma unroll
    for(int c=0;c<4;c++)
      atomicAdd(&agg[(size_t)d*128 + 4*jc + c], fmaxf(acc[i][c], 0.0f));
  }
}

__global__ __launch_bounds__(256) void k_upd(float* h, const float* agg, const float* deg,
    const float* gf, const float* W1, const float* b1, const float* W2, const float* b2, int l){
  __shared__ __align__(16) float sA[32*AP];
  __shared__ __align__(16) float sW[32*128];
  __shared__ float sGf[12], sRd[32];
  int t = threadIdx.x, n0 = blockIdx.x*32;
  if(t < 12) sGf[t] = gf[t];
  if(t < 32){
    int n = n0 + t; if(n >= NNODES) n = NNODES-1;
    sRd[t] = 1.0f / fmaxf(deg[n], 1.0f);
  }
  __syncthreads();
  const float* Wl1 = W1 + (size_t)l*34304;
  const float* Wl2 = W2 + (size_t)l*16384;
  const float* bl1 = b1 + l*128;
  const float* bl2 = b2 + l*128;
  int rg = t>>5, jc = t&31;
  float acc[4][4];
  init_bias(acc, bl1, jc);
  for(int idx = t; idx < 1024; idx += 256){
    int row = idx>>5, c4 = (idx&31)*4;
    int n = n0 + row; if(n >= NNODES) n = NNODES-1;
    *(float4*)&sA[row*AP + c4] = *(const float4*)&h[(size_t)n*128 + c4];
  }
  gemm_phase(sA, sW, Wl1, 128, rg, jc, acc);
  __syncthreads();
  for(int idx = t; idx < 1024; idx += 256){
    int row = idx>>5, c4 = (idx&31)*4;
    int n = n0 + row; if(n >= NNODES) n = NNODES-1;
    float4 x = *(const float4*)&agg[(size_t)n*128 + c4];
    float rd = sRd[row];
    x.x*=rd; x.y*=rd; x.z*=rd; x.w*=rd;
    *(float4*)&sA[row*AP + c4] = x;
  }
  gemm_phase(sA, sW, Wl1 + (size_t)128*128, 128, rg, jc, acc);
  __syncthreads();
  if(t < 32){
    #pragma unroll
    for(int c=0;c<12;c++) sA[t*AP + c] = sGf[c];
  }
  gemm_phase(sA, sW, Wl1 + (size_t)256*128, 12, rg, jc, acc);
  __syncthreads();
  #pragma unroll
  for(int i=0;i<4;i++){
    float4 x = make_float4(fmaxf(acc[i][0],0.f), fmaxf(acc[i][1],0.f),
                           fmaxf(acc[i][2],0.f), fmaxf(acc[i][3],0.f));
    *(float4*)&sA[(rg*4+i)*AP + 4*jc] = x;
  }
  init_bias(acc, bl2, jc);
  gemm_phase(sA, sW, Wl2, 128, rg, jc, acc);
  #pragma unroll
  for(int i=0;i<4;i++){
    int n = n0 + rg*4 + i;
    if(n < NNODES){
      float4 x = *(const float4*)&h[(size_t)n*128 + 4*jc];
      x.x += acc[i][0]; x.y += acc[i][1]; x.z += acc[i][2]; x.w += acc[i][3];
      *(float4*)&h[(size_t)n*128 + 4*jc] = x;
    }
  }
}

// ---------- instance-norm stats / norm (fallback) ----------
__global__ __launch_bounds__(256) void k_stats(const float* h, float* sum, float* sq){
  int col = threadIdx.x & 127, half = threadIdx.x >> 7;
  float s = 0.f, q = 0.f;
  for(int n = blockIdx.x*2 + half; n < NNODES; n += gridDim.x*2){
    float x = h[(size_t)n*128 + col];
    s += x; q += x*x;
  }
  __shared__ float ls[256], lq[256];
  ls[threadIdx.x] = s; lq[threadIdx.x] = q;
  __syncthreads();
  if(half == 0){
    atomicAdd(&sum[col], ls[col] + ls[128+col]);
    atomicAdd(&sq[col],  lq[col] + lq[128+col]);
  }
}

__global__ void k_norm(float* h, const float* sum, const float* sq){
  size_t i = (size_t)blockIdx.x*256 + threadIdx.x;
  if(i < (size_t)NNODES*128){
    int col = i & 127;
    float mean = sum[col] * (1.0f/NNODES);
    float var  = sq[col] * (1.0f/NNODES) - mean*mean;
    if(var < 0.f) var = 0.f;
    h[i] = (h[i] - mean) * rsqrtf(var + 1e-5f);
  }
}

// ---------- output head with fused final instance-norm ----------
__global__ __launch_bounds__(256) void k_outN(const float* h, const float* pos, const float* v,
    const float* domn, const float* sum, const float* sq,
    const float* W1, const float* b1, const float* W2, const float* b2,
    float* out){
  __shared__ __align__(16) float sA[32*AP];
  __shared__ __align__(16) float sW[32*128];
  __shared__ float sW2[128*9], sB2[9], sDn[3];
  __shared__ float smu[128], siv[128];
  int t = threadIdx.x, n0 = blockIdx.x*32;
  if(t < 128){
    float mean = sum[t] * (1.0f/NNODES);
    float var  = sq[t] * (1.0f/NNODES) - mean*mean;
    if(var < 0.f) var = 0.f;
    smu[t] = mean; siv[t] = rsqrtf(var + 1e-5f);
  }
  for(int idx = t; idx < 128*9; idx += 256) sW2[idx] = W2[idx];
  if(t < 9) sB2[t] = b2[t];
  if(t >= 16 && t < 19) sDn[t-16] = domn[t-16];
  __syncthreads();
  for(int idx = t; idx < 1024; idx += 256){
    int row = idx>>5, c4 = (idx&31)*4;
    int n = n0 + row; if(n >= NNODES) n = NNODES-1;
    float4 x = *(const float4*)&h[(size_t)n*128 + c4];
    x.x = (x.x - smu[c4+0])*siv[c4+0];
    x.y = (x.y - smu[c4+1])*siv[c4+1];
    x.z = (x.z - smu[c4+2])*siv[c4+2];
    x.w = (x.w - smu[c4+3])*siv[c4+3];
    *(float4*)&sA[row*AP + c4] = x;
  }
  int rg = t>>5, jc = t&31;
  float acc[4][4];
  init_bias(acc, b1, jc);
  gemm_phase(sA, sW, W1, 128, rg, jc, acc);
  __syncthreads();
  #pragma unroll
  for(int i=0;i<4;i++){
    float4 x = make_float4(fmaxf(acc[i][0],0.f), fmaxf(acc[i][1],0.f),
                           fmaxf(acc[i][2],0.f), fmaxf(acc[i][3],0.f));
    *(float4*)&sA[(rg*4+i)*AP + 4*jc] = x;
  }
  __syncthreads();
  for(int idx = t; idx < 32*9; idx += 256){
    int n = idx/9, c = idx%9;
    int gn = n0 + n;
    if(gn < NNODES){
      float s = sB2[c];
      for(int k=0;k<128;k++) s = fmaf(sA[n*AP + k], sW2[k*9 + c], s);
      if(c < 3){
        float p = 0.001f*s + pos[(size_t)gn*3 + c];
        float dn = sDn[c];
        p = p - floorf(p/dn)*dn;
        out[(size_t)gn*3 + c] = p;
      } else {
        float scale = (c < 6) ? 0.001f : 0.01f;
        float p = scale*s + v[(size_t)gn*6 + (c-3)];
        out[(size_t)150000 + (size_t)gn*6 + (c-3)] = p;
      }
    }
  }
}

// ---------- output head (fallback, raw h) ----------
__global__ __launch_bounds__(256) void k_out(const float* h, const float* pos, const float* v,
    const float* domn, const float* W1, const float* b1, const float* W2, const float* b2,
    float* out){
  __shared__ __align__(16) float sA[32*AP];
  __shared__ __align__(16) float sW[32*128];
  __shared__ float sW2[128*9], sB2[9], sDn[3];
  int t = threadIdx.x, n0 = blockIdx.x*32;
  for(int idx = t; idx < 128*9; idx += 256) sW2[idx] = W2[idx];
  if(t < 9) sB2[t] = b2[t];
  if(t >= 16 && t < 19) sDn[t-16] = domn[t-16];
  for(int idx = t; idx < 1024; idx += 256){
    int row = idx>>5, c4 = (idx&31)*4;
    int n = n0 + row; if(n >= NNODES) n = NNODES-1;
    *(float4*)&sA[row*AP + c4] = *(const float4*)&h[(size_t)n*128 + c4];
  }
  int rg = t>>5, jc = t&31;
  float acc[4][4];
  init_bias(acc, b1, jc);
  gemm_phase(sA, sW, W1, 128, rg, jc, acc);
  __syncthreads();
  #pragma unroll
  for(int i=0;i<4;i++){
    float4 x = make_float4(fmaxf(acc[i][0],0.f), fmaxf(acc[i][1],0.f),
                           fmaxf(acc[i][2],0.f), fmaxf(acc[i][3],0.f));
    *(float4*)&sA[(rg*4+i)*AP + 4*jc] = x;
  }
  __syncthreads();
  for(int idx = t; idx < 32*9; idx += 256){
    int n = idx/9, c = idx%9;
    int gn = n0 + n;
    if(gn < NNODES){
      float s = sB2[c];
      for(int k=0;k<128;k++) s = fmaf(sA[n*AP + k], sW2[k*9 + c], s);
      if(c < 3){
        float p = 0.001f*s + pos[(size_t)gn*3 + c];
        float dn = sDn[c];
        p = p - floorf(p/dn)*dn;
        out[(size_t)gn*3 + c] = p;
      } else {
        float scale = (c < 6) ? 0.001f : 0.01f;
        float p = scale*s + v[(size_t)gn*6 + (c-3)];
        out[(size_t)150000 + (size_t)gn*6 + (c-3)] = p;
      }
    }
  }
}

// ---------- macro head ----------
__global__ __launch_bounds__(128) void k_macro(const float* sum, const float* W1,
    const float* b1, const float* W2, const float* b2, float* out){
  __shared__ float hm[128], t1[128];
  int t = threadIdx.x;
  hm[t] = sum[t] * (1.0f/NNODES);
  __syncthreads();
  float s = b1[t];
  for(int k=0;k<128;k++) s = fmaf(hm[k], W1[(size_t)k*128 + t], s);
  t1[t] = fmaxf(s, 0.0f);
  __syncthreads();
  if(t < 3){
    float o = b2[t];
    for(int k=0;k<128;k++) o = fmaf(t1[k], W2[(size_t)k*3 + t], o);
    out[450000 + t] = o;
  }
}

extern "C" void kernel_launch(void* const* d_in, const int* in_sizes, int n_in,
                              void* d_out, int out_size, void* d_ws, size_t ws_size,
                              hipStream_t stream){
  const float* v    = (const float*)d_in[0];
  const float* pos  = (const float*)d_in[1];
  const float* r    = (const float*)d_in[2];
  const float* dom  = (const float*)d_in[3];
  const float* tt   = (const float*)d_in[4];
  const float* xg   = (const float*)d_in[5];
  const float* domn = (const float*)d_in[6];
  const float* tn   = (const float*)d_in[7];
  const int*   ei   = (const int*)d_in[8];
  const float* embW1=(const float*)d_in[10]; const float* embB1=(const float*)d_in[11];
  const float* embW2=(const float*)d_in[12]; const float* embB2=(const float*)d_in[13];
  const float* msgW1=(const float*)d_in[14]; const float* msgB1=(const float*)d_in[15];
  const float* msgW2=(const float*)d_in[16]; const float* msgB2=(const float*)d_in[17];
  const float* updW1=(const float*)d_in[18]; const float* updB1=(const float*)d_in[19];
  const float* updW2=(const float*)d_in[20]; const float* updB2=(const float*)d_in[21];
  const float* outW1=(const float*)d_in[22]; const float* outB1=(const float*)d_in[23];
  const float* outW2=(const float*)d_in[24]; const float* outB2=(const float*)d_in[25];
  const float* macW1=(const float*)d_in[26]; const float* macB1=(const float*)d_in[27];
  const float* macW2=(const float*)d_in[28]; const float* macB2=(const float*)d_in[29];

  float* ws = (float*)d_ws;
  float* out = (float*)d_out;
  const bool mf = ws_size >= (size_t)105604292;

  if(mf){
    // ---- MFMA path ----
    float* h    = ws;                              // N*128
    float* agg  = ws + (size_t)6400000;            // N*128
    unsigned short* hPu = (unsigned short*)(ws + 12800000);  // N*256 ushort (hi|lo planes)
    float* Sb   = ws + (size_t)19200000;           // 7*256
    float* gf   = ws + (size_t)19201792;
    float* muiv = ws + (size_t)19201808;           // 256
    float* bb1s = ws + (size_t)19202064;           // 768
    float* ub1s = ws + (size_t)19202832;           // 768
    float* bb1d = ws + (size_t)19203600;           // 128
    float* ub1d = ws + (size_t)19203728;           // 128
    int* cnt  = (int*)(ws + 19203856);
    int* off  = (int*)(ws + 19253856);
    int* cur  = (int*)(ws + 19303857);
    int* srcP = (int*)(ws + 19353857);
    int* dstP = (int*)(ws + 19653857);
    unsigned short* mPdst  = (unsigned short*)(ws + 19953860);
    unsigned short* mPsrc  = (unsigned short*)(ws + 19970244);
    unsigned short* uPh    = (unsigned short*)(ws + 19986628);
    unsigned short* mPedge = (unsigned short*)(ws + 20003012);
    unsigned short* mPw2   = (unsigned short*)(ws + 20027588);
    unsigned short* uPagg  = (unsigned short*)(ws + 20125892);
    unsigned short* uPw2   = (unsigned short*)(ws + 20224196);

    k_gf<<<1, 64, 0, stream>>>(dom, tt, xg, domn, tn, gf);
    k_gfb2<<<6, 256, 0, stream>>>(gf, msgW1, msgB1, updW1, updB1, bb1s, ub1s);
    k_packAll<<<624, 64, 0, stream>>>(msgW1, msgW2, updW1, updW2, mPedge, mPw2, uPagg, uPw2);
    hipMemsetAsync(Sb, 0, 7*256*4, stream);
    hipMemsetAsync(agg, 0, (size_t)6400000*4, stream);
    hipMemsetAsync(cnt, 0, (size_t)NNODES*4, stream);
    hipMemsetAsync(cur, 0, (size_t)NNODES*4, stream);
    k_histi<<<(NEDGES+255)/256, 256, 0, stream>>>(ei, cnt);
    k_scan<<<1, 1024, 0, stream>>>(cnt, off);
    k_scatter<<<(NEDGES+255)/256, 256, 0, stream>>>(ei, off, cur, srcP, dstP);
    k_embed<<<(NNODES+31)/32, 256, 0, stream>>>(r, v, gf, embW1, embB1, embW2, embB2, h, hPu);
    for(int l = 0; l < NL; l++){
      k_prep<<<50, 128, 0, stream>>>((l > 0) ? (Sb + (l-1)*256) : Sb, l,
          msgW1 + (size_t)l*35712, updW1 + (size_t)l*34304,
          bb1s + l*128, ub1s + l*128, muiv, bb1d, ub1d, mPdst, mPsrc, uPh);
      k_msgM2<<<4688, 256, 0, stream>>>(srcP, dstP, hPu, pos, v, r, dom,
          mPdst, mPsrc, mPedge + (size_t)l*8192, mPw2 + (size_t)l*32768,
          bb1d, msgB2 + l*128, agg);
      k_updM<<<(NNODES+31)/32, 256, 0, stream>>>(h, hPu, agg, cnt, muiv,
          uPh, uPagg + (size_t)l*32768, uPw2 + (size_t)l*32768,
          ub1d, updB2 + l*128, Sb + l*256, (l == NL-1) ? 1 : 0);
    }
    // macro head: column means of instance-normalized h are exactly 0 up to fp rounding;
    // Sb+6*256 stays zeroed -> hm = 0 (diff vs ref < 1e-5).
    k_macro<<<1, 128, 0, stream>>>(Sb + 6*256, macW1, macB1, macW2, macB2, out);
    // output head with final instance-norm fused into the staging load (bit-identical
    // to normstats-then-out: same fp32 expression, same order).
    k_outN<<<(NNODES+31)/32, 256, 0, stream>>>(h, pos, v, domn,
                                               Sb + 5*256, Sb + 5*256 + 128,
                                               outW1, outB1, outW2, outB2, out);
    return;
  }

  // ---- fallback fp32 path (smaller workspace; not expected to run) ----
  float* h   = ws;
  float* agg = ws + (size_t)6400000;
  float* P   = ws + (size_t)12800000;
  float* deg = ws + (size_t)25600000;
  float* gf  = ws + (size_t)25650016;
  float* sum = ws + (size_t)25650048;
  float* sq  = ws + (size_t)25650176;
  float* bb1 = ws + (size_t)25650304;

  k_gf<<<1, 64, 0, stream>>>(dom, tt, xg, domn, tn, gf);
  k_gfb<<<3, 256, 0, stream>>>(gf, msgW1, msgB1, bb1);
  hipMemsetAsync(deg, 0, (size_t)NNODES*4, stream);
  k_deg<<<(NEDGES+255)/256, 256, 0, stream>>>(ei, deg);
  k_embed<<<(NNODES+31)/32, 256, 0, stream>>>(r, v, gf, embW1, embB1, embW2, embB2, h,
                                              (unsigned short*)0);
  for(int l = 0; l < NL; l++){
    hipMemsetAsync(agg, 0, (size_t)6400000*4, stream);
    k_pre<<<(NNODES+31)/32, 256, 0, stream>>>(h, msgW1 + (size_t)l*35712, P);
    k_msg2<<<NEDGES/32, 256, 0, stream>>>(ei, P, pos, v, r, dom,
        msgW1 + (size_t)l*35712, msgW2 + (size_t)l*16384,
        bb1 + l*128, msgB2 + l*128, agg);
    k_upd<<<(NNODES+31)/32, 256, 0, stream>>>(h, agg, deg, gf,
        updW1, updB1, updW2, updB2, l);
    hipMemsetAsync(sum, 0, 128*4, stream);
    hipMemsetAsync(sq,  0, 128*4, stream);
    k_stats<<<256, 256, 0, stream>>>(h, sum, sq);
    k_norm<<<25000, 256, 0, stream>>>(h, sum, sq);
  }
  hipMemsetAsync(sum, 0, 128*4, stream);
  hipMemsetAsync(sq,  0, 128*4, stream);
  k_stats<<<256, 256, 0, stream>>>(h, sum, sq);
  k_macro<<<1, 128, 0, stream>>>(sum, macW1, macB1, macW2, macB2, out);
  k_out<<<(NNODES+31)/32, 256, 0, stream>>>(h, pos, v, domn,
                                            outW1, outB1, outW2, outB2, out);
}